// Round 6
// baseline (978.628 us; speedup 1.0000x reference)
//
#include <hip/hip_runtime.h>
#include <hip/hip_bf16.h>
#include <math.h>

using u16 = unsigned short;
using u32 = unsigned int;

typedef __attribute__((ext_vector_type(8))) short short8;
typedef __attribute__((ext_vector_type(4))) float f32x4;

__device__ __forceinline__ u16 f2bf_u16(float f) {
    __hip_bfloat16 h = __float2bfloat16(f);
    return __builtin_bit_cast(u16, h);
}
__device__ __forceinline__ float bfu(u32 u) { return __uint_as_float(u << 16); }

static constexpr int NN = 50000;
static constexpr int NE = 1600000;
static constexpr int NIDX = 8192;
static constexpr int NRANGE = 8;              // scatter ranges (XCD-local csr writes)
static constexpr int RN = NN / NRANGE;        // 6250 nodes per range
static constexpr int HCHUNK = 32;             // hist edge-chunks per range

static constexpr int G1B = 782;               // gemm1 blocks per enc (391 x 2)
static constexpr int G2B = 391;               // gemm2 blocks per enc (391 x 1)
static constexpr int AGB = NN / 4;            // agg blocks per enc (12500)
static constexpr int SCB = (2 * NE / 1024) * NRANGE;  // 25000 scatter blocks
static constexpr int ZLB = 64 * 63 / 2;       // 2016 lower-tri z tiles

// all pointers one struct so fused kernels stay tidy
struct P {
    const float* raw0; const float* raw1;
    const int *s1, *d1, *s2, *d2;
    int* cur_all; u16* csr_all;
    const int* rp_all;
    const u16 *W1t, *W2t;
    u16 *Y1, *H1, *Y2;
    float* H2;
    const float* norms;   // [enc*2+0]=ns(src), [enc*2+1]=nd(dst), each NN
    const float *b1_0, *b1_1, *b2_0, *b2_1;
    float* zout;
};

// ---------------- histogram: LDS-privatized partials, no global atomics ----------------

__global__ __launch_bounds__(256)
void hist_kernel(const int* __restrict__ s1, const int* __restrict__ d1,
                 const int* __restrict__ s2, const int* __restrict__ d2,
                 int* __restrict__ partial, int E) {
    __shared__ int h_out[RN];
    __shared__ int h_in[RN];
    int enc = blockIdx.y;
    int range = blockIdx.x & (NRANGE - 1);
    int chunk = blockIdx.x >> 3;
    const int* s = enc ? s2 : s1;
    const int* d = enc ? d2 : d1;
    int lo = range * RN;
    for (int i = threadIdx.x; i < RN; i += 256) { h_out[i] = 0; h_in[i] = 0; }
    __syncthreads();
    int per_chunk = E / HCHUNK;
    int e0 = chunk * per_chunk, e1 = e0 + per_chunk;
    for (int e = e0 + threadIdx.x * 4; e < e1; e += 256 * 4) {
        int4 sv = *(const int4*)(s + e);
        int4 dv = *(const int4*)(d + e);
        u32 a0 = (u32)(sv.x - lo), a1 = (u32)(sv.y - lo), a2 = (u32)(sv.z - lo), a3 = (u32)(sv.w - lo);
        u32 b0 = (u32)(dv.x - lo), b1 = (u32)(dv.y - lo), b2 = (u32)(dv.z - lo), b3 = (u32)(dv.w - lo);
        if (a0 < (u32)RN) atomicAdd(&h_out[a0], 1);
        if (a1 < (u32)RN) atomicAdd(&h_out[a1], 1);
        if (a2 < (u32)RN) atomicAdd(&h_out[a2], 1);
        if (a3 < (u32)RN) atomicAdd(&h_out[a3], 1);
        if (b0 < (u32)RN) atomicAdd(&h_in[b0], 1);
        if (b1 < (u32)RN) atomicAdd(&h_in[b1], 1);
        if (b2 < (u32)RN) atomicAdd(&h_in[b2], 1);
        if (b3 < (u32)RN) atomicAdd(&h_in[b3], 1);
    }
    __syncthreads();
    int* p_out = partial + ((size_t)(enc * 2 + 0) * HCHUNK + chunk) * NN + lo;
    int* p_in  = partial + ((size_t)(enc * 2 + 1) * HCHUNK + chunk) * NN + lo;
    for (int i = threadIdx.x; i < RN; i += 256) { p_out[i] = h_out[i]; p_in[i] = h_in[i]; }
}

__global__ void reduce_hist_kernel(const int* __restrict__ partial, int* __restrict__ deg_all) {
    int i = blockIdx.x * blockDim.x + threadIdx.x;
    if (i >= 4 * NN) return;
    int which = i / NN;
    int node = i - which * NN;
    const int* p = partial + (size_t)which * HCHUNK * NN + node;
    int sum = 0;
    #pragma unroll
    for (int c = 0; c < HCHUNK; ++c) sum += p[(size_t)c * NN];
    deg_all[i] = sum;
}

__global__ void norm_kernel(const int* __restrict__ deg_all, float* __restrict__ norms, int n4) {
    int i = blockIdx.x * blockDim.x + threadIdx.x;
    if (i < n4) norms[i] = rsqrtf(fmaxf((float)deg_all[i], 1.f));
}

__global__ __launch_bounds__(1024)
void scan_kernel(const int* __restrict__ deg_all, int* __restrict__ rp_all,
                 int* __restrict__ cur_all, int n) {
    int enc = blockIdx.x;
    const int* deg = deg_all + (size_t)(2 * enc + 1) * NN;
    int* row_ptr = rp_all + (size_t)enc * (NN + 1);
    int* cursor = cur_all + (size_t)enc * (NN + 1);
    __shared__ int wsum[16];
    __shared__ int carry;
    int t = threadIdx.x;
    int lane = t & 63, wid = t >> 6;
    if (t == 0) carry = 0;
    __syncthreads();
    for (int base = 0; base < n; base += 4096) {
        int i0 = base + t * 4;
        int4 v = make_int4(0, 0, 0, 0);
        if (i0 + 3 < n) v = *(const int4*)(deg + i0);
        else if (i0 < n) {
            v.x = deg[i0];
            if (i0 + 1 < n) v.y = deg[i0 + 1];
            if (i0 + 2 < n) v.z = deg[i0 + 2];
        }
        int s = v.x + v.y + v.z + v.w;
        int x = s;
        #pragma unroll
        for (int d = 1; d < 64; d <<= 1) {
            int y = __shfl_up(x, d, 64);
            if (lane >= d) x += y;
        }
        if (lane == 63) wsum[wid] = x;
        __syncthreads();
        if (t == 0) {
            int run = carry;
            #pragma unroll
            for (int w = 0; w < 16; ++w) { int q = wsum[w]; wsum[w] = run; run += q; }
            carry = run;
        }
        __syncthreads();
        if (i0 < n) {
            int excl = wsum[wid] + x - s;
            int p1 = excl + v.x, p2 = p1 + v.y, p3 = p2 + v.z;
            row_ptr[i0] = excl; cursor[i0] = excl;
            if (i0 + 1 < n) { row_ptr[i0 + 1] = p1; cursor[i0 + 1] = p1; }
            if (i0 + 2 < n) { row_ptr[i0 + 2] = p2; cursor[i0 + 2] = p2; }
            if (i0 + 3 < n) { row_ptr[i0 + 3] = p3; cursor[i0 + 3] = p3; }
        }
        __syncthreads();
    }
    if (t == 0) row_ptr[n] = carry;
}

__global__ void convw_kernel(const float* __restrict__ W1a, const float* __restrict__ W1b,
                             const float* __restrict__ W2a, const float* __restrict__ W2b,
                             u16* __restrict__ W1t_all, u16* __restrict__ W2t_all) {
    int mat = blockIdx.y;
    int idx = blockIdx.x * blockDim.x + threadIdx.x;
    const float* W; u16* Wt; int K, N;
    if (mat < 2) { W = mat ? W1b : W1a; Wt = W1t_all + (size_t)mat * 512 * 256; K = 512; N = 256; }
    else         { W = (mat == 3) ? W2b : W2a; Wt = W2t_all + (size_t)(mat - 2) * 256 * 128; K = 256; N = 128; }
    if (idx < K * N) {
        int k = idx / N, n = idx - k * N;
        Wt[(size_t)n * K + k] = f2bf_u16(W[idx]);
    }
}

// ---------------- device bodies ----------------

// scatter: range = sid&7 (XCD-pinned), chunk = sid>>3
__device__ __forceinline__ void scatter_body(const P& p, int sid) {
    int range = sid & (NRANGE - 1);
    int lo = range * RN, hi = lo + RN;
    int chunk = sid >> 3;
    int e = chunk * 1024 + threadIdx.x * 4;
    const int* s = p.s1; const int* d = p.d1; int enc = 0;
    if (e >= NE) { e -= NE; s = p.s2; d = p.d2; enc = 1; }
    if (e >= NE) return;
    int4 dv = *(const int4*)(d + e);
    bool any = (dv.x >= lo && dv.x < hi) || (dv.y >= lo && dv.y < hi) ||
               (dv.z >= lo && dv.z < hi) || (dv.w >= lo && dv.w < hi);
    if (!any) return;
    int4 sv = *(const int4*)(s + e);
    int* cursor = p.cur_all + (size_t)enc * (NN + 1);
    u16* csr = p.csr_all + (size_t)enc * NE;
    #pragma unroll
    for (int j = 0; j < 4; ++j) {
        int dst = j == 0 ? dv.x : j == 1 ? dv.y : j == 2 ? dv.z : dv.w;
        int src = j == 0 ? sv.x : j == 1 ? sv.y : j == 2 ? sv.z : sv.w;
        if (dst >= lo && dst < hi) {
            int pos = atomicAdd(&cursor[dst], 1);
            csr[pos] = (u16)src;
        }
    }
}

// MFMA GEMM tile: C = A @ Bt^T ; TRIANG epilogue zeroes col<row and uses NT stores.
template<bool A_F32, bool OUT_BF16, bool TRIANG, bool SCALE>
__device__ __forceinline__ void gemm_body(const void* __restrict__ A_, const u16* __restrict__ Bt,
                                          void* __restrict__ C_, const float* __restrict__ rowscale,
                                          int M, int N, int K, int it, int jt,
                                          u16* As, u16* Bs) {
    int t = threadIdx.x;
    int brow = it * 128, bcol = jt * 128;
    float* Cf = (float*)C_;
    int lane = t & 63, wv = t >> 6;
    int wr = wv >> 1, wc = wv & 1;
    f32x4 acc[4][4];
    #pragma unroll
    for (int m = 0; m < 4; ++m)
        #pragma unroll
        for (int n = 0; n < 4; ++n) acc[m][n] = f32x4{0.f, 0.f, 0.f, 0.f};

    for (int k0 = 0; k0 < K; k0 += 32) {
        if (A_F32) {
            const float* A = (const float*)A_;
            #pragma unroll
            for (int pq = 0; pq < 4; ++pq) {
                int r = pq * 32 + (t >> 3), c = (t & 7) * 4;
                int gr = brow + r;
                float4 v = make_float4(0.f, 0.f, 0.f, 0.f);
                if (gr < M) v = *(const float4*)(A + (size_t)gr * K + k0 + c);
                u32 lo = (u32)f2bf_u16(v.x) | ((u32)f2bf_u16(v.y) << 16);
                u32 hi = (u32)f2bf_u16(v.z) | ((u32)f2bf_u16(v.w) << 16);
                *(uint2*)&As[r * 40 + c] = make_uint2(lo, hi);
            }
        } else {
            const u16* A = (const u16*)A_;
            #pragma unroll
            for (int pq = 0; pq < 2; ++pq) {
                int r = pq * 64 + (t >> 2), c = (t & 3) * 8;
                int gr = brow + r;
                uint4 v = make_uint4(0u, 0u, 0u, 0u);
                if (gr < M) v = *(const uint4*)(A + (size_t)gr * K + k0 + c);
                *(uint4*)&As[r * 40 + c] = v;
            }
        }
        #pragma unroll
        for (int pq = 0; pq < 2; ++pq) {
            int r = pq * 64 + (t >> 2), c = (t & 3) * 8;
            int gn = bcol + r;
            uint4 v = make_uint4(0u, 0u, 0u, 0u);
            if (gn < N) v = *(const uint4*)(Bt + (size_t)gn * K + k0 + c);
            *(uint4*)&Bs[r * 40 + c] = v;
        }
        __syncthreads();
        int kg = (lane >> 4) * 8;
        short8 av[4], bv[4];
        #pragma unroll
        for (int m = 0; m < 4; ++m)
            av[m] = *(const short8*)&As[(wr * 64 + m * 16 + (lane & 15)) * 40 + kg];
        #pragma unroll
        for (int n = 0; n < 4; ++n)
            bv[n] = *(const short8*)&Bs[(wc * 64 + n * 16 + (lane & 15)) * 40 + kg];
        #pragma unroll
        for (int m = 0; m < 4; ++m)
            #pragma unroll
            for (int n = 0; n < 4; ++n)
                acc[m][n] = __builtin_amdgcn_mfma_f32_16x16x32_bf16(av[m], bv[n], acc[m][n], 0, 0, 0);
        __syncthreads();
    }
    #pragma unroll
    for (int m = 0; m < 4; ++m) {
        #pragma unroll
        for (int n = 0; n < 4; ++n) {
            #pragma unroll
            for (int r = 0; r < 4; ++r) {
                int row = brow + wr * 64 + m * 16 + (lane >> 4) * 4 + r;
                int col = bcol + wc * 64 + n * 16 + (lane & 15);
                if (row < M && col < N) {
                    float v = acc[m][n][r];
                    if (SCALE) v *= rowscale[row];
                    if (TRIANG) {
                        if (col < row) v = 0.f;
                        __builtin_nontemporal_store(v, Cf + (size_t)row * N + col);
                    } else if (OUT_BF16) {
                        ((u16*)C_)[(size_t)row * N + col] = f2bf_u16(v);
                    } else {
                        Cf[(size_t)row * N + col] = v;
                    }
                }
            }
        }
    }
}

// aggregation: out[node] = nd[node] * sum_{e} Y[csr[e]] + bias  (Y pre-scaled by ns)
template<int F, bool RELU, bool OUT_BF16>
__device__ __forceinline__ void agg_body(const u16* __restrict__ Y, const int* __restrict__ row_ptr,
                                         const u16* __restrict__ csr, const float* __restrict__ nd,
                                         const float* __restrict__ bias, void* __restrict__ out,
                                         int node) {
    constexpr int VPL = F / 64;
    int lane = threadIdx.x & 63;
    int e0 = row_ptr[node], e1 = row_ptr[node + 1];
    float acc[VPL];
    #pragma unroll
    for (int j = 0; j < VPL; ++j) acc[j] = 0.f;
    const int off = lane * VPL;

    int e = e0;
    for (; e < e1 && (e & 7) != 0; ++e) {
        int s = csr[e];
        if (VPL == 4) {
            uint2 d = *(const uint2*)(Y + (size_t)s * F + off);
            acc[0] += bfu(d.x & 0xffffu); acc[1] += bfu(d.x >> 16);
            acc[2] += bfu(d.y & 0xffffu); acc[3] += bfu(d.y >> 16);
        } else {
            u32 d = *(const u32*)(Y + (size_t)s * F + off);
            acc[0] += bfu(d & 0xffffu); acc[1] += bfu(d >> 16);
        }
    }
    for (; e + 8 <= e1; e += 8) {
        uint4 iv = *(const uint4*)(csr + e);
        int s0 = iv.x & 0xffff, s1 = iv.x >> 16;
        int s2 = iv.y & 0xffff, s3 = iv.y >> 16;
        int s4 = iv.z & 0xffff, s5 = iv.z >> 16;
        int s6 = iv.w & 0xffff, s7 = iv.w >> 16;
        if (VPL == 4) {
            uint2 d0 = *(const uint2*)(Y + (size_t)s0 * F + off);
            uint2 d1 = *(const uint2*)(Y + (size_t)s1 * F + off);
            uint2 d2 = *(const uint2*)(Y + (size_t)s2 * F + off);
            uint2 d3 = *(const uint2*)(Y + (size_t)s3 * F + off);
            uint2 d4 = *(const uint2*)(Y + (size_t)s4 * F + off);
            uint2 d5 = *(const uint2*)(Y + (size_t)s5 * F + off);
            uint2 d6 = *(const uint2*)(Y + (size_t)s6 * F + off);
            uint2 d7 = *(const uint2*)(Y + (size_t)s7 * F + off);
            acc[0] += bfu(d0.x & 0xffffu); acc[1] += bfu(d0.x >> 16); acc[2] += bfu(d0.y & 0xffffu); acc[3] += bfu(d0.y >> 16);
            acc[0] += bfu(d1.x & 0xffffu); acc[1] += bfu(d1.x >> 16); acc[2] += bfu(d1.y & 0xffffu); acc[3] += bfu(d1.y >> 16);
            acc[0] += bfu(d2.x & 0xffffu); acc[1] += bfu(d2.x >> 16); acc[2] += bfu(d2.y & 0xffffu); acc[3] += bfu(d2.y >> 16);
            acc[0] += bfu(d3.x & 0xffffu); acc[1] += bfu(d3.x >> 16); acc[2] += bfu(d3.y & 0xffffu); acc[3] += bfu(d3.y >> 16);
            acc[0] += bfu(d4.x & 0xffffu); acc[1] += bfu(d4.x >> 16); acc[2] += bfu(d4.y & 0xffffu); acc[3] += bfu(d4.y >> 16);
            acc[0] += bfu(d5.x & 0xffffu); acc[1] += bfu(d5.x >> 16); acc[2] += bfu(d5.y & 0xffffu); acc[3] += bfu(d5.y >> 16);
            acc[0] += bfu(d6.x & 0xffffu); acc[1] += bfu(d6.x >> 16); acc[2] += bfu(d6.y & 0xffffu); acc[3] += bfu(d6.y >> 16);
            acc[0] += bfu(d7.x & 0xffffu); acc[1] += bfu(d7.x >> 16); acc[2] += bfu(d7.y & 0xffffu); acc[3] += bfu(d7.y >> 16);
        } else {
            u32 d0 = *(const u32*)(Y + (size_t)s0 * F + off);
            u32 d1 = *(const u32*)(Y + (size_t)s1 * F + off);
            u32 d2 = *(const u32*)(Y + (size_t)s2 * F + off);
            u32 d3 = *(const u32*)(Y + (size_t)s3 * F + off);
            u32 d4 = *(const u32*)(Y + (size_t)s4 * F + off);
            u32 d5 = *(const u32*)(Y + (size_t)s5 * F + off);
            u32 d6 = *(const u32*)(Y + (size_t)s6 * F + off);
            u32 d7 = *(const u32*)(Y + (size_t)s7 * F + off);
            acc[0] += bfu(d0 & 0xffffu); acc[1] += bfu(d0 >> 16);
            acc[0] += bfu(d1 & 0xffffu); acc[1] += bfu(d1 >> 16);
            acc[0] += bfu(d2 & 0xffffu); acc[1] += bfu(d2 >> 16);
            acc[0] += bfu(d3 & 0xffffu); acc[1] += bfu(d3 >> 16);
            acc[0] += bfu(d4 & 0xffffu); acc[1] += bfu(d4 >> 16);
            acc[0] += bfu(d5 & 0xffffu); acc[1] += bfu(d5 >> 16);
            acc[0] += bfu(d6 & 0xffffu); acc[1] += bfu(d6 >> 16);
            acc[0] += bfu(d7 & 0xffffu); acc[1] += bfu(d7 >> 16);
        }
    }
    for (; e < e1; ++e) {
        int s = csr[e];
        if (VPL == 4) {
            uint2 d = *(const uint2*)(Y + (size_t)s * F + off);
            acc[0] += bfu(d.x & 0xffffu); acc[1] += bfu(d.x >> 16);
            acc[2] += bfu(d.y & 0xffffu); acc[3] += bfu(d.y >> 16);
        } else {
            u32 d = *(const u32*)(Y + (size_t)s * F + off);
            acc[0] += bfu(d & 0xffffu); acc[1] += bfu(d >> 16);
        }
    }

    float ndv = nd[node];
    #pragma unroll
    for (int j = 0; j < VPL; ++j) {
        float o = acc[j] * ndv + bias[off + j];
        if (RELU) o = fmaxf(o, 0.f);
        if (OUT_BF16) ((u16*)out)[(size_t)node * F + off + j] = f2bf_u16(o);
        else ((float*)out)[(size_t)node * F + off + j] = o;
    }
}

// zero-fill one lower-triangle 128x128 tile of z, NT stores; b enumerates jt<it pairs
__device__ __forceinline__ void zfill_body(float* __restrict__ out, int b) {
    float fit = (sqrtf(8.f * b + 1.f) + 1.f) * 0.5f;
    int it = (int)fit;
    if (it * (it - 1) / 2 > b) --it;
    else if ((it + 1) * it / 2 <= b) ++it;
    int jt = b - it * (it - 1) / 2;
    int brow = it * 128, bcol = jt * 128;
    f32x4 z = {0.f, 0.f, 0.f, 0.f};
    int t = threadIdx.x;
    #pragma unroll
    for (int pq = 0; pq < 16; ++pq) {
        int idx = pq * 256 + t;
        int r = idx >> 5, c4 = idx & 31;
        __builtin_nontemporal_store(z, (f32x4*)(out + (size_t)(brow + r) * NIDX + bcol + c4 * 4));
    }
}

// ---------------- fused pipeline kernels ----------------

// F0: gemm1(e0) [G1B blocks] + scatter [SCB blocks]
__global__ __launch_bounds__(256) void f0_kernel(P p) {
    __shared__ u16 As[128 * 40];
    __shared__ u16 Bs[128 * 40];
    int bid = blockIdx.x;
    if (bid < G1B) {
        gemm_body<true, true, false, true>(p.raw0, p.W1t, p.Y1, p.norms,
                                           NN, 256, 512, bid % 391, bid / 391, As, Bs);
    } else {
        scatter_body(p, bid - G1B);
    }
}

// F1: gemm1(e1) [G1B] + agg1(e0) [AGB]
__global__ __launch_bounds__(256) void f1_kernel(P p) {
    __shared__ u16 As[128 * 40];
    __shared__ u16 Bs[128 * 40];
    int bid = blockIdx.x;
    if (bid < G1B) {
        gemm_body<true, true, false, true>(p.raw1, p.W1t + (size_t)512 * 256,
                                           p.Y1 + (size_t)NN * 256, p.norms + 2 * NN,
                                           NN, 256, 512, bid % 391, bid / 391, As, Bs);
    } else {
        int node = (bid - G1B) * 4 + (threadIdx.x >> 6);
        agg_body<256, true, true>(p.Y1, p.rp_all, p.csr_all, p.norms + NN, p.b1_0, p.H1, node);
    }
}

// F2: gemm2(e0) [G2B] + agg1(e1) [AGB]
__global__ __launch_bounds__(256) void f2_kernel(P p) {
    __shared__ u16 As[128 * 40];
    __shared__ u16 Bs[128 * 40];
    int bid = blockIdx.x;
    if (bid < G2B) {
        gemm_body<false, true, false, true>(p.H1, p.W2t, p.Y2, p.norms,
                                            NN, 128, 256, bid, 0, As, Bs);
    } else {
        int node = (bid - G2B) * 4 + (threadIdx.x >> 6);
        agg_body<256, true, true>(p.Y1 + (size_t)NN * 256, p.rp_all + (NN + 1),
                                  p.csr_all + (size_t)NE, p.norms + 3 * NN, p.b1_1,
                                  p.H1 + (size_t)NN * 256, node);
    }
}

// F3: gemm2(e1) [G2B] + agg2(e0) [AGB]
__global__ __launch_bounds__(256) void f3_kernel(P p) {
    __shared__ u16 As[128 * 40];
    __shared__ u16 Bs[128 * 40];
    int bid = blockIdx.x;
    if (bid < G2B) {
        gemm_body<false, true, false, true>(p.H1 + (size_t)NN * 256, p.W2t + (size_t)256 * 128,
                                            p.Y2 + (size_t)NN * 128, p.norms + 2 * NN,
                                            NN, 128, 256, bid, 0, As, Bs);
    } else {
        int node = (bid - G2B) * 4 + (threadIdx.x >> 6);
        agg_body<128, false, false>(p.Y2, p.rp_all, p.csr_all, p.norms + NN, p.b2_0, p.H2, node);
    }
}

// F4: agg2(e1) [AGB] + z lower-triangle fill [ZLB]
__global__ __launch_bounds__(256) void f4_kernel(P p) {
    int bid = blockIdx.x;
    if (bid < AGB) {
        int node = bid * 4 + (threadIdx.x >> 6);
        agg_body<128, false, false>(p.Y2 + (size_t)NN * 128, p.rp_all + (NN + 1),
                                    p.csr_all + (size_t)NE, p.norms + 3 * NN, p.b2_1,
                                    p.H2 + (size_t)NN * 128, node);
    } else {
        zfill_body(p.zout, bid - AGB);
    }
}

// ---------------- normalize + build R = [ (a+b)/2 , (a-b)/(2*sqrt(3)) ] ----------------

__global__ __launch_bounds__(256)
void build_r_kernel(const float* __restrict__ H2a, const float* __restrict__ H2b,
                    const int* __restrict__ index, u16* __restrict__ R) {
    int lane = threadIdx.x & 63;
    int row = blockIdx.x * 4 + (threadIdx.x >> 6);
    int g = index[row];
    float2 a = *(const float2*)(H2a + (size_t)g * 128 + lane * 2);
    float2 b = *(const float2*)(H2b + (size_t)g * 128 + lane * 2);
    float sa = a.x * a.x + a.y * a.y;
    float sb = b.x * b.x + b.y * b.y;
    #pragma unroll
    for (int d = 1; d < 64; d <<= 1) {
        sa += __shfl_xor(sa, d, 64);
        sb += __shfl_xor(sb, d, 64);
    }
    float inva = 1.f / fmaxf(sqrtf(sa), 1e-12f);
    float invb = 1.f / fmaxf(sqrtf(sb), 1e-12f);
    float ax = a.x * inva, ay = a.y * inva;
    float bx = b.x * invb, by = b.y * invb;
    const float c2 = 0.5f, c3 = 0.28867513459481287f;  // 1/(2*sqrt(3))
    u16* Rp = R + (size_t)row * 256;
    Rp[lane * 2]           = f2bf_u16((ax + bx) * c2);
    Rp[lane * 2 + 1]       = f2bf_u16((ay + by) * c2);
    Rp[128 + lane * 2]     = f2bf_u16((ax - bx) * c3);
    Rp[128 + lane * 2 + 1] = f2bf_u16((ay - by) * c3);
}

// z = triu(R @ R^T): upper-tri blocks only (lower filled in F4)
__global__ __launch_bounds__(256)
void zgemm_kernel(const u16* __restrict__ R, float* __restrict__ out) {
    int it = blockIdx.x, jt = blockIdx.y;
    if (jt < it) return;
    __shared__ u16 As[128 * 40];
    __shared__ u16 Bs[128 * 40];
    gemm_body<false, false, true, false>(R, R, out, nullptr, NIDX, NIDX, 256, it, jt, As, Bs);
}

// ---------------- launch ----------------

extern "C" void kernel_launch(void* const* d_in, const int* in_sizes, int n_in,
                              void* d_out, int out_size, void* d_ws, size_t ws_size,
                              hipStream_t stream) {
    (void)in_sizes; (void)n_in; (void)out_size; (void)ws_size;
    char* wp = (char*)d_ws;
    auto alloc = [&](size_t bytes) -> char* {
        char* r = wp;
        wp += (bytes + 255) & ~(size_t)255;
        return r;
    };
    int*   deg_all = (int*)alloc((size_t)4 * NN * 4);
    float* norms   = (float*)alloc((size_t)4 * NN * 4);
    int*   rp_all  = (int*)alloc((size_t)2 * (NN + 1) * 4);
    int*   cur_all = (int*)alloc((size_t)2 * (NN + 1) * 4);
    u16*   csr_all = (u16*)alloc((size_t)2 * NE * 2);
    u16*   W1t     = (u16*)alloc((size_t)2 * 512 * 256 * 2);
    u16*   W2t     = (u16*)alloc((size_t)2 * 256 * 128 * 2);
    u16*   Y1      = (u16*)alloc((size_t)2 * NN * 256 * 2);
    u16*   H1      = (u16*)alloc((size_t)2 * NN * 256 * 2);
    u16*   Y2      = (u16*)alloc((size_t)2 * NN * 128 * 2);
    float* H2      = (float*)alloc((size_t)2 * NN * 128 * 4);
    u16*   R       = (u16*)alloc((size_t)NIDX * 256 * 2);
    int*   partial = (int*)Y1;  // hist partials (25.6 MB) alias Y1; dead before Y1 written

    P p;
    p.raw0 = (const float*)d_in[0]; p.raw1 = (const float*)d_in[1];
    p.s1 = (const int*)d_in[2]; p.d1 = (const int*)d_in[3];
    p.s2 = (const int*)d_in[4]; p.d2 = (const int*)d_in[5];
    const int* index = (const int*)d_in[6];
    const float* W1a = (const float*)d_in[7];
    p.b1_0 = (const float*)d_in[8];
    const float* W2a = (const float*)d_in[9];
    p.b2_0 = (const float*)d_in[10];
    const float* W1b = (const float*)d_in[11];
    p.b1_1 = (const float*)d_in[12];
    const float* W2b = (const float*)d_in[13];
    p.b2_1 = (const float*)d_in[14];
    p.cur_all = cur_all; p.csr_all = csr_all; p.rp_all = rp_all;
    p.W1t = W1t; p.W2t = W2t;
    p.Y1 = Y1; p.H1 = H1; p.Y2 = Y2; p.H2 = H2;
    p.norms = norms;
    p.zout = (float*)d_out;

    convw_kernel<<<dim3((512 * 256 + 255) / 256, 4), 256, 0, stream>>>(W1a, W1b, W2a, W2b, W1t, W2t);
    hist_kernel<<<dim3(NRANGE * HCHUNK, 2), 256, 0, stream>>>(p.s1, p.d1, p.s2, p.d2, partial, NE);
    reduce_hist_kernel<<<(4 * NN + 255) / 256, 256, 0, stream>>>(partial, deg_all);
    norm_kernel<<<(4 * NN + 255) / 256, 256, 0, stream>>>(deg_all, norms, 4 * NN);
    scan_kernel<<<2, 1024, 0, stream>>>(deg_all, rp_all, cur_all, NN);

    f0_kernel<<<G1B + SCB, 256, 0, stream>>>(p);   // gemm1(e0) || scatter
    f1_kernel<<<G1B + AGB, 256, 0, stream>>>(p);   // gemm1(e1) || agg1(e0)
    f2_kernel<<<G2B + AGB, 256, 0, stream>>>(p);   // gemm2(e0) || agg1(e1)
    f3_kernel<<<G2B + AGB, 256, 0, stream>>>(p);   // gemm2(e1) || agg2(e0)
    f4_kernel<<<AGB + ZLB, 256, 0, stream>>>(p);   // agg2(e1) || z lower fill

    build_r_kernel<<<NIDX / 4, 256, 0, stream>>>(H2, H2 + (size_t)NN * 128, index, R);
    zgemm_kernel<<<dim3(64, 64), 256, 0, stream>>>(R, (float*)d_out);
}

// Round 7
// 849.322 us; speedup vs baseline: 1.1522x; 1.1522x over previous
//
#include <hip/hip_runtime.h>
#include <hip/hip_bf16.h>

using u16 = unsigned short;
using u32 = unsigned int;

typedef __attribute__((ext_vector_type(8))) short short8;
typedef __attribute__((ext_vector_type(4))) float f32x4;

__device__ __forceinline__ u16 f2bf_u16(float f) {
    __hip_bfloat16 h = __float2bfloat16(f);
    return __builtin_bit_cast(u16, h);
}
__device__ __forceinline__ float bfu(u32 u) { return __uint_as_float(u << 16); }

static constexpr int NN = 50000;
static constexpr int NE = 1600000;
static constexpr int NIDX = 8192;
static constexpr int NRANGE = 8;              // src ranges AND scatter dst-ranges (XCD pinning)
static constexpr int RN = NN / NRANGE;        // 6250 nodes per range
static constexpr int HCH = 64;                // hist edge-chunks (25000 edges each)
static constexpr int NK = NN * NRANGE;        // 400000 (dst,range) keys per enc
static constexpr int SAB = (NK + 4095) / 4096;  // 98 scanA blocks per enc

// deg_all / norms layout: [enc*2+0]=out(src), [enc*2+1]=in(dst), each NN.
// rp2/cursor2: per enc, 400001 / 400000 ints; key = dst*8 + src_range.

// ---------------- hist: per-(dst,src-range) counts + src out-degree, LDS only ----------------
// grid.x = NRANGE * HCH (stripe = x&7, chunk = x>>3), grid.y = enc.
// h2: byte-packed counts (4 per u32) for (dstLocal*8+r); ho: halfword-packed src counts.
// Byte counters safe: per chunk (25000 edges) expected count per (dst,r) ~0.0625, never near 255.

__global__ __launch_bounds__(256)
void hist_kernel(const int* __restrict__ s1, const int* __restrict__ d1,
                 const int* __restrict__ s2, const int* __restrict__ d2,
                 u32* __restrict__ partial2, u32* __restrict__ partial_out) {
    __shared__ u32 h2[RN * 2];    // 12500 words = RN*8 bytes
    __shared__ u32 ho[RN / 2];    // 3125 words = RN halfwords
    int enc = blockIdx.y;
    int stripe = blockIdx.x & (NRANGE - 1);
    int chunk = blockIdx.x >> 3;
    const int* s = enc ? s2 : s1;
    const int* d = enc ? d2 : d1;
    int lo = stripe * RN;
    for (int i = threadIdx.x; i < RN * 2; i += 256) h2[i] = 0;
    for (int i = threadIdx.x; i < RN / 2; i += 256) ho[i] = 0;
    __syncthreads();
    int per_chunk = NE / HCH;  // 25000
    int e0 = chunk * per_chunk, e1 = e0 + per_chunk;
    for (int e = e0 + threadIdx.x * 4; e < e1; e += 256 * 4) {
        int4 sv = *(const int4*)(s + e);
        int4 dv = *(const int4*)(d + e);
        #pragma unroll
        for (int j = 0; j < 4; ++j) {
            int src = j == 0 ? sv.x : j == 1 ? sv.y : j == 2 ? sv.z : sv.w;
            int dst = j == 0 ? dv.x : j == 1 ? dv.y : j == 2 ? dv.z : dv.w;
            u32 sl = (u32)(src - lo);
            if (sl < (u32)RN) atomicAdd(&ho[sl >> 1], 1u << ((sl & 1) * 16));
            u32 dl = (u32)(dst - lo);
            if (dl < (u32)RN) {
                u32 idx = dl * 8 + (u32)(src / RN);
                atomicAdd(&h2[idx >> 2], 1u << ((idx & 3) * 8));
            }
        }
    }
    __syncthreads();
    u32* p2 = partial2 + ((size_t)enc * HCH + chunk) * (NN * 2) + stripe * (RN * 2);
    for (int i = threadIdx.x; i < RN * 2; i += 256) p2[i] = h2[i];
    u32* po = partial_out + ((size_t)enc * HCH + chunk) * (NN / 2) + stripe * (RN / 2);
    for (int i = threadIdx.x; i < RN / 2; i += 256) po[i] = ho[i];
}

// one thread per (enc, node): sum byte/halfword partials over chunks
__global__ void reduce_hist_kernel(const u32* __restrict__ partial2,
                                   const u32* __restrict__ partial_out,
                                   int* __restrict__ deg2, int* __restrict__ deg_all) {
    int i = blockIdx.x * blockDim.x + threadIdx.x;
    if (i >= 2 * NN) return;
    int enc = i / NN;
    int dst = i - enc * NN;
    int cnt[8];
    #pragma unroll
    for (int r = 0; r < 8; ++r) cnt[r] = 0;
    for (int c = 0; c < HCH; ++c) {
        const u32* p = partial2 + ((size_t)enc * HCH + c) * (NN * 2) + dst * 2;
        u32 w0 = p[0], w1 = p[1];
        cnt[0] += w0 & 0xff; cnt[1] += (w0 >> 8) & 0xff; cnt[2] += (w0 >> 16) & 0xff; cnt[3] += w0 >> 24;
        cnt[4] += w1 & 0xff; cnt[5] += (w1 >> 8) & 0xff; cnt[6] += (w1 >> 16) & 0xff; cnt[7] += w1 >> 24;
    }
    int* dp = deg2 + (size_t)enc * NK + dst * 8;
    int din = 0;
    #pragma unroll
    for (int r = 0; r < 8; ++r) { dp[r] = cnt[r]; din += cnt[r]; }
    deg_all[(enc * 2 + 1) * NN + dst] = din;
    int dout = 0;
    for (int c = 0; c < HCH; ++c) {
        u32 w = partial_out[((size_t)enc * HCH + c) * (NN / 2) + (dst >> 1)];
        dout += (w >> ((dst & 1) * 16)) & 0xffff;
    }
    deg_all[(enc * 2 + 0) * NN + dst] = dout;
}

__global__ void norm_kernel(const int* __restrict__ deg_all, float* __restrict__ norms, int n4) {
    int i = blockIdx.x * blockDim.x + threadIdx.x;
    if (i < n4) norms[i] = rsqrtf(fmaxf((float)deg_all[i], 1.f));
}

// ---------------- 3-phase scan over deg2 (400000 per enc) ----------------

__global__ __launch_bounds__(1024)
void scanA_kernel(const int* __restrict__ deg2, int* __restrict__ rp2_all, int* __restrict__ tot) {
    int enc = blockIdx.y;
    const int* deg = deg2 + (size_t)enc * NK;
    int* rp = rp2_all + (size_t)enc * (NK + 1);
    __shared__ int wsum[16];
    int t = threadIdx.x, lane = t & 63, wid = t >> 6;
    int i0 = blockIdx.x * 4096 + t * 4;
    int4 v = make_int4(0, 0, 0, 0);
    bool in = (i0 + 3 < NK);
    if (in) v = *(const int4*)(deg + i0);
    int s = v.x + v.y + v.z + v.w;
    int x = s;
    #pragma unroll
    for (int d = 1; d < 64; d <<= 1) {
        int y = __shfl_up(x, d, 64);
        if (lane >= d) x += y;
    }
    if (lane == 63) wsum[wid] = x;
    __syncthreads();
    if (t == 0) {
        int run = 0;
        #pragma unroll
        for (int w = 0; w < 16; ++w) { int q = wsum[w]; wsum[w] = run; run += q; }
        tot[enc * SAB + blockIdx.x] = run;
    }
    __syncthreads();
    if (in) {
        int excl = wsum[wid] + x - s;
        rp[i0] = excl;
        rp[i0 + 1] = excl + v.x;
        rp[i0 + 2] = excl + v.x + v.y;
        rp[i0 + 3] = excl + v.x + v.y + v.z;
    }
}

__global__ void scanB_kernel(int* __restrict__ tot) {
    int enc = threadIdx.x;
    if (enc < 2) {
        int run = 0;
        for (int b = 0; b < SAB; ++b) { int q = tot[enc * SAB + b]; tot[enc * SAB + b] = run; run += q; }
    }
}

__global__ __launch_bounds__(256)
void scanC_kernel(int* __restrict__ rp2_all, int* __restrict__ cur2_all, const int* __restrict__ tot) {
    int enc = blockIdx.y;
    int* rp = rp2_all + (size_t)enc * (NK + 1);
    int* cur = cur2_all + (size_t)enc * NK;
    int idx = (blockIdx.x * 256 + threadIdx.x) * 4;
    if (idx < NK) {
        int off = tot[enc * SAB + (idx >> 12)];
        int4 v = *(const int4*)(rp + idx);
        v.x += off; v.y += off; v.z += off; v.w += off;
        *(int4*)(rp + idx) = v;
        *(int4*)(cur + idx) = v;
    }
    if (blockIdx.x == 0 && threadIdx.x == 0) rp[NK] = NE;
}

// ---------------- scatter: XCD-pinned by dst-range, key = dst*8 + src_range ----------------

__global__ __launch_bounds__(256)
void scatter_kernel(const int* __restrict__ s1, const int* __restrict__ d1,
                    const int* __restrict__ s2, const int* __restrict__ d2,
                    int* __restrict__ cur2_all, u16* __restrict__ csr_all) {
    int range = blockIdx.x & (NRANGE - 1);
    int lo = range * RN, hi = lo + RN;
    int chunk = blockIdx.x >> 3;
    int e = chunk * 1024 + threadIdx.x * 4;
    const int* s = s1; const int* d = d1; int enc = 0;
    if (e >= NE) { e -= NE; s = s2; d = d2; enc = 1; }
    if (e >= NE) return;
    int4 dv = *(const int4*)(d + e);
    bool any = (dv.x >= lo && dv.x < hi) || (dv.y >= lo && dv.y < hi) ||
               (dv.z >= lo && dv.z < hi) || (dv.w >= lo && dv.w < hi);
    if (!any) return;
    int4 sv = *(const int4*)(s + e);
    int* cursor = cur2_all + (size_t)enc * NK;
    u16* csr = csr_all + (size_t)enc * NE;
    #pragma unroll
    for (int j = 0; j < 4; ++j) {
        int dst = j == 0 ? dv.x : j == 1 ? dv.y : j == 2 ? dv.z : dv.w;
        int src = j == 0 ? sv.x : j == 1 ? sv.y : j == 2 ? sv.z : sv.w;
        if (dst >= lo && dst < hi) {
            int key = dst * 8 + src / RN;
            int pos = atomicAdd(&cursor[key], 1);
            csr[pos] = (u16)src;
        }
    }
}

// all four weight matrices: blockIdx.y = {W1a, W1b, W2a, W2b};  W [K][N] f32 -> Wt [N][K] bf16
__global__ void convw_kernel(const float* __restrict__ W1a, const float* __restrict__ W1b,
                             const float* __restrict__ W2a, const float* __restrict__ W2b,
                             u16* __restrict__ W1t_all, u16* __restrict__ W2t_all) {
    int mat = blockIdx.y;
    int idx = blockIdx.x * blockDim.x + threadIdx.x;
    const float* W; u16* Wt; int K, N;
    if (mat < 2) { W = mat ? W1b : W1a; Wt = W1t_all + (size_t)mat * 512 * 256; K = 512; N = 256; }
    else         { W = (mat == 3) ? W2b : W2a; Wt = W2t_all + (size_t)(mat - 2) * 256 * 128; K = 256; N = 128; }
    if (idx < K * N) {
        int k = idx / N, n = idx - k * N;
        Wt[(size_t)n * K + k] = f2bf_u16(W[idx]);
    }
}

// ---------------- MFMA GEMM: C = A @ Bt^T (dual-encoder via blockIdx.z) ----------------

template<bool A_F32, bool OUT_BF16, bool TRIANG, bool SCALE>
__global__ __launch_bounds__(256)
void gemm_kernel(const void* __restrict__ A0_, const void* __restrict__ A1_,
                 const u16* __restrict__ Bt0, const u16* __restrict__ Bt1,
                 void* __restrict__ C0_, void* __restrict__ C1_,
                 const float* __restrict__ rs0, const float* __restrict__ rs1,
                 int M, int N, int K) {
    int enc = blockIdx.z;
    const void* A_ = enc ? A1_ : A0_;
    const u16* Bt = enc ? Bt1 : Bt0;
    void* C_ = enc ? C1_ : C0_;
    const float* rowscale = enc ? rs1 : rs0;

    int it = blockIdx.x, jt = blockIdx.y;
    int t = threadIdx.x;
    int brow = it * 128, bcol = jt * 128;
    float* Cf = (float*)C_;
    if (TRIANG && jt < it) {
        f32x4 z = {0.f, 0.f, 0.f, 0.f};
        #pragma unroll
        for (int p = 0; p < 16; ++p) {
            int idx = p * 256 + t;
            int r = idx >> 5, c4 = idx & 31;
            __builtin_nontemporal_store(z, (f32x4*)(Cf + (size_t)(brow + r) * N + bcol + c4 * 4));
        }
        return;
    }
    __shared__ u16 As[128 * 40];
    __shared__ u16 Bs[128 * 40];
    int lane = t & 63, wv = t >> 6;
    int wr = wv >> 1, wc = wv & 1;
    f32x4 acc[4][4];
    #pragma unroll
    for (int m = 0; m < 4; ++m)
        #pragma unroll
        for (int n = 0; n < 4; ++n) acc[m][n] = f32x4{0.f, 0.f, 0.f, 0.f};

    for (int k0 = 0; k0 < K; k0 += 32) {
        if (A_F32) {
            const float* A = (const float*)A_;
            #pragma unroll
            for (int p = 0; p < 4; ++p) {
                int r = p * 32 + (t >> 3), c = (t & 7) * 4;
                int gr = brow + r;
                float4 v = make_float4(0.f, 0.f, 0.f, 0.f);
                if (gr < M) v = *(const float4*)(A + (size_t)gr * K + k0 + c);
                u32 lo = (u32)f2bf_u16(v.x) | ((u32)f2bf_u16(v.y) << 16);
                u32 hi = (u32)f2bf_u16(v.z) | ((u32)f2bf_u16(v.w) << 16);
                *(uint2*)&As[r * 40 + c] = make_uint2(lo, hi);
            }
        } else {
            const u16* A = (const u16*)A_;
            #pragma unroll
            for (int p = 0; p < 2; ++p) {
                int r = p * 64 + (t >> 2), c = (t & 3) * 8;
                int gr = brow + r;
                uint4 v = make_uint4(0u, 0u, 0u, 0u);
                if (gr < M) v = *(const uint4*)(A + (size_t)gr * K + k0 + c);
                *(uint4*)&As[r * 40 + c] = v;
            }
        }
        #pragma unroll
        for (int p = 0; p < 2; ++p) {
            int r = p * 64 + (t >> 2), c = (t & 3) * 8;
            int gn = bcol + r;
            uint4 v = make_uint4(0u, 0u, 0u, 0u);
            if (gn < N) v = *(const uint4*)(Bt + (size_t)gn * K + k0 + c);
            *(uint4*)&Bs[r * 40 + c] = v;
        }
        __syncthreads();
        int kg = (lane >> 4) * 8;
        short8 av[4], bv[4];
        #pragma unroll
        for (int m = 0; m < 4; ++m)
            av[m] = *(const short8*)&As[(wr * 64 + m * 16 + (lane & 15)) * 40 + kg];
        #pragma unroll
        for (int n = 0; n < 4; ++n)
            bv[n] = *(const short8*)&Bs[(wc * 64 + n * 16 + (lane & 15)) * 40 + kg];
        #pragma unroll
        for (int m = 0; m < 4; ++m)
            #pragma unroll
            for (int n = 0; n < 4; ++n)
                acc[m][n] = __builtin_amdgcn_mfma_f32_16x16x32_bf16(av[m], bv[n], acc[m][n], 0, 0, 0);
        __syncthreads();
    }
    #pragma unroll
    for (int m = 0; m < 4; ++m) {
        #pragma unroll
        for (int n = 0; n < 4; ++n) {
            #pragma unroll
            for (int r = 0; r < 4; ++r) {
                int row = brow + wr * 64 + m * 16 + (lane >> 4) * 4 + r;
                int col = bcol + wc * 64 + n * 16 + (lane & 15);
                if (row < M && col < N) {
                    float v = acc[m][n][r];
                    if (SCALE) v *= rowscale[row];
                    if (TRIANG) {
                        if (col < row) v = 0.f;
                        __builtin_nontemporal_store(v, Cf + (size_t)row * N + col);
                    } else if (OUT_BF16) {
                        ((u16*)C_)[(size_t)row * N + col] = f2bf_u16(v);
                    } else {
                        Cf[(size_t)row * N + col] = v;
                    }
                }
            }
        }
    }
}

// ---------------- aggregation (single enc): out[d] = nd[d]*sum Y[csr[e]] + b ----------------
// csr rows are sorted by src-range (layout property) -> L2-phase-aligned gather.

template<int F, bool RELU, bool OUT_BF16>
__global__ __launch_bounds__(256)
void agg_kernel(const u16* __restrict__ Y, const int* __restrict__ rp2,
                const u16* __restrict__ csr, const float* __restrict__ nd,
                const float* __restrict__ bias, void* __restrict__ out) {
    constexpr int VPL = F / 64;
    int lane = threadIdx.x & 63;
    int node = blockIdx.x * 4 + (threadIdx.x >> 6);
    if (node >= NN) return;
    int e0 = rp2[node * 8], e1 = rp2[node * 8 + 8];
    float acc[VPL];
    #pragma unroll
    for (int j = 0; j < VPL; ++j) acc[j] = 0.f;
    const int off = lane * VPL;

    int e = e0;
    for (; e < e1 && (e & 7) != 0; ++e) {
        int s = csr[e];
        if (VPL == 4) {
            uint2 d = *(const uint2*)(Y + (size_t)s * F + off);
            acc[0] += bfu(d.x & 0xffffu); acc[1] += bfu(d.x >> 16);
            acc[2] += bfu(d.y & 0xffffu); acc[3] += bfu(d.y >> 16);
        } else {
            u32 d = *(const u32*)(Y + (size_t)s * F + off);
            acc[0] += bfu(d & 0xffffu); acc[1] += bfu(d >> 16);
        }
    }
    for (; e + 8 <= e1; e += 8) {
        uint4 iv = *(const uint4*)(csr + e);
        int s0 = iv.x & 0xffff, s1 = iv.x >> 16;
        int s2 = iv.y & 0xffff, s3 = iv.y >> 16;
        int s4 = iv.z & 0xffff, s5 = iv.z >> 16;
        int s6 = iv.w & 0xffff, s7 = iv.w >> 16;
        if (VPL == 4) {
            uint2 d0 = *(const uint2*)(Y + (size_t)s0 * F + off);
            uint2 d1 = *(const uint2*)(Y + (size_t)s1 * F + off);
            uint2 d2 = *(const uint2*)(Y + (size_t)s2 * F + off);
            uint2 d3 = *(const uint2*)(Y + (size_t)s3 * F + off);
            uint2 d4 = *(const uint2*)(Y + (size_t)s4 * F + off);
            uint2 d5 = *(const uint2*)(Y + (size_t)s5 * F + off);
            uint2 d6 = *(const uint2*)(Y + (size_t)s6 * F + off);
            uint2 d7 = *(const uint2*)(Y + (size_t)s7 * F + off);
            acc[0] += bfu(d0.x & 0xffffu); acc[1] += bfu(d0.x >> 16); acc[2] += bfu(d0.y & 0xffffu); acc[3] += bfu(d0.y >> 16);
            acc[0] += bfu(d1.x & 0xffffu); acc[1] += bfu(d1.x >> 16); acc[2] += bfu(d1.y & 0xffffu); acc[3] += bfu(d1.y >> 16);
            acc[0] += bfu(d2.x & 0xffffu); acc[1] += bfu(d2.x >> 16); acc[2] += bfu(d2.y & 0xffffu); acc[3] += bfu(d2.y >> 16);
            acc[0] += bfu(d3.x & 0xffffu); acc[1] += bfu(d3.x >> 16); acc[2] += bfu(d3.y & 0xffffu); acc[3] += bfu(d3.y >> 16);
            acc[0] += bfu(d4.x & 0xffffu); acc[1] += bfu(d4.x >> 16); acc[2] += bfu(d4.y & 0xffffu); acc[3] += bfu(d4.y >> 16);
            acc[0] += bfu(d5.x & 0xffffu); acc[1] += bfu(d5.x >> 16); acc[2] += bfu(d5.y & 0xffffu); acc[3] += bfu(d5.y >> 16);
            acc[0] += bfu(d6.x & 0xffffu); acc[1] += bfu(d6.x >> 16); acc[2] += bfu(d6.y & 0xffffu); acc[3] += bfu(d6.y >> 16);
            acc[0] += bfu(d7.x & 0xffffu); acc[1] += bfu(d7.x >> 16); acc[2] += bfu(d7.y & 0xffffu); acc[3] += bfu(d7.y >> 16);
        } else {
            u32 d0 = *(const u32*)(Y + (size_t)s0 * F + off);
            u32 d1 = *(const u32*)(Y + (size_t)s1 * F + off);
            u32 d2 = *(const u32*)(Y + (size_t)s2 * F + off);
            u32 d3 = *(const u32*)(Y + (size_t)s3 * F + off);
            u32 d4 = *(const u32*)(Y + (size_t)s4 * F + off);
            u32 d5 = *(const u32*)(Y + (size_t)s5 * F + off);
            u32 d6 = *(const u32*)(Y + (size_t)s6 * F + off);
            u32 d7 = *(const u32*)(Y + (size_t)s7 * F + off);
            acc[0] += bfu(d0 & 0xffffu); acc[1] += bfu(d0 >> 16);
            acc[0] += bfu(d1 & 0xffffu); acc[1] += bfu(d1 >> 16);
            acc[0] += bfu(d2 & 0xffffu); acc[1] += bfu(d2 >> 16);
            acc[0] += bfu(d3 & 0xffffu); acc[1] += bfu(d3 >> 16);
            acc[0] += bfu(d4 & 0xffffu); acc[1] += bfu(d4 >> 16);
            acc[0] += bfu(d5 & 0xffffu); acc[1] += bfu(d5 >> 16);
            acc[0] += bfu(d6 & 0xffffu); acc[1] += bfu(d6 >> 16);
            acc[0] += bfu(d7 & 0xffffu); acc[1] += bfu(d7 >> 16);
        }
    }
    for (; e < e1; ++e) {
        int s = csr[e];
        if (VPL == 4) {
            uint2 d = *(const uint2*)(Y + (size_t)s * F + off);
            acc[0] += bfu(d.x & 0xffffu); acc[1] += bfu(d.x >> 16);
            acc[2] += bfu(d.y & 0xffffu); acc[3] += bfu(d.y >> 16);
        } else {
            u32 d = *(const u32*)(Y + (size_t)s * F + off);
            acc[0] += bfu(d & 0xffffu); acc[1] += bfu(d >> 16);
        }
    }

    float ndv = nd[node];
    #pragma unroll
    for (int j = 0; j < VPL; ++j) {
        float o = acc[j] * ndv + bias[off + j];
        if (RELU) o = fmaxf(o, 0.f);
        if (OUT_BF16) ((u16*)out)[(size_t)node * F + off + j] = f2bf_u16(o);
        else ((float*)out)[(size_t)node * F + off + j] = o;
    }
}

// ---------------- normalize + build R = [ (a+b)/2 , (a-b)/(2*sqrt(3)) ] ----------------

__global__ __launch_bounds__(256)
void build_r_kernel(const float* __restrict__ H2a, const float* __restrict__ H2b,
                    const int* __restrict__ index, u16* __restrict__ R) {
    int lane = threadIdx.x & 63;
    int row = blockIdx.x * 4 + (threadIdx.x >> 6);
    int g = index[row];
    float2 a = *(const float2*)(H2a + (size_t)g * 128 + lane * 2);
    float2 b = *(const float2*)(H2b + (size_t)g * 128 + lane * 2);
    float sa = a.x * a.x + a.y * a.y;
    float sb = b.x * b.x + b.y * b.y;
    #pragma unroll
    for (int d = 1; d < 64; d <<= 1) {
        sa += __shfl_xor(sa, d, 64);
        sb += __shfl_xor(sb, d, 64);
    }
    float inva = 1.f / fmaxf(sqrtf(sa), 1e-12f);
    float invb = 1.f / fmaxf(sqrtf(sb), 1e-12f);
    float ax = a.x * inva, ay = a.y * inva;
    float bx = b.x * invb, by = b.y * invb;
    const float c2 = 0.5f, c3 = 0.28867513459481287f;  // 1/(2*sqrt(3))
    u16* Rp = R + (size_t)row * 256;
    Rp[lane * 2]           = f2bf_u16((ax + bx) * c2);
    Rp[lane * 2 + 1]       = f2bf_u16((ay + by) * c2);
    Rp[128 + lane * 2]     = f2bf_u16((ax - bx) * c3);
    Rp[128 + lane * 2 + 1] = f2bf_u16((ay - by) * c3);
}

// ---------------- launch ----------------

extern "C" void kernel_launch(void* const* d_in, const int* in_sizes, int n_in,
                              void* d_out, int out_size, void* d_ws, size_t ws_size,
                              hipStream_t stream) {
    (void)in_sizes; (void)n_in; (void)out_size; (void)ws_size;
    const float* raw0 = (const float*)d_in[0];
    const float* raw1 = (const float*)d_in[1];
    const int* src1 = (const int*)d_in[2], *dst1 = (const int*)d_in[3];
    const int* src2 = (const int*)d_in[4], *dst2 = (const int*)d_in[5];
    const int* index = (const int*)d_in[6];
    const float* W1a = (const float*)d_in[7];  const float* b1a = (const float*)d_in[8];
    const float* W2a = (const float*)d_in[9];  const float* b2a = (const float*)d_in[10];
    const float* W1b = (const float*)d_in[11]; const float* b1b = (const float*)d_in[12];
    const float* W2b = (const float*)d_in[13]; const float* b2b = (const float*)d_in[14];

    char* wp = (char*)d_ws;
    auto alloc = [&](size_t bytes) -> char* {
        char* r = wp;
        wp += (bytes + 255) & ~(size_t)255;
        return r;
    };
    int*   deg_all = (int*)alloc((size_t)4 * NN * 4);
    float* norms   = (float*)alloc((size_t)4 * NN * 4);
    int*   deg2    = (int*)alloc((size_t)2 * NK * 4);
    int*   rp2     = (int*)alloc((size_t)2 * (NK + 1) * 4);
    int*   cur2    = (int*)alloc((size_t)2 * NK * 4);
    int*   tot     = (int*)alloc((size_t)2 * SAB * 4);
    u16*   csr_all = (u16*)alloc((size_t)2 * NE * 2);
    u16*   W1t     = (u16*)alloc((size_t)2 * 512 * 256 * 2);
    u16*   W2t     = (u16*)alloc((size_t)2 * 256 * 128 * 2);
    u16*   Y1      = (u16*)alloc((size_t)2 * NN * 256 * 2);
    u16*   H1      = (u16*)alloc((size_t)2 * NN * 256 * 2);
    u16*   Y2      = (u16*)alloc((size_t)2 * NN * 128 * 2);
    float* H2      = (float*)alloc((size_t)2 * NN * 128 * 4);
    u16*   R       = (u16*)alloc((size_t)NIDX * 256 * 2);
    // hist partials alias Y1 (51.2MB) and H1 (51.2MB): dead until gemm1/agg1.
    u32* partial2   = (u32*)Y1;   // 2*64*100000*4 = 51.2 MB
    u32* partial_out = (u32*)H1;  // 2*64*25000*4 = 12.8 MB

    const int MT = (NN + 127) / 128;  // 391 row tiles

    convw_kernel<<<dim3((512 * 256 + 255) / 256, 4), 256, 0, stream>>>(W1a, W1b, W2a, W2b, W1t, W2t);
    hist_kernel<<<dim3(NRANGE * HCH, 2), 256, 0, stream>>>(src1, dst1, src2, dst2, partial2, partial_out);
    reduce_hist_kernel<<<(2 * NN + 255) / 256, 256, 0, stream>>>(partial2, partial_out, deg2, deg_all);
    norm_kernel<<<(4 * NN + 255) / 256, 256, 0, stream>>>(deg_all, norms, 4 * NN);
    scanA_kernel<<<dim3(SAB, 2), 1024, 0, stream>>>(deg2, rp2, tot);
    scanB_kernel<<<1, 64, 0, stream>>>(tot);
    scanC_kernel<<<dim3((NK / 4 + 255) / 256, 2), 256, 0, stream>>>(rp2, cur2, tot);
    scatter_kernel<<<(2 * NE / 1024) * NRANGE, 256, 0, stream>>>(src1, dst1, src2, dst2, cur2, csr_all);

    // Y1 = (raw @ W1) * ns[row]   (both encoders)
    gemm_kernel<true, true, false, true><<<dim3(MT, 2, 2), 256, 0, stream>>>(
        raw0, raw1, W1t, W1t + (size_t)512 * 256, Y1, Y1 + (size_t)NN * 256,
        norms, norms + (size_t)2 * NN, NN, 256, 512);
    // H1 = relu(nd * agg(Y1) + b1), bf16 — per-enc sequential (L2 slice residency)
    agg_kernel<256, true, true><<<(NN + 3) / 4, 256, 0, stream>>>(
        Y1, rp2, csr_all, norms + NN, b1a, H1);
    agg_kernel<256, true, true><<<(NN + 3) / 4, 256, 0, stream>>>(
        Y1 + (size_t)NN * 256, rp2 + (NK + 1), csr_all + (size_t)NE, norms + 3 * NN, b1b,
        H1 + (size_t)NN * 256);
    // Y2 = (H1 @ W2) * ns[row]
    gemm_kernel<false, true, false, true><<<dim3(MT, 1, 2), 256, 0, stream>>>(
        H1, H1 + (size_t)NN * 256, W2t, W2t + (size_t)256 * 128, Y2, Y2 + (size_t)NN * 128,
        norms, norms + (size_t)2 * NN, NN, 128, 256);
    // H2 = nd * agg(Y2) + b2, f32
    agg_kernel<128, false, false><<<(NN + 3) / 4, 256, 0, stream>>>(
        Y2, rp2, csr_all, norms + NN, b2a, H2);
    agg_kernel<128, false, false><<<(NN + 3) / 4, 256, 0, stream>>>(
        Y2 + (size_t)NN * 128, rp2 + (NK + 1), csr_all + (size_t)NE, norms + 3 * NN, b2b,
        H2 + (size_t)NN * 128);

    // R = [ (c1n+c2n)/2 , (c1n-c2n)/(2*sqrt(3)) ]  (8192 x 256, bf16)
    build_r_kernel<<<NIDX / 4, 256, 0, stream>>>(H2, H2 + (size_t)NN * 128, index, R);
    // z = triu(R @ R^T), nontemporal f32 output (lower tiles zero-filled in-kernel)
    gemm_kernel<false, false, true, false><<<dim3(64, 64, 1), 256, 0, stream>>>(
        R, R, R, R, (float*)d_out, (float*)d_out, nullptr, nullptr, NIDX, NIDX, 256);
}

// Round 8
// 802.229 us; speedup vs baseline: 1.2199x; 1.0587x over previous
//
#include <hip/hip_runtime.h>
#include <hip/hip_bf16.h>

using u16 = unsigned short;
using u32 = unsigned int;

typedef __attribute__((ext_vector_type(8))) short short8;
typedef __attribute__((ext_vector_type(4))) float f32x4;

__device__ __forceinline__ u16 f2bf_u16(float f) {
    __hip_bfloat16 h = __float2bfloat16(f);
    return __builtin_bit_cast(u16, h);
}
__device__ __forceinline__ float bfu(u32 u) { return __uint_as_float(u << 16); }

static constexpr int NN = 50000;
static constexpr int NE = 1600000;
static constexpr int NIDX = 8192;
static constexpr int NRANGE = 8;              // src ranges AND scatter dst-ranges (XCD pinning)
static constexpr int RN = NN / NRANGE;        // 6250 nodes per range
static constexpr int HCH = 64;                // hist edge-chunks (25000 edges each)
static constexpr int NK = NN * NRANGE;        // 400000 (dst,range) keys per enc
static constexpr int SAB = (NK + 4095) / 4096;  // 98 scanA blocks per enc

// ---------------- hist: per-(dst,src-range) counts + src out-degree, LDS only ----------------

__global__ __launch_bounds__(256)
void hist_kernel(const int* __restrict__ s1, const int* __restrict__ d1,
                 const int* __restrict__ s2, const int* __restrict__ d2,
                 u32* __restrict__ partial2, u32* __restrict__ partial_out) {
    __shared__ u32 h2[RN * 2];    // byte-packed (dstLocal*8+r) counts
    __shared__ u32 ho[RN / 2];    // halfword-packed src out-counts
    int enc = blockIdx.y;
    int stripe = blockIdx.x & (NRANGE - 1);
    int chunk = blockIdx.x >> 3;
    const int* s = enc ? s2 : s1;
    const int* d = enc ? d2 : d1;
    int lo = stripe * RN;
    for (int i = threadIdx.x; i < RN * 2; i += 256) h2[i] = 0;
    for (int i = threadIdx.x; i < RN / 2; i += 256) ho[i] = 0;
    __syncthreads();
    int per_chunk = NE / HCH;  // 25000
    int e0 = chunk * per_chunk, e1 = e0 + per_chunk;
    for (int e = e0 + threadIdx.x * 4; e < e1; e += 256 * 4) {
        int4 sv = *(const int4*)(s + e);
        int4 dv = *(const int4*)(d + e);
        #pragma unroll
        for (int j = 0; j < 4; ++j) {
            int src = j == 0 ? sv.x : j == 1 ? sv.y : j == 2 ? sv.z : sv.w;
            int dst = j == 0 ? dv.x : j == 1 ? dv.y : j == 2 ? dv.z : dv.w;
            u32 sl = (u32)(src - lo);
            if (sl < (u32)RN) atomicAdd(&ho[sl >> 1], 1u << ((sl & 1) * 16));
            u32 dl = (u32)(dst - lo);
            if (dl < (u32)RN) {
                u32 idx = dl * 8 + (u32)(src / RN);
                atomicAdd(&h2[idx >> 2], 1u << ((idx & 3) * 8));
            }
        }
    }
    __syncthreads();
    u32* p2 = partial2 + ((size_t)enc * HCH + chunk) * (NN * 2) + stripe * (RN * 2);
    for (int i = threadIdx.x; i < RN * 2; i += 256) p2[i] = h2[i];
    u32* po = partial_out + ((size_t)enc * HCH + chunk) * (NN / 2) + stripe * (RN / 2);
    for (int i = threadIdx.x; i < RN / 2; i += 256) po[i] = ho[i];
}

__global__ void reduce_hist_kernel(const u32* __restrict__ partial2,
                                   const u32* __restrict__ partial_out,
                                   int* __restrict__ deg2, int* __restrict__ deg_all) {
    int i = blockIdx.x * blockDim.x + threadIdx.x;
    if (i >= 2 * NN) return;
    int enc = i / NN;
    int dst = i - enc * NN;
    int cnt[8];
    #pragma unroll
    for (int r = 0; r < 8; ++r) cnt[r] = 0;
    for (int c = 0; c < HCH; ++c) {
        const u32* p = partial2 + ((size_t)enc * HCH + c) * (NN * 2) + dst * 2;
        u32 w0 = p[0], w1 = p[1];
        cnt[0] += w0 & 0xff; cnt[1] += (w0 >> 8) & 0xff; cnt[2] += (w0 >> 16) & 0xff; cnt[3] += w0 >> 24;
        cnt[4] += w1 & 0xff; cnt[5] += (w1 >> 8) & 0xff; cnt[6] += (w1 >> 16) & 0xff; cnt[7] += w1 >> 24;
    }
    int* dp = deg2 + (size_t)enc * NK + dst * 8;
    int din = 0;
    #pragma unroll
    for (int r = 0; r < 8; ++r) { dp[r] = cnt[r]; din += cnt[r]; }
    deg_all[(enc * 2 + 1) * NN + dst] = din;
    int dout = 0;
    for (int c = 0; c < HCH; ++c) {
        u32 w = partial_out[((size_t)enc * HCH + c) * (NN / 2) + (dst >> 1)];
        dout += (w >> ((dst & 1) * 16)) & 0xffff;
    }
    deg_all[(enc * 2 + 0) * NN + dst] = dout;
}

__global__ void norm_kernel(const int* __restrict__ deg_all, float* __restrict__ norms, int n4) {
    int i = blockIdx.x * blockDim.x + threadIdx.x;
    if (i < n4) norms[i] = rsqrtf(fmaxf((float)deg_all[i], 1.f));
}

// ---------------- 3-phase scan over deg2 (400000 per enc) ----------------

__global__ __launch_bounds__(1024)
void scanA_kernel(const int* __restrict__ deg2, int* __restrict__ rp2_all, int* __restrict__ tot) {
    int enc = blockIdx.y;
    const int* deg = deg2 + (size_t)enc * NK;
    int* rp = rp2_all + (size_t)enc * (NK + 1);
    __shared__ int wsum[16];
    int t = threadIdx.x, lane = t & 63, wid = t >> 6;
    int i0 = blockIdx.x * 4096 + t * 4;
    int4 v = make_int4(0, 0, 0, 0);
    bool in = (i0 + 3 < NK);
    if (in) v = *(const int4*)(deg + i0);
    int s = v.x + v.y + v.z + v.w;
    int x = s;
    #pragma unroll
    for (int d = 1; d < 64; d <<= 1) {
        int y = __shfl_up(x, d, 64);
        if (lane >= d) x += y;
    }
    if (lane == 63) wsum[wid] = x;
    __syncthreads();
    if (t == 0) {
        int run = 0;
        #pragma unroll
        for (int w = 0; w < 16; ++w) { int q = wsum[w]; wsum[w] = run; run += q; }
        tot[enc * SAB + blockIdx.x] = run;
    }
    __syncthreads();
    if (in) {
        int excl = wsum[wid] + x - s;
        rp[i0] = excl;
        rp[i0 + 1] = excl + v.x;
        rp[i0 + 2] = excl + v.x + v.y;
        rp[i0 + 3] = excl + v.x + v.y + v.z;
    }
}

__global__ void scanB_kernel(int* __restrict__ tot) {
    int enc = threadIdx.x;
    if (enc < 2) {
        int run = 0;
        for (int b = 0; b < SAB; ++b) { int q = tot[enc * SAB + b]; tot[enc * SAB + b] = run; run += q; }
    }
}

__global__ __launch_bounds__(256)
void scanC_kernel(int* __restrict__ rp2_all, int* __restrict__ cur2_all, const int* __restrict__ tot) {
    int enc = blockIdx.y;
    int* rp = rp2_all + (size_t)enc * (NK + 1);
    int* cur = cur2_all + (size_t)enc * NK;
    int idx = (blockIdx.x * 256 + threadIdx.x) * 4;
    if (idx < NK) {
        int off = tot[enc * SAB + (idx >> 12)];
        int4 v = *(const int4*)(rp + idx);
        v.x += off; v.y += off; v.z += off; v.w += off;
        *(int4*)(rp + idx) = v;
        *(int4*)(cur + idx) = v;
    }
    if (blockIdx.x == 0 && threadIdx.x == 0) rp[NK] = NE;
}

// ---------------- scatter: XCD-pinned by dst-range, key = dst*8 + src_range ----------------

__global__ __launch_bounds__(256)
void scatter_kernel(const int* __restrict__ s1, const int* __restrict__ d1,
                    const int* __restrict__ s2, const int* __restrict__ d2,
                    int* __restrict__ cur2_all, u16* __restrict__ csr_all) {
    int range = blockIdx.x & (NRANGE - 1);
    int lo = range * RN, hi = lo + RN;
    int chunk = blockIdx.x >> 3;
    int e = chunk * 1024 + threadIdx.x * 4;
    const int* s = s1; const int* d = d1; int enc = 0;
    if (e >= NE) { e -= NE; s = s2; d = d2; enc = 1; }
    if (e >= NE) return;
    int4 dv = *(const int4*)(d + e);
    bool any = (dv.x >= lo && dv.x < hi) || (dv.y >= lo && dv.y < hi) ||
               (dv.z >= lo && dv.z < hi) || (dv.w >= lo && dv.w < hi);
    if (!any) return;
    int4 sv = *(const int4*)(s + e);
    int* cursor = cur2_all + (size_t)enc * NK;
    u16* csr = csr_all + (size_t)enc * NE;
    #pragma unroll
    for (int j = 0; j < 4; ++j) {
        int dst = j == 0 ? dv.x : j == 1 ? dv.y : j == 2 ? dv.z : dv.w;
        int src = j == 0 ? sv.x : j == 1 ? sv.y : j == 2 ? sv.z : sv.w;
        if (dst >= lo && dst < hi) {
            int key = dst * 8 + src / RN;
            int pos = atomicAdd(&cursor[key], 1);
            csr[pos] = (u16)src;
        }
    }
}

__global__ void convw_kernel(const float* __restrict__ W1a, const float* __restrict__ W1b,
                             const float* __restrict__ W2a, const float* __restrict__ W2b,
                             u16* __restrict__ W1t_all, u16* __restrict__ W2t_all) {
    int mat = blockIdx.y;
    int idx = blockIdx.x * blockDim.x + threadIdx.x;
    const float* W; u16* Wt; int K, N;
    if (mat < 2) { W = mat ? W1b : W1a; Wt = W1t_all + (size_t)mat * 512 * 256; K = 512; N = 256; }
    else         { W = (mat == 3) ? W2b : W2a; Wt = W2t_all + (size_t)(mat - 2) * 256 * 128; K = 256; N = 128; }
    if (idx < K * N) {
        int k = idx / N, n = idx - k * N;
        Wt[(size_t)n * K + k] = f2bf_u16(W[idx]);
    }
}

// ---------------- MFMA GEMM: C = A @ Bt^T, LDS-repacked full-line epilogue ----------------

template<bool A_F32, bool OUT_BF16, bool TRIANG, bool SCALE>
__global__ __launch_bounds__(256)
void gemm_kernel(const void* __restrict__ A0_, const void* __restrict__ A1_,
                 const u16* __restrict__ Bt0, const u16* __restrict__ Bt1,
                 void* __restrict__ C0_, void* __restrict__ C1_,
                 const float* __restrict__ rs0, const float* __restrict__ rs1,
                 int M, int N, int K) {
    int enc = blockIdx.z;
    const void* A_ = enc ? A1_ : A0_;
    const u16* Bt = enc ? Bt1 : Bt0;
    void* C_ = enc ? C1_ : C0_;
    const float* rowscale = enc ? rs1 : rs0;

    int it = blockIdx.x, jt = blockIdx.y;
    int t = threadIdx.x;
    int brow = it * 128, bcol = jt * 128;
    float* Cf = (float*)C_;
    if (TRIANG && jt < it) {
        f32x4 z = {0.f, 0.f, 0.f, 0.f};
        #pragma unroll
        for (int p = 0; p < 16; ++p) {
            int idx = p * 256 + t;
            int r = idx >> 5, c4 = idx & 31;
            __builtin_nontemporal_store(z, (f32x4*)(Cf + (size_t)(brow + r) * N + bcol + c4 * 4));
        }
        return;
    }
    __shared__ alignas(16) u16 smem[128 * 40 * 2];
    u16* As = smem;
    u16* Bs = smem + 128 * 40;
    int lane = t & 63, wv = t >> 6;
    int wr = wv >> 1, wc = wv & 1;
    f32x4 acc[4][4];
    #pragma unroll
    for (int m = 0; m < 4; ++m)
        #pragma unroll
        for (int n = 0; n < 4; ++n) acc[m][n] = f32x4{0.f, 0.f, 0.f, 0.f};

    for (int k0 = 0; k0 < K; k0 += 32) {
        if (A_F32) {
            const float* A = (const float*)A_;
            #pragma unroll
            for (int p = 0; p < 4; ++p) {
                int r = p * 32 + (t >> 3), c = (t & 7) * 4;
                int gr = brow + r;
                float4 v = make_float4(0.f, 0.f, 0.f, 0.f);
                if (gr < M) v = *(const float4*)(A + (size_t)gr * K + k0 + c);
                u32 lo = (u32)f2bf_u16(v.x) | ((u32)f2bf_u16(v.y) << 16);
                u32 hi = (u32)f2bf_u16(v.z) | ((u32)f2bf_u16(v.w) << 16);
                *(uint2*)&As[r * 40 + c] = make_uint2(lo, hi);
            }
        } else {
            const u16* A = (const u16*)A_;
            #pragma unroll
            for (int p = 0; p < 2; ++p) {
                int r = p * 64 + (t >> 2), c = (t & 3) * 8;
                int gr = brow + r;
                uint4 v = make_uint4(0u, 0u, 0u, 0u);
                if (gr < M) v = *(const uint4*)(A + (size_t)gr * K + k0 + c);
                *(uint4*)&As[r * 40 + c] = v;
            }
        }
        #pragma unroll
        for (int p = 0; p < 2; ++p) {
            int r = p * 64 + (t >> 2), c = (t & 3) * 8;
            int gn = bcol + r;
            uint4 v = make_uint4(0u, 0u, 0u, 0u);
            if (gn < N) v = *(const uint4*)(Bt + (size_t)gn * K + k0 + c);
            *(uint4*)&Bs[r * 40 + c] = v;
        }
        __syncthreads();
        int kg = (lane >> 4) * 8;
        short8 av[4], bv[4];
        #pragma unroll
        for (int m = 0; m < 4; ++m)
            av[m] = *(const short8*)&As[(wr * 64 + m * 16 + (lane & 15)) * 40 + kg];
        #pragma unroll
        for (int n = 0; n < 4; ++n)
            bv[n] = *(const short8*)&Bs[(wc * 64 + n * 16 + (lane & 15)) * 40 + kg];
        #pragma unroll
        for (int m = 0; m < 4; ++m)
            #pragma unroll
            for (int n = 0; n < 4; ++n)
                acc[m][n] = __builtin_amdgcn_mfma_f32_16x16x32_bf16(av[m], bv[n], acc[m][n], 0, 0, 0);
        __syncthreads();
    }

    // ---- epilogue: per-wave LDS repack -> full-line stores ----
    // Wave's region: rows brow+wr*64+m*16+[0,16), cols bcol+wc*64+[0,64).
    const int lane15 = lane & 15, lanehi = lane >> 4;
    if (OUT_BF16) {
        u16* stg = smem + wv * 1024;          // 16x64 u16 = 2 KB per wave
        #pragma unroll
        for (int m = 0; m < 4; ++m) {
            #pragma unroll
            for (int n = 0; n < 4; ++n)
                #pragma unroll
                for (int r = 0; r < 4; ++r) {
                    float v = acc[m][n][r];
                    if (SCALE) v *= rowscale[brow + wr * 64 + m * 16 + lanehi * 4 + r];
                    stg[(lanehi * 4 + r) * 64 + n * 16 + lane15] = f2bf_u16(v);
                }
            #pragma unroll
            for (int pass = 0; pass < 2; ++pass) {
                int lr = pass * 8 + (lane >> 3);
                int grow = brow + wr * 64 + m * 16 + lr;
                uint4 w = *(uint4*)&stg[lr * 64 + (lane & 7) * 8];
                if (grow < M)
                    *(uint4*)((u16*)C_ + (size_t)grow * N + bcol + wc * 64 + (lane & 7) * 8) = w;
            }
        }
    } else {
        float* stg = (float*)smem + wv * 1024;  // 16x64 f32 = 4 KB per wave
        #pragma unroll
        for (int m = 0; m < 4; ++m) {
            #pragma unroll
            for (int n = 0; n < 4; ++n)
                #pragma unroll
                for (int r = 0; r < 4; ++r) {
                    int row = brow + wr * 64 + m * 16 + lanehi * 4 + r;
                    int col = bcol + wc * 64 + n * 16 + lane15;
                    float v = acc[m][n][r];
                    if (SCALE) v *= rowscale[row];
                    if (TRIANG && col < row) v = 0.f;
                    stg[(lanehi * 4 + r) * 64 + n * 16 + lane15] = v;
                }
            #pragma unroll
            for (int pass = 0; pass < 4; ++pass) {
                int lr = pass * 4 + lanehi;
                int grow = brow + wr * 64 + m * 16 + lr;
                f32x4 w = *(f32x4*)&stg[lr * 64 + lane15 * 4];
                if (grow < M) {
                    float* dp = Cf + (size_t)grow * N + bcol + wc * 64 + lane15 * 4;
                    if (TRIANG) __builtin_nontemporal_store(w, (f32x4*)dp);
                    else *(f32x4*)dp = w;
                }
            }
        }
    }
}

// ---------------- aggregation (single enc): out[d] = nd[d]*sum Y[csr[e]] + b ----------------

template<int F, bool RELU, bool OUT_BF16>
__global__ __launch_bounds__(256)
void agg_kernel(const u16* __restrict__ Y, const int* __restrict__ rp2,
                const u16* __restrict__ csr, const float* __restrict__ nd,
                const float* __restrict__ bias, void* __restrict__ out) {
    constexpr int VPL = F / 64;
    int lane = threadIdx.x & 63;
    int node = blockIdx.x * 4 + (threadIdx.x >> 6);
    if (node >= NN) return;
    int e0 = rp2[node * 8], e1 = rp2[node * 8 + 8];
    float acc[VPL];
    #pragma unroll
    for (int j = 0; j < VPL; ++j) acc[j] = 0.f;
    const int off = lane * VPL;

    int e = e0;
    for (; e < e1 && (e & 7) != 0; ++e) {
        int s = csr[e];
        if (VPL == 4) {
            uint2 d = *(const uint2*)(Y + (size_t)s * F + off);
            acc[0] += bfu(d.x & 0xffffu); acc[1] += bfu(d.x >> 16);
            acc[2] += bfu(d.y & 0xffffu); acc[3] += bfu(d.y >> 16);
        } else {
            u32 d = *(const u32*)(Y + (size_t)s * F + off);
            acc[0] += bfu(d & 0xffffu); acc[1] += bfu(d >> 16);
        }
    }
    for (; e + 8 <= e1; e += 8) {
        uint4 iv = *(const uint4*)(csr + e);
        int s0 = iv.x & 0xffff, s1 = iv.x >> 16;
        int s2 = iv.y & 0xffff, s3 = iv.y >> 16;
        int s4 = iv.z & 0xffff, s5 = iv.z >> 16;
        int s6 = iv.w & 0xffff, s7 = iv.w >> 16;
        if (VPL == 4) {
            uint2 d0 = *(const uint2*)(Y + (size_t)s0 * F + off);
            uint2 d1 = *(const uint2*)(Y + (size_t)s1 * F + off);
            uint2 d2 = *(const uint2*)(Y + (size_t)s2 * F + off);
            uint2 d3 = *(const uint2*)(Y + (size_t)s3 * F + off);
            uint2 d4 = *(const uint2*)(Y + (size_t)s4 * F + off);
            uint2 d5 = *(const uint2*)(Y + (size_t)s5 * F + off);
            uint2 d6 = *(const uint2*)(Y + (size_t)s6 * F + off);
            uint2 d7 = *(const uint2*)(Y + (size_t)s7 * F + off);
            acc[0] += bfu(d0.x & 0xffffu); acc[1] += bfu(d0.x >> 16); acc[2] += bfu(d0.y & 0xffffu); acc[3] += bfu(d0.y >> 16);
            acc[0] += bfu(d1.x & 0xffffu); acc[1] += bfu(d1.x >> 16); acc[2] += bfu(d1.y & 0xffffu); acc[3] += bfu(d1.y >> 16);
            acc[0] += bfu(d2.x & 0xffffu); acc[1] += bfu(d2.x >> 16); acc[2] += bfu(d2.y & 0xffffu); acc[3] += bfu(d2.y >> 16);
            acc[0] += bfu(d3.x & 0xffffu); acc[1] += bfu(d3.x >> 16); acc[2] += bfu(d3.y & 0xffffu); acc[3] += bfu(d3.y >> 16);
            acc[0] += bfu(d4.x & 0xffffu); acc[1] += bfu(d4.x >> 16); acc[2] += bfu(d4.y & 0xffffu); acc[3] += bfu(d4.y >> 16);
            acc[0] += bfu(d5.x & 0xffffu); acc[1] += bfu(d5.x >> 16); acc[2] += bfu(d5.y & 0xffffu); acc[3] += bfu(d5.y >> 16);
            acc[0] += bfu(d6.x & 0xffffu); acc[1] += bfu(d6.x >> 16); acc[2] += bfu(d6.y & 0xffffu); acc[3] += bfu(d6.y >> 16);
            acc[0] += bfu(d7.x & 0xffffu); acc[1] += bfu(d7.x >> 16); acc[2] += bfu(d7.y & 0xffffu); acc[3] += bfu(d7.y >> 16);
        } else {
            u32 d0 = *(const u32*)(Y + (size_t)s0 * F + off);
            u32 d1 = *(const u32*)(Y + (size_t)s1 * F + off);
            u32 d2 = *(const u32*)(Y + (size_t)s2 * F + off);
            u32 d3 = *(const u32*)(Y + (size_t)s3 * F + off);
            u32 d4 = *(const u32*)(Y + (size_t)s4 * F + off);
            u32 d5 = *(const u32*)(Y + (size_t)s5 * F + off);
            u32 d6 = *(const u32*)(Y + (size_t)s6 * F + off);
            u32 d7 = *(const u32*)(Y + (size_t)s7 * F + off);
            acc[0] += bfu(d0 & 0xffffu); acc[1] += bfu(d0 >> 16);
            acc[0] += bfu(d1 & 0xffffu); acc[1] += bfu(d1 >> 16);
            acc[0] += bfu(d2 & 0xffffu); acc[1] += bfu(d2 >> 16);
            acc[0] += bfu(d3 & 0xffffu); acc[1] += bfu(d3 >> 16);
            acc[0] += bfu(d4 & 0xffffu); acc[1] += bfu(d4 >> 16);
            acc[0] += bfu(d5 & 0xffffu); acc[1] += bfu(d5 >> 16);
            acc[0] += bfu(d6 & 0xffffu); acc[1] += bfu(d6 >> 16);
            acc[0] += bfu(d7 & 0xffffu); acc[1] += bfu(d7 >> 16);
        }
    }
    for (; e < e1; ++e) {
        int s = csr[e];
        if (VPL == 4) {
            uint2 d = *(const uint2*)(Y + (size_t)s * F + off);
            acc[0] += bfu(d.x & 0xffffu); acc[1] += bfu(d.x >> 16);
            acc[2] += bfu(d.y & 0xffffu); acc[3] += bfu(d.y >> 16);
        } else {
            u32 d = *(const u32*)(Y + (size_t)s * F + off);
            acc[0] += bfu(d & 0xffffu); acc[1] += bfu(d >> 16);
        }
    }

    float ndv = nd[node];
    #pragma unroll
    for (int j = 0; j < VPL; ++j) {
        float o = acc[j] * ndv + bias[off + j];
        if (RELU) o = fmaxf(o, 0.f);
        if (OUT_BF16) ((u16*)out)[(size_t)node * F + off + j] = f2bf_u16(o);
        else ((float*)out)[(size_t)node * F + off + j] = o;
    }
}

// ---------------- normalize + build R = [ (a+b)/2 , (a-b)/(2*sqrt(3)) ] ----------------

__global__ __launch_bounds__(256)
void build_r_kernel(const float* __restrict__ H2a, const float* __restrict__ H2b,
                    const int* __restrict__ index, u16* __restrict__ R) {
    int lane = threadIdx.x & 63;
    int row = blockIdx.x * 4 + (threadIdx.x >> 6);
    int g = index[row];
    float2 a = *(const float2*)(H2a + (size_t)g * 128 + lane * 2);
    float2 b = *(const float2*)(H2b + (size_t)g * 128 + lane * 2);
    float sa = a.x * a.x + a.y * a.y;
    float sb = b.x * b.x + b.y * b.y;
    #pragma unroll
    for (int d = 1; d < 64; d <<= 1) {
        sa += __shfl_xor(sa, d, 64);
        sb += __shfl_xor(sb, d, 64);
    }
    float inva = 1.f / fmaxf(sqrtf(sa), 1e-12f);
    float invb = 1.f / fmaxf(sqrtf(sb), 1e-12f);
    float ax = a.x * inva, ay = a.y * inva;
    float bx = b.x * invb, by = b.y * invb;
    const float c2 = 0.5f, c3 = 0.28867513459481287f;  // 1/(2*sqrt(3))
    u16* Rp = R + (size_t)row * 256;
    Rp[lane * 2]           = f2bf_u16((ax + bx) * c2);
    Rp[lane * 2 + 1]       = f2bf_u16((ay + by) * c2);
    Rp[128 + lane * 2]     = f2bf_u16((ax - bx) * c3);
    Rp[128 + lane * 2 + 1] = f2bf_u16((ay - by) * c3);
}

// ---------------- launch ----------------

extern "C" void kernel_launch(void* const* d_in, const int* in_sizes, int n_in,
                              void* d_out, int out_size, void* d_ws, size_t ws_size,
                              hipStream_t stream) {
    (void)in_sizes; (void)n_in; (void)out_size; (void)ws_size;
    const float* raw0 = (const float*)d_in[0];
    const float* raw1 = (const float*)d_in[1];
    const int* src1 = (const int*)d_in[2], *dst1 = (const int*)d_in[3];
    const int* src2 = (const int*)d_in[4], *dst2 = (const int*)d_in[5];
    const int* index = (const int*)d_in[6];
    const float* W1a = (const float*)d_in[7];  const float* b1a = (const float*)d_in[8];
    const float* W2a = (const float*)d_in[9];  const float* b2a = (const float*)d_in[10];
    const float* W1b = (const float*)d_in[11]; const float* b1b = (const float*)d_in[12];
    const float* W2b = (const float*)d_in[13]; const float* b2b = (const float*)d_in[14];

    char* wp = (char*)d_ws;
    auto alloc = [&](size_t bytes) -> char* {
        char* r = wp;
        wp += (bytes + 255) & ~(size_t)255;
        return r;
    };
    int*   deg_all = (int*)alloc((size_t)4 * NN * 4);
    float* norms   = (float*)alloc((size_t)4 * NN * 4);
    int*   deg2    = (int*)alloc((size_t)2 * NK * 4);
    int*   rp2     = (int*)alloc((size_t)2 * (NK + 1) * 4);
    int*   cur2    = (int*)alloc((size_t)2 * NK * 4);
    int*   tot     = (int*)alloc((size_t)2 * SAB * 4);
    u16*   csr_all = (u16*)alloc((size_t)2 * NE * 2);
    u16*   W1t     = (u16*)alloc((size_t)2 * 512 * 256 * 2);
    u16*   W2t     = (u16*)alloc((size_t)2 * 256 * 128 * 2);
    u16*   Y1      = (u16*)alloc((size_t)2 * NN * 256 * 2);
    u16*   H1      = (u16*)alloc((size_t)2 * NN * 256 * 2);
    u16*   Y2      = (u16*)alloc((size_t)2 * NN * 128 * 2);
    float* H2      = (float*)alloc((size_t)2 * NN * 128 * 4);
    u16*   R       = (u16*)alloc((size_t)NIDX * 256 * 2);
    // hist partials alias Y1 (51.2MB) and H1 (51.2MB): dead until gemm1/agg1.
    u32* partial2   = (u32*)Y1;
    u32* partial_out = (u32*)H1;

    const int MT = (NN + 127) / 128;  // 391 row tiles

    convw_kernel<<<dim3((512 * 256 + 255) / 256, 4), 256, 0, stream>>>(W1a, W1b, W2a, W2b, W1t, W2t);
    hist_kernel<<<dim3(NRANGE * HCH, 2), 256, 0, stream>>>(src1, dst1, src2, dst2, partial2, partial_out);
    reduce_hist_kernel<<<(2 * NN + 255) / 256, 256, 0, stream>>>(partial2, partial_out, deg2, deg_all);
    norm_kernel<<<(4 * NN + 255) / 256, 256, 0, stream>>>(deg_all, norms, 4 * NN);
    scanA_kernel<<<dim3(SAB, 2), 1024, 0, stream>>>(deg2, rp2, tot);
    scanB_kernel<<<1, 64, 0, stream>>>(tot);
    scanC_kernel<<<dim3((NK / 4 + 255) / 256, 2), 256, 0, stream>>>(rp2, cur2, tot);
    scatter_kernel<<<(2 * NE / 1024) * NRANGE, 256, 0, stream>>>(src1, dst1, src2, dst2, cur2, csr_all);

    // Y1 = (raw @ W1) * ns[row]   (both encoders)
    gemm_kernel<true, true, false, true><<<dim3(MT, 2, 2), 256, 0, stream>>>(
        raw0, raw1, W1t, W1t + (size_t)512 * 256, Y1, Y1 + (size_t)NN * 256,
        norms, norms + (size_t)2 * NN, NN, 256, 512);
    // H1 = relu(nd * agg(Y1) + b1), bf16 — per-enc sequential (L2 slice residency)
    agg_kernel<256, true, true><<<(NN + 3) / 4, 256, 0, stream>>>(
        Y1, rp2, csr_all, norms + NN, b1a, H1);
    agg_kernel<256, true, true><<<(NN + 3) / 4, 256, 0, stream>>>(
        Y1 + (size_t)NN * 256, rp2 + (NK + 1), csr_all + (size_t)NE, norms + 3 * NN, b1b,
        H1 + (size_t)NN * 256);
    // Y2 = (H1 @ W2) * ns[row]
    gemm_kernel<false, true, false, true><<<dim3(MT, 1, 2), 256, 0, stream>>>(
        H1, H1 + (size_t)NN * 256, W2t, W2t + (size_t)256 * 128, Y2, Y2 + (size_t)NN * 128,
        norms, norms + (size_t)2 * NN, NN, 128, 256);
    // H2 = nd * agg(Y2) + b2, f32
    agg_kernel<128, false, false><<<(NN + 3) / 4, 256, 0, stream>>>(
        Y2, rp2, csr_all, norms + NN, b2a, H2);
    agg_kernel<128, false, false><<<(NN + 3) / 4, 256, 0, stream>>>(
        Y2 + (size_t)NN * 128, rp2 + (NK + 1), csr_all + (size_t)NE, norms + 3 * NN, b2b,
        H2 + (size_t)NN * 128);

    // R = [ (c1n+c2n)/2 , (c1n-c2n)/(2*sqrt(3)) ]  (8192 x 256, bf16)
    build_r_kernel<<<NIDX / 4, 256, 0, stream>>>(H2, H2 + (size_t)NN * 128, index, R);
    // z = triu(R @ R^T), LDS-repacked NT full-line stores (lower tiles zero-filled in-kernel)
    gemm_kernel<false, false, true, false><<<dim3(64, 64, 1), 256, 0, stream>>>(
        R, R, R, R, (float*)d_out, (float*)d_out, nullptr, nullptr, NIDX, NIDX, 256);
}

// Round 9
// 729.171 us; speedup vs baseline: 1.3421x; 1.1002x over previous
//
#include <hip/hip_runtime.h>
#include <hip/hip_bf16.h>

using u16 = unsigned short;
using u32 = unsigned int;

typedef __attribute__((ext_vector_type(8))) short short8;
typedef __attribute__((ext_vector_type(4))) float f32x4;

__device__ __forceinline__ u16 f2bf_u16(float f) {
    __hip_bfloat16 h = __float2bfloat16(f);
    return __builtin_bit_cast(u16, h);
}
__device__ __forceinline__ float bfu(u32 u) { return __uint_as_float(u << 16); }

static constexpr int NN = 50000;
static constexpr int NE = 1600000;
static constexpr int NIDX = 8192;
static constexpr int NRANGE = 8;              // src ranges AND scatter dst-ranges (XCD pinning)
static constexpr int RN = NN / NRANGE;        // 6250 nodes per range
static constexpr int HCH = 64;                // hist edge-chunks (25000 edges each)
static constexpr int NK = NN * NRANGE;        // 400000 (dst,range) keys per enc
static constexpr int SAB = (NK + 4095) / 4096;  // 98 scanA blocks per enc

// ---------------- hist: per-(dst,src-range) counts + src out-degree, LDS only ----------------

__global__ __launch_bounds__(256)
void hist_kernel(const int* __restrict__ s1, const int* __restrict__ d1,
                 const int* __restrict__ s2, const int* __restrict__ d2,
                 u32* __restrict__ partial2, u32* __restrict__ partial_out) {
    __shared__ u32 h2[RN * 2];    // byte-packed (dstLocal*8+r) counts
    __shared__ u32 ho[RN / 2];    // halfword-packed src out-counts
    int enc = blockIdx.y;
    int stripe = blockIdx.x & (NRANGE - 1);
    int chunk = blockIdx.x >> 3;
    const int* s = enc ? s2 : s1;
    const int* d = enc ? d2 : d1;
    int lo = stripe * RN;
    for (int i = threadIdx.x; i < RN * 2; i += 256) h2[i] = 0;
    for (int i = threadIdx.x; i < RN / 2; i += 256) ho[i] = 0;
    __syncthreads();
    int per_chunk = NE / HCH;  // 25000
    int e0 = chunk * per_chunk, e1 = e0 + per_chunk;
    for (int e = e0 + threadIdx.x * 4; e < e1; e += 256 * 4) {
        int4 sv = *(const int4*)(s + e);
        int4 dv = *(const int4*)(d + e);
        #pragma unroll
        for (int j = 0; j < 4; ++j) {
            int src = j == 0 ? sv.x : j == 1 ? sv.y : j == 2 ? sv.z : sv.w;
            int dst = j == 0 ? dv.x : j == 1 ? dv.y : j == 2 ? dv.z : dv.w;
            u32 sl = (u32)(src - lo);
            if (sl < (u32)RN) atomicAdd(&ho[sl >> 1], 1u << ((sl & 1) * 16));
            u32 dl = (u32)(dst - lo);
            if (dl < (u32)RN) {
                u32 idx = dl * 8 + (u32)(src / RN);
                atomicAdd(&h2[idx >> 2], 1u << ((idx & 3) * 8));
            }
        }
    }
    __syncthreads();
    u32* p2 = partial2 + ((size_t)enc * HCH + chunk) * (NN * 2) + stripe * (RN * 2);
    for (int i = threadIdx.x; i < RN * 2; i += 256) p2[i] = h2[i];
    u32* po = partial_out + ((size_t)enc * HCH + chunk) * (NN / 2) + stripe * (RN / 2);
    for (int i = threadIdx.x; i < RN / 2; i += 256) po[i] = ho[i];
}

__global__ void reduce_hist_kernel(const u32* __restrict__ partial2,
                                   const u32* __restrict__ partial_out,
                                   int* __restrict__ deg2, int* __restrict__ deg_all) {
    int i = blockIdx.x * blockDim.x + threadIdx.x;
    if (i >= 2 * NN) return;
    int enc = i / NN;
    int dst = i - enc * NN;
    int cnt[8];
    #pragma unroll
    for (int r = 0; r < 8; ++r) cnt[r] = 0;
    for (int c = 0; c < HCH; ++c) {
        const u32* p = partial2 + ((size_t)enc * HCH + c) * (NN * 2) + dst * 2;
        u32 w0 = p[0], w1 = p[1];
        cnt[0] += w0 & 0xff; cnt[1] += (w0 >> 8) & 0xff; cnt[2] += (w0 >> 16) & 0xff; cnt[3] += w0 >> 24;
        cnt[4] += w1 & 0xff; cnt[5] += (w1 >> 8) & 0xff; cnt[6] += (w1 >> 16) & 0xff; cnt[7] += w1 >> 24;
    }
    int* dp = deg2 + (size_t)enc * NK + dst * 8;
    int din = 0;
    #pragma unroll
    for (int r = 0; r < 8; ++r) { dp[r] = cnt[r]; din += cnt[r]; }
    deg_all[(enc * 2 + 1) * NN + dst] = din;
    int dout = 0;
    for (int c = 0; c < HCH; ++c) {
        u32 w = partial_out[((size_t)enc * HCH + c) * (NN / 2) + (dst >> 1)];
        dout += (w >> ((dst & 1) * 16)) & 0xffff;
    }
    deg_all[(enc * 2 + 0) * NN + dst] = dout;
}

__global__ void norm_kernel(const int* __restrict__ deg_all, float* __restrict__ norms, int n4) {
    int i = blockIdx.x * blockDim.x + threadIdx.x;
    if (i < n4) norms[i] = rsqrtf(fmaxf((float)deg_all[i], 1.f));
}

// ---------------- 3-phase scan over deg2 (400000 per enc) ----------------

__global__ __launch_bounds__(1024)
void scanA_kernel(const int* __restrict__ deg2, int* __restrict__ rp2_all, int* __restrict__ tot) {
    int enc = blockIdx.y;
    const int* deg = deg2 + (size_t)enc * NK;
    int* rp = rp2_all + (size_t)enc * (NK + 1);
    __shared__ int wsum[16];
    int t = threadIdx.x, lane = t & 63, wid = t >> 6;
    int i0 = blockIdx.x * 4096 + t * 4;
    int4 v = make_int4(0, 0, 0, 0);
    bool in = (i0 + 3 < NK);
    if (in) v = *(const int4*)(deg + i0);
    int s = v.x + v.y + v.z + v.w;
    int x = s;
    #pragma unroll
    for (int d = 1; d < 64; d <<= 1) {
        int y = __shfl_up(x, d, 64);
        if (lane >= d) x += y;
    }
    if (lane == 63) wsum[wid] = x;
    __syncthreads();
    if (t == 0) {
        int run = 0;
        #pragma unroll
        for (int w = 0; w < 16; ++w) { int q = wsum[w]; wsum[w] = run; run += q; }
        tot[enc * SAB + blockIdx.x] = run;
    }
    __syncthreads();
    if (in) {
        int excl = wsum[wid] + x - s;
        rp[i0] = excl;
        rp[i0 + 1] = excl + v.x;
        rp[i0 + 2] = excl + v.x + v.y;
        rp[i0 + 3] = excl + v.x + v.y + v.z;
    }
}

__global__ void scanB_kernel(int* __restrict__ tot) {
    int enc = threadIdx.x;
    if (enc < 2) {
        int run = 0;
        for (int b = 0; b < SAB; ++b) { int q = tot[enc * SAB + b]; tot[enc * SAB + b] = run; run += q; }
    }
}

__global__ __launch_bounds__(256)
void scanC_kernel(int* __restrict__ rp2_all, int* __restrict__ cur2_all, const int* __restrict__ tot) {
    int enc = blockIdx.y;
    int* rp = rp2_all + (size_t)enc * (NK + 1);
    int* cur = cur2_all + (size_t)enc * NK;
    int idx = (blockIdx.x * 256 + threadIdx.x) * 4;
    if (idx < NK) {
        int off = tot[enc * SAB + (idx >> 12)];
        int4 v = *(const int4*)(rp + idx);
        v.x += off; v.y += off; v.z += off; v.w += off;
        *(int4*)(rp + idx) = v;
        *(int4*)(cur + idx) = v;
    }
    if (blockIdx.x == 0 && threadIdx.x == 0) rp[NK] = NE;
}

// ---------------- scatter: XCD-pinned by dst-range, key = dst*8 + src_range ----------------

__global__ __launch_bounds__(256)
void scatter_kernel(const int* __restrict__ s1, const int* __restrict__ d1,
                    const int* __restrict__ s2, const int* __restrict__ d2,
                    int* __restrict__ cur2_all, u16* __restrict__ csr_all) {
    int range = blockIdx.x & (NRANGE - 1);
    int lo = range * RN, hi = lo + RN;
    int chunk = blockIdx.x >> 3;
    int e = chunk * 1024 + threadIdx.x * 4;
    const int* s = s1; const int* d = d1; int enc = 0;
    if (e >= NE) { e -= NE; s = s2; d = d2; enc = 1; }
    if (e >= NE) return;
    int4 dv = *(const int4*)(d + e);
    bool any = (dv.x >= lo && dv.x < hi) || (dv.y >= lo && dv.y < hi) ||
               (dv.z >= lo && dv.z < hi) || (dv.w >= lo && dv.w < hi);
    if (!any) return;
    int4 sv = *(const int4*)(s + e);
    int* cursor = cur2_all + (size_t)enc * NK;
    u16* csr = csr_all + (size_t)enc * NE;
    #pragma unroll
    for (int j = 0; j < 4; ++j) {
        int dst = j == 0 ? dv.x : j == 1 ? dv.y : j == 2 ? dv.z : dv.w;
        int src = j == 0 ? sv.x : j == 1 ? sv.y : j == 2 ? sv.z : sv.w;
        if (dst >= lo && dst < hi) {
            int key = dst * 8 + src / RN;
            int pos = atomicAdd(&cursor[key], 1);
            csr[pos] = (u16)src;
        }
    }
}

__global__ void convw_kernel(const float* __restrict__ W1a, const float* __restrict__ W1b,
                             const float* __restrict__ W2a, const float* __restrict__ W2b,
                             u16* __restrict__ W1t_all, u16* __restrict__ W2t_all) {
    int mat = blockIdx.y;
    int idx = blockIdx.x * blockDim.x + threadIdx.x;
    const float* W; u16* Wt; int K, N;
    if (mat < 2) { W = mat ? W1b : W1a; Wt = W1t_all + (size_t)mat * 512 * 256; K = 512; N = 256; }
    else         { W = (mat == 3) ? W2b : W2a; Wt = W2t_all + (size_t)(mat - 2) * 256 * 128; K = 256; N = 128; }
    if (idx < K * N) {
        int k = idx / N, n = idx - k * N;
        Wt[(size_t)n * K + k] = f2bf_u16(W[idx]);
    }
}

// ---------------- MFMA GEMM: C = A @ Bt^T, register-prefetch pipeline + ----------------
// ---------------- LDS-repacked full-line epilogue ----------------

template<bool A_F32, bool OUT_BF16, bool TRIANG, bool SCALE>
__global__ __launch_bounds__(256)
void gemm_kernel(const void* __restrict__ A0_, const void* __restrict__ A1_,
                 const u16* __restrict__ Bt0, const u16* __restrict__ Bt1,
                 void* __restrict__ C0_, void* __restrict__ C1_,
                 const float* __restrict__ rs0, const float* __restrict__ rs1,
                 int M, int N, int K) {
    int enc = blockIdx.z;
    const void* A_ = enc ? A1_ : A0_;
    const u16* Bt = enc ? Bt1 : Bt0;
    void* C_ = enc ? C1_ : C0_;
    const float* rowscale = enc ? rs1 : rs0;

    int it = blockIdx.x, jt = blockIdx.y;
    int t = threadIdx.x;
    int brow = it * 128, bcol = jt * 128;
    float* Cf = (float*)C_;
    if (TRIANG && jt < it) {
        f32x4 z = {0.f, 0.f, 0.f, 0.f};
        #pragma unroll
        for (int p = 0; p < 16; ++p) {
            int idx = p * 256 + t;
            int r = idx >> 5, c4 = idx & 31;
            __builtin_nontemporal_store(z, (f32x4*)(Cf + (size_t)(brow + r) * N + bcol + c4 * 4));
        }
        return;
    }
    __shared__ alignas(16) u16 smem[128 * 40 * 2];
    u16* As = smem;
    u16* Bs = smem + 128 * 40;
    int lane = t & 63, wv = t >> 6;
    int wr = wv >> 1, wc = wv & 1;
    f32x4 acc[4][4];
    #pragma unroll
    for (int m = 0; m < 4; ++m)
        #pragma unroll
        for (int n = 0; n < 4; ++n) acc[m][n] = f32x4{0.f, 0.f, 0.f, 0.f};

    // staging registers (one K-step ahead)
    float4 a_f[4];
    uint4  a_h[2];
    uint4  b_h[2];

    auto loadTile = [&](int k0) {
        if constexpr (A_F32) {
            const float* A = (const float*)A_;
            #pragma unroll
            for (int p = 0; p < 4; ++p) {
                int r = p * 32 + (t >> 3), c = (t & 7) * 4;
                int gr = brow + r;
                a_f[p] = make_float4(0.f, 0.f, 0.f, 0.f);
                if (gr < M) a_f[p] = *(const float4*)(A + (size_t)gr * K + k0 + c);
            }
        } else {
            const u16* A = (const u16*)A_;
            #pragma unroll
            for (int p = 0; p < 2; ++p) {
                int r = p * 64 + (t >> 2), c = (t & 3) * 8;
                int gr = brow + r;
                a_h[p] = make_uint4(0u, 0u, 0u, 0u);
                if (gr < M) a_h[p] = *(const uint4*)(A + (size_t)gr * K + k0 + c);
            }
        }
        #pragma unroll
        for (int p = 0; p < 2; ++p) {
            int r = p * 64 + (t >> 2), c = (t & 3) * 8;
            int gn = bcol + r;
            b_h[p] = make_uint4(0u, 0u, 0u, 0u);
            if (gn < N) b_h[p] = *(const uint4*)(Bt + (size_t)gn * K + k0 + c);
        }
    };
    auto storeLDS = [&]() {
        if constexpr (A_F32) {
            #pragma unroll
            for (int p = 0; p < 4; ++p) {
                int r = p * 32 + (t >> 3), c = (t & 7) * 4;
                u32 lo = (u32)f2bf_u16(a_f[p].x) | ((u32)f2bf_u16(a_f[p].y) << 16);
                u32 hi = (u32)f2bf_u16(a_f[p].z) | ((u32)f2bf_u16(a_f[p].w) << 16);
                *(uint2*)&As[r * 40 + c] = make_uint2(lo, hi);
            }
        } else {
            #pragma unroll
            for (int p = 0; p < 2; ++p) {
                int r = p * 64 + (t >> 2), c = (t & 3) * 8;
                *(uint4*)&As[r * 40 + c] = a_h[p];
            }
        }
        #pragma unroll
        for (int p = 0; p < 2; ++p) {
            int r = p * 64 + (t >> 2), c = (t & 3) * 8;
            *(uint4*)&Bs[r * 40 + c] = b_h[p];
        }
    };

    loadTile(0);
    for (int k0 = 0; k0 < K; k0 += 32) {
        storeLDS();
        __syncthreads();
        if (k0 + 32 < K) loadTile(k0 + 32);   // prefetch next step; latency hides under MFMA
        int kg = (lane >> 4) * 8;
        short8 av[4], bv[4];
        #pragma unroll
        for (int m = 0; m < 4; ++m)
            av[m] = *(const short8*)&As[(wr * 64 + m * 16 + (lane & 15)) * 40 + kg];
        #pragma unroll
        for (int n = 0; n < 4; ++n)
            bv[n] = *(const short8*)&Bs[(wc * 64 + n * 16 + (lane & 15)) * 40 + kg];
        #pragma unroll
        for (int m = 0; m < 4; ++m)
            #pragma unroll
            for (int n = 0; n < 4; ++n)
                acc[m][n] = __builtin_amdgcn_mfma_f32_16x16x32_bf16(av[m], bv[n], acc[m][n], 0, 0, 0);
        __syncthreads();
    }

    // ---- epilogue: per-wave LDS repack -> full-line stores ----
    const int lane15 = lane & 15, lanehi = lane >> 4;
    if (OUT_BF16) {
        u16* stg = smem + wv * 1024;          // 16x64 u16 = 2 KB per wave
        #pragma unroll
        for (int m = 0; m < 4; ++m) {
            #pragma unroll
            for (int n = 0; n < 4; ++n)
                #pragma unroll
                for (int r = 0; r < 4; ++r) {
                    float v = acc[m][n][r];
                    if (SCALE) v *= rowscale[brow + wr * 64 + m * 16 + lanehi * 4 + r];
                    stg[(lanehi * 4 + r) * 64 + n * 16 + lane15] = f2bf_u16(v);
                }
            #pragma unroll
            for (int pass = 0; pass < 2; ++pass) {
                int lr = pass * 8 + (lane >> 3);
                int grow = brow + wr * 64 + m * 16 + lr;
                uint4 w = *(uint4*)&stg[lr * 64 + (lane & 7) * 8];
                if (grow < M)
                    *(uint4*)((u16*)C_ + (size_t)grow * N + bcol + wc * 64 + (lane & 7) * 8) = w;
            }
        }
    } else {
        float* stg = (float*)smem + wv * 1024;  // 16x64 f32 = 4 KB per wave
        #pragma unroll
        for (int m = 0; m < 4; ++m) {
            #pragma unroll
            for (int n = 0; n < 4; ++n)
                #pragma unroll
                for (int r = 0; r < 4; ++r) {
                    int row = brow + wr * 64 + m * 16 + lanehi * 4 + r;
                    int col = bcol + wc * 64 + n * 16 + lane15;
                    float v = acc[m][n][r];
                    if (SCALE) v *= rowscale[row];
                    if (TRIANG && col < row) v = 0.f;
                    stg[(lanehi * 4 + r) * 64 + n * 16 + lane15] = v;
                }
            #pragma unroll
            for (int pass = 0; pass < 4; ++pass) {
                int lr = pass * 4 + lanehi;
                int grow = brow + wr * 64 + m * 16 + lr;
                f32x4 w = *(f32x4*)&stg[lr * 64 + lane15 * 4];
                if (grow < M) {
                    float* dp = Cf + (size_t)grow * N + bcol + wc * 64 + lane15 * 4;
                    if (TRIANG) __builtin_nontemporal_store(w, (f32x4*)dp);
                    else *(f32x4*)dp = w;
                }
            }
        }
    }
}

// ---------------- aggregation (single enc): out[d] = nd[d]*sum Y[csr[e]] + b ----------------

template<int F, bool RELU, bool OUT_BF16>
__global__ __launch_bounds__(256)
void agg_kernel(const u16* __restrict__ Y, const int* __restrict__ rp2,
                const u16* __restrict__ csr, const float* __restrict__ nd,
                const float* __restrict__ bias, void* __restrict__ out) {
    constexpr int VPL = F / 64;
    int lane = threadIdx.x & 63;
    int node = blockIdx.x * 4 + (threadIdx.x >> 6);
    if (node >= NN) return;
    int e0 = rp2[node * 8], e1 = rp2[node * 8 + 8];
    float acc[VPL];
    #pragma unroll
    for (int j = 0; j < VPL; ++j) acc[j] = 0.f;
    const int off = lane * VPL;

    int e = e0;
    for (; e < e1 && (e & 7) != 0; ++e) {
        int s = csr[e];
        if (VPL == 4) {
            uint2 d = *(const uint2*)(Y + (size_t)s * F + off);
            acc[0] += bfu(d.x & 0xffffu); acc[1] += bfu(d.x >> 16);
            acc[2] += bfu(d.y & 0xffffu); acc[3] += bfu(d.y >> 16);
        } else {
            u32 d = *(const u32*)(Y + (size_t)s * F + off);
            acc[0] += bfu(d & 0xffffu); acc[1] += bfu(d >> 16);
        }
    }
    for (; e + 8 <= e1; e += 8) {
        uint4 iv = *(const uint4*)(csr + e);
        int s0 = iv.x & 0xffff, s1 = iv.x >> 16;
        int s2 = iv.y & 0xffff, s3 = iv.y >> 16;
        int s4 = iv.z & 0xffff, s5 = iv.z >> 16;
        int s6 = iv.w & 0xffff, s7 = iv.w >> 16;
        if (VPL == 4) {
            uint2 d0 = *(const uint2*)(Y + (size_t)s0 * F + off);
            uint2 d1 = *(const uint2*)(Y + (size_t)s1 * F + off);
            uint2 d2 = *(const uint2*)(Y + (size_t)s2 * F + off);
            uint2 d3 = *(const uint2*)(Y + (size_t)s3 * F + off);
            uint2 d4 = *(const uint2*)(Y + (size_t)s4 * F + off);
            uint2 d5 = *(const uint2*)(Y + (size_t)s5 * F + off);
            uint2 d6 = *(const uint2*)(Y + (size_t)s6 * F + off);
            uint2 d7 = *(const uint2*)(Y + (size_t)s7 * F + off);
            acc[0] += bfu(d0.x & 0xffffu); acc[1] += bfu(d0.x >> 16); acc[2] += bfu(d0.y & 0xffffu); acc[3] += bfu(d0.y >> 16);
            acc[0] += bfu(d1.x & 0xffffu); acc[1] += bfu(d1.x >> 16); acc[2] += bfu(d1.y & 0xffffu); acc[3] += bfu(d1.y >> 16);
            acc[0] += bfu(d2.x & 0xffffu); acc[1] += bfu(d2.x >> 16); acc[2] += bfu(d2.y & 0xffffu); acc[3] += bfu(d2.y >> 16);
            acc[0] += bfu(d3.x & 0xffffu); acc[1] += bfu(d3.x >> 16); acc[2] += bfu(d3.y & 0xffffu); acc[3] += bfu(d3.y >> 16);
            acc[0] += bfu(d4.x & 0xffffu); acc[1] += bfu(d4.x >> 16); acc[2] += bfu(d4.y & 0xffffu); acc[3] += bfu(d4.y >> 16);
            acc[0] += bfu(d5.x & 0xffffu); acc[1] += bfu(d5.x >> 16); acc[2] += bfu(d5.y & 0xffffu); acc[3] += bfu(d5.y >> 16);
            acc[0] += bfu(d6.x & 0xffffu); acc[1] += bfu(d6.x >> 16); acc[2] += bfu(d6.y & 0xffffu); acc[3] += bfu(d6.y >> 16);
            acc[0] += bfu(d7.x & 0xffffu); acc[1] += bfu(d7.x >> 16); acc[2] += bfu(d7.y & 0xffffu); acc[3] += bfu(d7.y >> 16);
        } else {
            u32 d0 = *(const u32*)(Y + (size_t)s0 * F + off);
            u32 d1 = *(const u32*)(Y + (size_t)s1 * F + off);
            u32 d2 = *(const u32*)(Y + (size_t)s2 * F + off);
            u32 d3 = *(const u32*)(Y + (size_t)s3 * F + off);
            u32 d4 = *(const u32*)(Y + (size_t)s4 * F + off);
            u32 d5 = *(const u32*)(Y + (size_t)s5 * F + off);
            u32 d6 = *(const u32*)(Y + (size_t)s6 * F + off);
            u32 d7 = *(const u32*)(Y + (size_t)s7 * F + off);
            acc[0] += bfu(d0 & 0xffffu); acc[1] += bfu(d0 >> 16);
            acc[0] += bfu(d1 & 0xffffu); acc[1] += bfu(d1 >> 16);
            acc[0] += bfu(d2 & 0xffffu); acc[1] += bfu(d2 >> 16);
            acc[0] += bfu(d3 & 0xffffu); acc[1] += bfu(d3 >> 16);
            acc[0] += bfu(d4 & 0xffffu); acc[1] += bfu(d4 >> 16);
            acc[0] += bfu(d5 & 0xffffu); acc[1] += bfu(d5 >> 16);
            acc[0] += bfu(d6 & 0xffffu); acc[1] += bfu(d6 >> 16);
            acc[0] += bfu(d7 & 0xffffu); acc[1] += bfu(d7 >> 16);
        }
    }
    for (; e < e1; ++e) {
        int s = csr[e];
        if (VPL == 4) {
            uint2 d = *(const uint2*)(Y + (size_t)s * F + off);
            acc[0] += bfu(d.x & 0xffffu); acc[1] += bfu(d.x >> 16);
            acc[2] += bfu(d.y & 0xffffu); acc[3] += bfu(d.y >> 16);
        } else {
            u32 d = *(const u32*)(Y + (size_t)s * F + off);
            acc[0] += bfu(d & 0xffffu); acc[1] += bfu(d >> 16);
        }
    }

    float ndv = nd[node];
    #pragma unroll
    for (int j = 0; j < VPL; ++j) {
        float o = acc[j] * ndv + bias[off + j];
        if (RELU) o = fmaxf(o, 0.f);
        if (OUT_BF16) ((u16*)out)[(size_t)node * F + off + j] = f2bf_u16(o);
        else ((float*)out)[(size_t)node * F + off + j] = o;
    }
}

// ---------------- normalize + build R = [ (a+b)/2 , (a-b)/(2*sqrt(3)) ] ----------------

__global__ __launch_bounds__(256)
void build_r_kernel(const float* __restrict__ H2a, const float* __restrict__ H2b,
                    const int* __restrict__ index, u16* __restrict__ R) {
    int lane = threadIdx.x & 63;
    int row = blockIdx.x * 4 + (threadIdx.x >> 6);
    int g = index[row];
    float2 a = *(const float2*)(H2a + (size_t)g * 128 + lane * 2);
    float2 b = *(const float2*)(H2b + (size_t)g * 128 + lane * 2);
    float sa = a.x * a.x + a.y * a.y;
    float sb = b.x * b.x + b.y * b.y;
    #pragma unroll
    for (int d = 1; d < 64; d <<= 1) {
        sa += __shfl_xor(sa, d, 64);
        sb += __shfl_xor(sb, d, 64);
    }
    float inva = 1.f / fmaxf(sqrtf(sa), 1e-12f);
    float invb = 1.f / fmaxf(sqrtf(sb), 1e-12f);
    float ax = a.x * inva, ay = a.y * inva;
    float bx = b.x * invb, by = b.y * invb;
    const float c2 = 0.5f, c3 = 0.28867513459481287f;  // 1/(2*sqrt(3))
    u16* Rp = R + (size_t)row * 256;
    Rp[lane * 2]           = f2bf_u16((ax + bx) * c2);
    Rp[lane * 2 + 1]       = f2bf_u16((ay + by) * c2);
    Rp[128 + lane * 2]     = f2bf_u16((ax - bx) * c3);
    Rp[128 + lane * 2 + 1] = f2bf_u16((ay - by) * c3);
}

// ---------------- launch ----------------

extern "C" void kernel_launch(void* const* d_in, const int* in_sizes, int n_in,
                              void* d_out, int out_size, void* d_ws, size_t ws_size,
                              hipStream_t stream) {
    (void)in_sizes; (void)n_in; (void)out_size; (void)ws_size;
    const float* raw0 = (const float*)d_in[0];
    const float* raw1 = (const float*)d_in[1];
    const int* src1 = (const int*)d_in[2], *dst1 = (const int*)d_in[3];
    const int* src2 = (const int*)d_in[4], *dst2 = (const int*)d_in[5];
    const int* index = (const int*)d_in[6];
    const float* W1a = (const float*)d_in[7];  const float* b1a = (const float*)d_in[8];
    const float* W2a = (const float*)d_in[9];  const float* b2a = (const float*)d_in[10];
    const float* W1b = (const float*)d_in[11]; const float* b1b = (const float*)d_in[12];
    const float* W2b = (const float*)d_in[13]; const float* b2b = (const float*)d_in[14];

    char* wp = (char*)d_ws;
    auto alloc = [&](size_t bytes) -> char* {
        char* r = wp;
        wp += (bytes + 255) & ~(size_t)255;
        return r;
    };
    int*   deg_all = (int*)alloc((size_t)4 * NN * 4);
    float* norms   = (float*)alloc((size_t)4 * NN * 4);
    int*   deg2    = (int*)alloc((size_t)2 * NK * 4);
    int*   rp2     = (int*)alloc((size_t)2 * (NK + 1) * 4);
    int*   cur2    = (int*)alloc((size_t)2 * NK * 4);
    int*   tot     = (int*)alloc((size_t)2 * SAB * 4);
    u16*   csr_all = (u16*)alloc((size_t)2 * NE * 2);
    u16*   W1t     = (u16*)alloc((size_t)2 * 512 * 256 * 2);
    u16*   W2t     = (u16*)alloc((size_t)2 * 256 * 128 * 2);
    u16*   Y1      = (u16*)alloc((size_t)2 * NN * 256 * 2);
    u16*   H1      = (u16*)alloc((size_t)2 * NN * 256 * 2);
    u16*   Y2      = (u16*)alloc((size_t)2 * NN * 128 * 2);
    float* H2      = (float*)alloc((size_t)2 * NN * 128 * 4);
    u16*   R       = (u16*)alloc((size_t)NIDX * 256 * 2);
    // hist partials alias Y1 (51.2MB) and H1 (51.2MB): dead until gemm1/agg1.
    u32* partial2   = (u32*)Y1;
    u32* partial_out = (u32*)H1;

    const int MT = (NN + 127) / 128;  // 391 row tiles

    convw_kernel<<<dim3((512 * 256 + 255) / 256, 4), 256, 0, stream>>>(W1a, W1b, W2a, W2b, W1t, W2t);
    hist_kernel<<<dim3(NRANGE * HCH, 2), 256, 0, stream>>>(src1, dst1, src2, dst2, partial2, partial_out);
    reduce_hist_kernel<<<(2 * NN + 255) / 256, 256, 0, stream>>>(partial2, partial_out, deg2, deg_all);
    norm_kernel<<<(4 * NN + 255) / 256, 256, 0, stream>>>(deg_all, norms, 4 * NN);
    scanA_kernel<<<dim3(SAB, 2), 1024, 0, stream>>>(deg2, rp2, tot);
    scanB_kernel<<<1, 64, 0, stream>>>(tot);
    scanC_kernel<<<dim3((NK / 4 + 255) / 256, 2), 256, 0, stream>>>(rp2, cur2, tot);
    scatter_kernel<<<(2 * NE / 1024) * NRANGE, 256, 0, stream>>>(src1, dst1, src2, dst2, cur2, csr_all);

    // Y1 = (raw @ W1) * ns[row]   (both encoders)
    gemm_kernel<true, true, false, true><<<dim3(MT, 2, 2), 256, 0, stream>>>(
        raw0, raw1, W1t, W1t + (size_t)512 * 256, Y1, Y1 + (size_t)NN * 256,
        norms, norms + (size_t)2 * NN, NN, 256, 512);
    // H1 = relu(nd * agg(Y1) + b1), bf16 — per-enc sequential (L2 slice residency)
    agg_kernel<256, true, true><<<(NN + 3) / 4, 256, 0, stream>>>(
        Y1, rp2, csr_all, norms + NN, b1a, H1);
    agg_kernel<256, true, true><<<(NN + 3) / 4, 256, 0, stream>>>(
        Y1 + (size_t)NN * 256, rp2 + (NK + 1), csr_all + (size_t)NE, norms + 3 * NN, b1b,
        H1 + (size_t)NN * 256);
    // Y2 = (H1 @ W2) * ns[row]
    gemm_kernel<false, true, false, true><<<dim3(MT, 1, 2), 256, 0, stream>>>(
        H1, H1 + (size_t)NN * 256, W2t, W2t + (size_t)256 * 128, Y2, Y2 + (size_t)NN * 128,
        norms, norms + (size_t)2 * NN, NN, 128, 256);
    // H2 = nd * agg(Y2) + b2, f32
    agg_kernel<128, false, false><<<(NN + 3) / 4, 256, 0, stream>>>(
        Y2, rp2, csr_all, norms + NN, b2a, H2);
    agg_kernel<128, false, false><<<(NN + 3) / 4, 256, 0, stream>>>(
        Y2 + (size_t)NN * 128, rp2 + (NK + 1), csr_all + (size_t)NE, norms + 3 * NN, b2b,
        H2 + (size_t)NN * 128);

    // R = [ (c1n+c2n)/2 , (c1n-c2n)/(2*sqrt(3)) ]  (8192 x 256, bf16)
    build_r_kernel<<<NIDX / 4, 256, 0, stream>>>(H2, H2 + (size_t)NN * 128, index, R);
    // z = triu(R @ R^T), LDS-repacked NT full-line stores (lower tiles zero-filled in-kernel)
    gemm_kernel<false, false, true, false><<<dim3(64, 64, 1), 256, 0, stream>>>(
        R, R, R, R, (float*)d_out, (float*)d_out, nullptr, nullptr, NIDX, NIDX, 256);
}

// Round 10
// 706.473 us; speedup vs baseline: 1.3852x; 1.0321x over previous
//
#include <hip/hip_runtime.h>
#include <hip/hip_bf16.h>

using u16 = unsigned short;
using u32 = unsigned int;

typedef __attribute__((ext_vector_type(8))) short short8;
typedef __attribute__((ext_vector_type(4))) float f32x4;

__device__ __forceinline__ u16 f2bf_u16(float f) {
    __hip_bfloat16 h = __float2bfloat16(f);
    return __builtin_bit_cast(u16, h);
}
__device__ __forceinline__ float bfu(u32 u) { return __uint_as_float(u << 16); }

static constexpr int NN = 50000;
static constexpr int NE = 1600000;
static constexpr int NIDX = 8192;
static constexpr int NRANGE = 8;              // src ranges AND scatter dst-ranges (XCD pinning)
static constexpr int RN = NN / NRANGE;        // 6250 nodes per range
static constexpr int HCH = 64;                // hist edge-chunks (25000 edges each)
static constexpr int NK = NN * NRANGE;        // 400000 (dst,range) keys per enc
static constexpr int SAB = (NK + 4095) / 4096;  // 98 scanA blocks per enc

// ---------------- hist: per-(dst,src-range) counts + src out-degree, LDS only ----------------

__global__ __launch_bounds__(256)
void hist_kernel(const int* __restrict__ s1, const int* __restrict__ d1,
                 const int* __restrict__ s2, const int* __restrict__ d2,
                 u32* __restrict__ partial2, u32* __restrict__ partial_out) {
    __shared__ u32 h2[RN * 2];    // byte-packed (dstLocal*8+r) counts
    __shared__ u32 ho[RN / 2];    // halfword-packed src out-counts
    int enc = blockIdx.y;
    int stripe = blockIdx.x & (NRANGE - 1);
    int chunk = blockIdx.x >> 3;
    const int* s = enc ? s2 : s1;
    const int* d = enc ? d2 : d1;
    int lo = stripe * RN;
    for (int i = threadIdx.x; i < RN * 2; i += 256) h2[i] = 0;
    for (int i = threadIdx.x; i < RN / 2; i += 256) ho[i] = 0;
    __syncthreads();
    int per_chunk = NE / HCH;  // 25000
    int e0 = chunk * per_chunk, e1 = e0 + per_chunk;
    for (int e = e0 + threadIdx.x * 4; e < e1; e += 256 * 4) {
        int4 sv = *(const int4*)(s + e);
        int4 dv = *(const int4*)(d + e);
        #pragma unroll
        for (int j = 0; j < 4; ++j) {
            int src = j == 0 ? sv.x : j == 1 ? sv.y : j == 2 ? sv.z : sv.w;
            int dst = j == 0 ? dv.x : j == 1 ? dv.y : j == 2 ? dv.z : dv.w;
            u32 sl = (u32)(src - lo);
            if (sl < (u32)RN) atomicAdd(&ho[sl >> 1], 1u << ((sl & 1) * 16));
            u32 dl = (u32)(dst - lo);
            if (dl < (u32)RN) {
                u32 idx = dl * 8 + (u32)(src / RN);
                atomicAdd(&h2[idx >> 2], 1u << ((idx & 3) * 8));
            }
        }
    }
    __syncthreads();
    u32* p2 = partial2 + ((size_t)enc * HCH + chunk) * (NN * 2) + stripe * (RN * 2);
    for (int i = threadIdx.x; i < RN * 2; i += 256) p2[i] = h2[i];
    u32* po = partial_out + ((size_t)enc * HCH + chunk) * (NN / 2) + stripe * (RN / 2);
    for (int i = threadIdx.x; i < RN / 2; i += 256) po[i] = ho[i];
}

// sum byte/halfword partials over chunks; writes deg2 (for scan) and norms directly
__global__ void reduce_hist_kernel(const u32* __restrict__ partial2,
                                   const u32* __restrict__ partial_out,
                                   int* __restrict__ deg2, float* __restrict__ norms) {
    int i = blockIdx.x * blockDim.x + threadIdx.x;
    if (i >= 2 * NN) return;
    int enc = i / NN;
    int dst = i - enc * NN;
    int cnt[8];
    #pragma unroll
    for (int r = 0; r < 8; ++r) cnt[r] = 0;
    for (int c = 0; c < HCH; ++c) {
        const u32* p = partial2 + ((size_t)enc * HCH + c) * (NN * 2) + dst * 2;
        u32 w0 = p[0], w1 = p[1];
        cnt[0] += w0 & 0xff; cnt[1] += (w0 >> 8) & 0xff; cnt[2] += (w0 >> 16) & 0xff; cnt[3] += w0 >> 24;
        cnt[4] += w1 & 0xff; cnt[5] += (w1 >> 8) & 0xff; cnt[6] += (w1 >> 16) & 0xff; cnt[7] += w1 >> 24;
    }
    int* dp = deg2 + (size_t)enc * NK + dst * 8;
    int din = 0;
    #pragma unroll
    for (int r = 0; r < 8; ++r) { dp[r] = cnt[r]; din += cnt[r]; }
    norms[(enc * 2 + 1) * NN + dst] = rsqrtf(fmaxf((float)din, 1.f));
    int dout = 0;
    for (int c = 0; c < HCH; ++c) {
        u32 w = partial_out[((size_t)enc * HCH + c) * (NN / 2) + (dst >> 1)];
        dout += (w >> ((dst & 1) * 16)) & 0xffff;
    }
    norms[(enc * 2 + 0) * NN + dst] = rsqrtf(fmaxf((float)dout, 1.f));
}

// ---------------- 3-phase scan over deg2 (400000 per enc) ----------------

__global__ __launch_bounds__(1024)
void scanA_kernel(const int* __restrict__ deg2, int* __restrict__ rp2_all, int* __restrict__ tot) {
    int enc = blockIdx.y;
    const int* deg = deg2 + (size_t)enc * NK;
    int* rp = rp2_all + (size_t)enc * (NK + 1);
    __shared__ int wsum[16];
    int t = threadIdx.x, lane = t & 63, wid = t >> 6;
    int i0 = blockIdx.x * 4096 + t * 4;
    int4 v = make_int4(0, 0, 0, 0);
    bool in = (i0 + 3 < NK);
    if (in) v = *(const int4*)(deg + i0);
    int s = v.x + v.y + v.z + v.w;
    int x = s;
    #pragma unroll
    for (int d = 1; d < 64; d <<= 1) {
        int y = __shfl_up(x, d, 64);
        if (lane >= d) x += y;
    }
    if (lane == 63) wsum[wid] = x;
    __syncthreads();
    if (t == 0) {
        int run = 0;
        #pragma unroll
        for (int w = 0; w < 16; ++w) { int q = wsum[w]; wsum[w] = run; run += q; }
        tot[enc * SAB + blockIdx.x] = run;
    }
    __syncthreads();
    if (in) {
        int excl = wsum[wid] + x - s;
        rp[i0] = excl;
        rp[i0 + 1] = excl + v.x;
        rp[i0 + 2] = excl + v.x + v.y;
        rp[i0 + 3] = excl + v.x + v.y + v.z;
    }
}

__global__ void scanB_kernel(int* __restrict__ tot) {
    int enc = threadIdx.x;
    if (enc < 2) {
        int run = 0;
        for (int b = 0; b < SAB; ++b) { int q = tot[enc * SAB + b]; tot[enc * SAB + b] = run; run += q; }
    }
}

__global__ __launch_bounds__(256)
void scanC_kernel(int* __restrict__ rp2_all, int* __restrict__ cur2_all, const int* __restrict__ tot) {
    int enc = blockIdx.y;
    int* rp = rp2_all + (size_t)enc * (NK + 1);
    int* cur = cur2_all + (size_t)enc * NK;
    int idx = (blockIdx.x * 256 + threadIdx.x) * 4;
    if (idx < NK) {
        int off = tot[enc * SAB + (idx >> 12)];
        int4 v = *(const int4*)(rp + idx);
        v.x += off; v.y += off; v.z += off; v.w += off;
        *(int4*)(rp + idx) = v;
        *(int4*)(cur + idx) = v;
    }
    if (blockIdx.x == 0 && threadIdx.x == 0) rp[NK] = NE;
}

// ---------------- scatter: XCD-pinned by dst-range, key = dst*8 + src_range ----------------

__global__ __launch_bounds__(256)
void scatter_kernel(const int* __restrict__ s1, const int* __restrict__ d1,
                    const int* __restrict__ s2, const int* __restrict__ d2,
                    int* __restrict__ cur2_all, u16* __restrict__ csr_all) {
    int range = blockIdx.x & (NRANGE - 1);
    int lo = range * RN, hi = lo + RN;
    int chunk = blockIdx.x >> 3;
    int e = chunk * 1024 + threadIdx.x * 4;
    const int* s = s1; const int* d = d1; int enc = 0;
    if (e >= NE) { e -= NE; s = s2; d = d2; enc = 1; }
    if (e >= NE) return;
    int4 dv = *(const int4*)(d + e);
    bool any = (dv.x >= lo && dv.x < hi) || (dv.y >= lo && dv.y < hi) ||
               (dv.z >= lo && dv.z < hi) || (dv.w >= lo && dv.w < hi);
    if (!any) return;
    int4 sv = *(const int4*)(s + e);
    int* cursor = cur2_all + (size_t)enc * NK;
    u16* csr = csr_all + (size_t)enc * NE;
    #pragma unroll
    for (int j = 0; j < 4; ++j) {
        int dst = j == 0 ? dv.x : j == 1 ? dv.y : j == 2 ? dv.z : dv.w;
        int src = j == 0 ? sv.x : j == 1 ? sv.y : j == 2 ? sv.z : sv.w;
        if (dst >= lo && dst < hi) {
            int key = dst * 8 + src / RN;
            int pos = atomicAdd(&cursor[key], 1);
            csr[pos] = (u16)src;
        }
    }
}

__global__ void convw_kernel(const float* __restrict__ W1a, const float* __restrict__ W1b,
                             const float* __restrict__ W2a, const float* __restrict__ W2b,
                             u16* __restrict__ W1t_all, u16* __restrict__ W2t_all) {
    int mat = blockIdx.y;
    int idx = blockIdx.x * blockDim.x + threadIdx.x;
    const float* W; u16* Wt; int K, N;
    if (mat < 2) { W = mat ? W1b : W1a; Wt = W1t_all + (size_t)mat * 512 * 256; K = 512; N = 256; }
    else         { W = (mat == 3) ? W2b : W2a; Wt = W2t_all + (size_t)(mat - 2) * 256 * 128; K = 256; N = 128; }
    if (idx < K * N) {
        int k = idx / N, n = idx - k * N;
        Wt[(size_t)n * K + k] = f2bf_u16(W[idx]);
    }
}

// ---------------- MFMA GEMM: C = A @ Bt^T, 2-deep register-prefetch pipeline + ----------------
// ---------------- LDS-repacked full-line epilogue. K must be a multiple of 64. ----------------

template<bool A_F32, bool OUT_BF16, bool TRIANG, bool SCALE>
__global__ __launch_bounds__(256)
void gemm_kernel(const void* __restrict__ A0_, const void* __restrict__ A1_,
                 const u16* __restrict__ Bt0, const u16* __restrict__ Bt1,
                 void* __restrict__ C0_, void* __restrict__ C1_,
                 const float* __restrict__ rs0, const float* __restrict__ rs1,
                 int M, int N, int K) {
    int enc = blockIdx.z;
    const void* A_ = enc ? A1_ : A0_;
    const u16* Bt = enc ? Bt1 : Bt0;
    void* C_ = enc ? C1_ : C0_;
    const float* rowscale = enc ? rs1 : rs0;

    int it = blockIdx.x, jt = blockIdx.y;
    int t = threadIdx.x;
    int brow = it * 128, bcol = jt * 128;
    float* Cf = (float*)C_;
    if (TRIANG && jt < it) {
        f32x4 z = {0.f, 0.f, 0.f, 0.f};
        #pragma unroll
        for (int p = 0; p < 16; ++p) {
            int idx = p * 256 + t;
            int r = idx >> 5, c4 = idx & 31;
            __builtin_nontemporal_store(z, (f32x4*)(Cf + (size_t)(brow + r) * N + bcol + c4 * 4));
        }
        return;
    }
    __shared__ alignas(16) u16 smem[128 * 40 * 2];
    u16* As = smem;
    u16* Bs = smem + 128 * 40;
    int lane = t & 63, wv = t >> 6;
    int wr = wv >> 1, wc = wv & 1;
    f32x4 acc[4][4];
    #pragma unroll
    for (int m = 0; m < 4; ++m)
        #pragma unroll
        for (int n = 0; n < 4; ++n) acc[m][n] = f32x4{0.f, 0.f, 0.f, 0.f};

    // two named staging sets (static indexing only — runtime-indexed sets spill to scratch)
    float4 a_f0[4], a_f1[4];
    uint4  a_h0[2], a_h1[2];
    uint4  b_h0[2], b_h1[2];

#define LOADT(S, kk) do {                                                          \
    if constexpr (A_F32) {                                                         \
        const float* A = (const float*)A_;                                         \
        _Pragma("unroll")                                                          \
        for (int p = 0; p < 4; ++p) {                                              \
            int r = p * 32 + (t >> 3), c = (t & 7) * 4;                            \
            int gr = brow + r;                                                     \
            a_f##S[p] = make_float4(0.f, 0.f, 0.f, 0.f);                           \
            if (gr < M) a_f##S[p] = *(const float4*)(A + (size_t)gr * K + (kk) + c); \
        }                                                                          \
    } else {                                                                       \
        const u16* A = (const u16*)A_;                                             \
        _Pragma("unroll")                                                          \
        for (int p = 0; p < 2; ++p) {                                              \
            int r = p * 64 + (t >> 2), c = (t & 3) * 8;                            \
            int gr = brow + r;                                                     \
            a_h##S[p] = make_uint4(0u, 0u, 0u, 0u);                                \
            if (gr < M) a_h##S[p] = *(const uint4*)(A + (size_t)gr * K + (kk) + c); \
        }                                                                          \
    }                                                                              \
    _Pragma("unroll")                                                              \
    for (int p = 0; p < 2; ++p) {                                                  \
        int r = p * 64 + (t >> 2), c = (t & 3) * 8;                                \
        int gn = bcol + r;                                                         \
        b_h##S[p] = make_uint4(0u, 0u, 0u, 0u);                                    \
        if (gn < N) b_h##S[p] = *(const uint4*)(Bt + (size_t)gn * K + (kk) + c);   \
    }                                                                              \
} while (0)

#define STORET(S) do {                                                             \
    if constexpr (A_F32) {                                                         \
        _Pragma("unroll")                                                          \
        for (int p = 0; p < 4; ++p) {                                              \
            int r = p * 32 + (t >> 3), c = (t & 7) * 4;                            \
            u32 lo = (u32)f2bf_u16(a_f##S[p].x) | ((u32)f2bf_u16(a_f##S[p].y) << 16); \
            u32 hi = (u32)f2bf_u16(a_f##S[p].z) | ((u32)f2bf_u16(a_f##S[p].w) << 16); \
            *(uint2*)&As[r * 40 + c] = make_uint2(lo, hi);                         \
        }                                                                          \
    } else {                                                                       \
        _Pragma("unroll")                                                          \
        for (int p = 0; p < 2; ++p) {                                              \
            int r = p * 64 + (t >> 2), c = (t & 3) * 8;                            \
            *(uint4*)&As[r * 40 + c] = a_h##S[p];                                  \
        }                                                                          \
    }                                                                              \
    _Pragma("unroll")                                                              \
    for (int p = 0; p < 2; ++p) {                                                  \
        int r = p * 64 + (t >> 2), c = (t & 3) * 8;                                \
        *(uint4*)&Bs[r * 40 + c] = b_h##S[p];                                      \
    }                                                                              \
} while (0)

    auto compute = [&]() {
        int kg = (lane >> 4) * 8;
        short8 av[4], bv[4];
        #pragma unroll
        for (int m = 0; m < 4; ++m)
            av[m] = *(const short8*)&As[(wr * 64 + m * 16 + (lane & 15)) * 40 + kg];
        #pragma unroll
        for (int n = 0; n < 4; ++n)
            bv[n] = *(const short8*)&Bs[(wc * 64 + n * 16 + (lane & 15)) * 40 + kg];
        #pragma unroll
        for (int m = 0; m < 4; ++m)
            #pragma unroll
            for (int n = 0; n < 4; ++n)
                acc[m][n] = __builtin_amdgcn_mfma_f32_16x16x32_bf16(av[m], bv[n], acc[m][n], 0, 0, 0);
    };

    LOADT(0, 0);
    LOADT(1, 32);
    for (int k0 = 0; k0 < K; k0 += 64) {
        STORET(0);
        __syncthreads();
        if (k0 + 64 < K) LOADT(0, k0 + 64);   // 2 steps ahead — two MFMA phases of slack
        compute();
        __syncthreads();
        STORET(1);
        __syncthreads();
        if (k0 + 96 < K) LOADT(1, k0 + 96);
        compute();
        __syncthreads();
    }
#undef LOADT
#undef STORET

    // ---- epilogue: per-wave LDS repack -> full-line stores ----
    const int lane15 = lane & 15, lanehi = lane >> 4;
    if (OUT_BF16) {
        u16* stg = smem + wv * 1024;          // 16x64 u16 = 2 KB per wave
        #pragma unroll
        for (int m = 0; m < 4; ++m) {
            #pragma unroll
            for (int n = 0; n < 4; ++n)
                #pragma unroll
                for (int r = 0; r < 4; ++r) {
                    float v = acc[m][n][r];
                    if (SCALE) v *= rowscale[brow + wr * 64 + m * 16 + lanehi * 4 + r];
                    stg[(lanehi * 4 + r) * 64 + n * 16 + lane15] = f2bf_u16(v);
                }
            #pragma unroll
            for (int pass = 0; pass < 2; ++pass) {
                int lr = pass * 8 + (lane >> 3);
                int grow = brow + wr * 64 + m * 16 + lr;
                uint4 w = *(uint4*)&stg[lr * 64 + (lane & 7) * 8];
                if (grow < M)
                    *(uint4*)((u16*)C_ + (size_t)grow * N + bcol + wc * 64 + (lane & 7) * 8) = w;
            }
        }
    } else {
        float* stg = (float*)smem + wv * 1024;  // 16x64 f32 = 4 KB per wave
        #pragma unroll
        for (int m = 0; m < 4; ++m) {
            #pragma unroll
            for (int n = 0; n < 4; ++n)
                #pragma unroll
                for (int r = 0; r < 4; ++r) {
                    int row = brow + wr * 64 + m * 16 + lanehi * 4 + r;
                    int col = bcol + wc * 64 + n * 16 + lane15;
                    float v = acc[m][n][r];
                    if (SCALE) v *= rowscale[row];
                    if (TRIANG && col < row) v = 0.f;
                    stg[(lanehi * 4 + r) * 64 + n * 16 + lane15] = v;
                }
            #pragma unroll
            for (int pass = 0; pass < 4; ++pass) {
                int lr = pass * 4 + lanehi;
                int grow = brow + wr * 64 + m * 16 + lr;
                f32x4 w = *(f32x4*)&stg[lr * 64 + lane15 * 4];
                if (grow < M) {
                    float* dp = Cf + (size_t)grow * N + bcol + wc * 64 + lane15 * 4;
                    if (TRIANG) __builtin_nontemporal_store(w, (f32x4*)dp);
                    else *(f32x4*)dp = w;
                }
            }
        }
    }
}

// ---------------- aggregation (single enc): out[d] = nd[d]*sum Y[csr[e]] + b ----------------

template<int F, bool RELU, bool OUT_BF16>
__global__ __launch_bounds__(256)
void agg_kernel(const u16* __restrict__ Y, const int* __restrict__ rp2,
                const u16* __restrict__ csr, const float* __restrict__ nd,
                const float* __restrict__ bias, void* __restrict__ out) {
    constexpr int VPL = F / 64;
    int lane = threadIdx.x & 63;
    int node = blockIdx.x * 4 + (threadIdx.x >> 6);
    if (node >= NN) return;
    int e0 = rp2[node * 8], e1 = rp2[node * 8 + 8];
    float acc[VPL];
    #pragma unroll
    for (int j = 0; j < VPL; ++j) acc[j] = 0.f;
    const int off = lane * VPL;

    int e = e0;
    for (; e < e1 && (e & 7) != 0; ++e) {
        int s = csr[e];
        if (VPL == 4) {
            uint2 d = *(const uint2*)(Y + (size_t)s * F + off);
            acc[0] += bfu(d.x & 0xffffu); acc[1] += bfu(d.x >> 16);
            acc[2] += bfu(d.y & 0xffffu); acc[3] += bfu(d.y >> 16);
        } else {
            u32 d = *(const u32*)(Y + (size_t)s * F + off);
            acc[0] += bfu(d & 0xffffu); acc[1] += bfu(d >> 16);
        }
    }
    for (; e + 8 <= e1; e += 8) {
        uint4 iv = *(const uint4*)(csr + e);
        int s0 = iv.x & 0xffff, s1 = iv.x >> 16;
        int s2 = iv.y & 0xffff, s3 = iv.y >> 16;
        int s4 = iv.z & 0xffff, s5 = iv.z >> 16;
        int s6 = iv.w & 0xffff, s7 = iv.w >> 16;
        if (VPL == 4) {
            uint2 d0 = *(const uint2*)(Y + (size_t)s0 * F + off);
            uint2 d1 = *(const uint2*)(Y + (size_t)s1 * F + off);
            uint2 d2 = *(const uint2*)(Y + (size_t)s2 * F + off);
            uint2 d3 = *(const uint2*)(Y + (size_t)s3 * F + off);
            uint2 d4 = *(const uint2*)(Y + (size_t)s4 * F + off);
            uint2 d5 = *(const uint2*)(Y + (size_t)s5 * F + off);
            uint2 d6 = *(const uint2*)(Y + (size_t)s6 * F + off);
            uint2 d7 = *(const uint2*)(Y + (size_t)s7 * F + off);
            acc[0] += bfu(d0.x & 0xffffu); acc[1] += bfu(d0.x >> 16); acc[2] += bfu(d0.y & 0xffffu); acc[3] += bfu(d0.y >> 16);
            acc[0] += bfu(d1.x & 0xffffu); acc[1] += bfu(d1.x >> 16); acc[2] += bfu(d1.y & 0xffffu); acc[3] += bfu(d1.y >> 16);
            acc[0] += bfu(d2.x & 0xffffu); acc[1] += bfu(d2.x >> 16); acc[2] += bfu(d2.y & 0xffffu); acc[3] += bfu(d2.y >> 16);
            acc[0] += bfu(d3.x & 0xffffu); acc[1] += bfu(d3.x >> 16); acc[2] += bfu(d3.y & 0xffffu); acc[3] += bfu(d3.y >> 16);
            acc[0] += bfu(d4.x & 0xffffu); acc[1] += bfu(d4.x >> 16); acc[2] += bfu(d4.y & 0xffffu); acc[3] += bfu(d4.y >> 16);
            acc[0] += bfu(d5.x & 0xffffu); acc[1] += bfu(d5.x >> 16); acc[2] += bfu(d5.y & 0xffffu); acc[3] += bfu(d5.y >> 16);
            acc[0] += bfu(d6.x & 0xffffu); acc[1] += bfu(d6.x >> 16); acc[2] += bfu(d6.y & 0xffffu); acc[3] += bfu(d6.y >> 16);
            acc[0] += bfu(d7.x & 0xffffu); acc[1] += bfu(d7.x >> 16); acc[2] += bfu(d7.y & 0xffffu); acc[3] += bfu(d7.y >> 16);
        } else {
            u32 d0 = *(const u32*)(Y + (size_t)s0 * F + off);
            u32 d1 = *(const u32*)(Y + (size_t)s1 * F + off);
            u32 d2 = *(const u32*)(Y + (size_t)s2 * F + off);
            u32 d3 = *(const u32*)(Y + (size_t)s3 * F + off);
            u32 d4 = *(const u32*)(Y + (size_t)s4 * F + off);
            u32 d5 = *(const u32*)(Y + (size_t)s5 * F + off);
            u32 d6 = *(const u32*)(Y + (size_t)s6 * F + off);
            u32 d7 = *(const u32*)(Y + (size_t)s7 * F + off);
            acc[0] += bfu(d0 & 0xffffu); acc[1] += bfu(d0 >> 16);
            acc[0] += bfu(d1 & 0xffffu); acc[1] += bfu(d1 >> 16);
            acc[0] += bfu(d2 & 0xffffu); acc[1] += bfu(d2 >> 16);
            acc[0] += bfu(d3 & 0xffffu); acc[1] += bfu(d3 >> 16);
            acc[0] += bfu(d4 & 0xffffu); acc[1] += bfu(d4 >> 16);
            acc[0] += bfu(d5 & 0xffffu); acc[1] += bfu(d5 >> 16);
            acc[0] += bfu(d6 & 0xffffu); acc[1] += bfu(d6 >> 16);
            acc[0] += bfu(d7 & 0xffffu); acc[1] += bfu(d7 >> 16);
        }
    }
    for (; e < e1; ++e) {
        int s = csr[e];
        if (VPL == 4) {
            uint2 d = *(const uint2*)(Y + (size_t)s * F + off);
            acc[0] += bfu(d.x & 0xffffu); acc[1] += bfu(d.x >> 16);
            acc[2] += bfu(d.y & 0xffffu); acc[3] += bfu(d.y >> 16);
        } else {
            u32 d = *(const u32*)(Y + (size_t)s * F + off);
            acc[0] += bfu(d & 0xffffu); acc[1] += bfu(d >> 16);
        }
    }

    float ndv = nd[node];
    #pragma unroll
    for (int j = 0; j < VPL; ++j) {
        float o = acc[j] * ndv + bias[off + j];
        if (RELU) o = fmaxf(o, 0.f);
        if (OUT_BF16) ((u16*)out)[(size_t)node * F + off + j] = f2bf_u16(o);
        else ((float*)out)[(size_t)node * F + off + j] = o;
    }
}

// ---------------- normalize + build R = [ (a+b)/2 , (a-b)/(2*sqrt(3)) ] ----------------

__global__ __launch_bounds__(256)
void build_r_kernel(const float* __restrict__ H2a, const float* __restrict__ H2b,
                    const int* __restrict__ index, u16* __restrict__ R) {
    int lane = threadIdx.x & 63;
    int row = blockIdx.x * 4 + (threadIdx.x >> 6);
    int g = index[row];
    float2 a = *(const float2*)(H2a + (size_t)g * 128 + lane * 2);
    float2 b = *(const float2*)(H2b + (size_t)g * 128 + lane * 2);
    float sa = a.x * a.x + a.y * a.y;
    float sb = b.x * b.x + b.y * b.y;
    #pragma unroll
    for (int d = 1; d < 64; d <<= 1) {
        sa += __shfl_xor(sa, d, 64);
        sb += __shfl_xor(sb, d, 64);
    }
    float inva = 1.f / fmaxf(sqrtf(sa), 1e-12f);
    float invb = 1.f / fmaxf(sqrtf(sb), 1e-12f);
    float ax = a.x * inva, ay = a.y * inva;
    float bx = b.x * invb, by = b.y * invb;
    const float c2 = 0.5f, c3 = 0.28867513459481287f;  // 1/(2*sqrt(3))
    u16* Rp = R + (size_t)row * 256;
    Rp[lane * 2]           = f2bf_u16((ax + bx) * c2);
    Rp[lane * 2 + 1]       = f2bf_u16((ay + by) * c2);
    Rp[128 + lane * 2]     = f2bf_u16((ax - bx) * c3);
    Rp[128 + lane * 2 + 1] = f2bf_u16((ay - by) * c3);
}

// ---------------- launch ----------------

extern "C" void kernel_launch(void* const* d_in, const int* in_sizes, int n_in,
                              void* d_out, int out_size, void* d_ws, size_t ws_size,
                              hipStream_t stream) {
    (void)in_sizes; (void)n_in; (void)out_size; (void)ws_size;
    const float* raw0 = (const float*)d_in[0];
    const float* raw1 = (const float*)d_in[1];
    const int* src1 = (const int*)d_in[2], *dst1 = (const int*)d_in[3];
    const int* src2 = (const int*)d_in[4], *dst2 = (const int*)d_in[5];
    const int* index = (const int*)d_in[6];
    const float* W1a = (const float*)d_in[7];  const float* b1a = (const float*)d_in[8];
    const float* W2a = (const float*)d_in[9];  const float* b2a = (const float*)d_in[10];
    const float* W1b = (const float*)d_in[11]; const float* b1b = (const float*)d_in[12];
    const float* W2b = (const float*)d_in[13]; const float* b2b = (const float*)d_in[14];

    char* wp = (char*)d_ws;
    auto alloc = [&](size_t bytes) -> char* {
        char* r = wp;
        wp += (bytes + 255) & ~(size_t)255;
        return r;
    };
    float* norms   = (float*)alloc((size_t)4 * NN * 4);
    int*   deg2    = (int*)alloc((size_t)2 * NK * 4);
    int*   rp2     = (int*)alloc((size_t)2 * (NK + 1) * 4);
    int*   cur2    = (int*)alloc((size_t)2 * NK * 4);
    int*   tot     = (int*)alloc((size_t)2 * SAB * 4);
    u16*   csr_all = (u16*)alloc((size_t)2 * NE * 2);
    u16*   W1t     = (u16*)alloc((size_t)2 * 512 * 256 * 2);
    u16*   W2t     = (u16*)alloc((size_t)2 * 256 * 128 * 2);
    u16*   Y1      = (u16*)alloc((size_t)2 * NN * 256 * 2);
    u16*   H1      = (u16*)alloc((size_t)2 * NN * 256 * 2);
    u16*   Y2      = (u16*)alloc((size_t)2 * NN * 128 * 2);
    float* H2      = (float*)alloc((size_t)2 * NN * 128 * 4);
    u16*   R       = (u16*)alloc((size_t)NIDX * 256 * 2);
    // hist partials alias Y1 (51.2MB) and H1 (51.2MB): dead until gemm1/agg1.
    u32* partial2   = (u32*)Y1;
    u32* partial_out = (u32*)H1;

    const int MT = (NN + 127) / 128;  // 391 row tiles

    convw_kernel<<<dim3((512 * 256 + 255) / 256, 4), 256, 0, stream>>>(W1a, W1b, W2a, W2b, W1t, W2t);
    hist_kernel<<<dim3(NRANGE * HCH, 2), 256, 0, stream>>>(src1, dst1, src2, dst2, partial2, partial_out);
    reduce_hist_kernel<<<(2 * NN + 255) / 256, 256, 0, stream>>>(partial2, partial_out, deg2, norms);
    scanA_kernel<<<dim3(SAB, 2), 1024, 0, stream>>>(deg2, rp2, tot);
    scanB_kernel<<<1, 64, 0, stream>>>(tot);
    scanC_kernel<<<dim3((NK / 4 + 255) / 256, 2), 256, 0, stream>>>(rp2, cur2, tot);
    scatter_kernel<<<(2 * NE / 1024) * NRANGE, 256, 0, stream>>>(src1, dst1, src2, dst2, cur2, csr_all);

    // Y1 = (raw @ W1) * ns[row]   (both encoders)
    gemm_kernel<true, true, false, true><<<dim3(MT, 2, 2), 256, 0, stream>>>(
        raw0, raw1, W1t, W1t + (size_t)512 * 256, Y1, Y1 + (size_t)NN * 256,
        norms, norms + (size_t)2 * NN, NN, 256, 512);
    // H1 = relu(nd * agg(Y1) + b1), bf16 — per-enc sequential (L2 slice residency)
    agg_kernel<256, true, true><<<(NN + 3) / 4, 256, 0, stream>>>(
        Y1, rp2, csr_all, norms + NN, b1a, H1);
    agg_kernel<256, true, true><<<(NN + 3) / 4, 256, 0, stream>>>(
        Y1 + (size_t)NN * 256, rp2 + (NK + 1), csr_all + (size_t)NE, norms + 3 * NN, b1b,
        H1 + (size_t)NN * 256);
    // Y2 = (H1 @ W2) * ns[row]
    gemm_kernel<false, true, false, true><<<dim3(MT, 1, 2), 256, 0, stream>>>(
        H1, H1 + (size_t)NN * 256, W2t, W2t + (size_t)256 * 128, Y2, Y2 + (size_t)NN * 128,
        norms, norms + (size_t)2 * NN, NN, 128, 256);
    // H2 = nd * agg(Y2) + b2, f32
    agg_kernel<128, false, false><<<(NN + 3) / 4, 256, 0, stream>>>(
        Y2, rp2, csr_all, norms + NN, b2a, H2);
    agg_kernel<128, false, false><<<(NN + 3) / 4, 256, 0, stream>>>(
        Y2 + (size_t)NN * 128, rp2 + (NK + 1), csr_all + (size_t)NE, norms + 3 * NN, b2b,
        H2 + (size_t)NN * 128);

    // R = [ (c1n+c2n)/2 , (c1n-c2n)/(2*sqrt(3)) ]  (8192 x 256, bf16)
    build_r_kernel<<<NIDX / 4, 256, 0, stream>>>(H2, H2 + (size_t)NN * 128, index, R);
    // z = triu(R @ R^T), LDS-repacked NT full-line stores (lower tiles zero-filled in-kernel)
    gemm_kernel<false, false, true, false><<<dim3(64, 64, 1), 256, 0, stream>>>(
        R, R, R, R, (float*)d_out, (float*)d_out, nullptr, nullptr, NIDX, NIDX, 256);
}

// Round 11
// 676.836 us; speedup vs baseline: 1.4459x; 1.0438x over previous
//
#include <hip/hip_runtime.h>
#include <hip/hip_bf16.h>

using u16 = unsigned short;
using u32 = unsigned int;

typedef __attribute__((ext_vector_type(8))) short short8;
typedef __attribute__((ext_vector_type(4))) float f32x4;

__device__ __forceinline__ u16 f2bf_u16(float f) {
    __hip_bfloat16 h = __float2bfloat16(f);
    return __builtin_bit_cast(u16, h);
}
__device__ __forceinline__ float bfu(u32 u) { return __uint_as_float(u << 16); }

static constexpr int NN = 50000;
static constexpr int NE = 1600000;
static constexpr int NIDX = 8192;
static constexpr int NRANGE = 8;              // src ranges AND dst-ranges (XCD pinning)
static constexpr int RN = NN / NRANGE;        // 6250 nodes per range
static constexpr int HCH = 16;                // hist chunks per bucket
static constexpr int NK = NN * NRANGE;        // 400000 (dst,range) keys per enc
static constexpr int SAB = (NK + 4095) / 4096;  // 98 scanA blocks per enc
static constexpr int CAPB = 262144;           // per-bucket capacity (>> NE/8 + 147 sigma)
static constexpr int PEB = 8192;              // edges per partition block
static constexpr int PGX = (NE + PEB - 1) / PEB;  // 196
static constexpr int PSTG = 1536;             // LDS staging slots per bucket (+16 sigma)

// bcur layout: [enc][ {0..7}=dst-buckets, {8..15}=src-buckets ]  (32 ints)

// ---------------- partition: one edge read -> compacted per-range buckets ----------------

__global__ __launch_bounds__(256)
void partition_kernel(const int* __restrict__ s1, const int* __restrict__ d1,
                      const int* __restrict__ s2, const int* __restrict__ d2,
                      int* __restrict__ bcur, u32* __restrict__ ebuf_d, u16* __restrict__ ebuf_s) {
    __shared__ u32 stage_d[8][PSTG];
    __shared__ u16 stage_s[8][PSTG];
    __shared__ int cnt_d[8], cnt_s[8], base_d[8], base_s[8];
    int enc = blockIdx.y;
    const int* s = enc ? s2 : s1;
    const int* d = enc ? d2 : d1;
    if (threadIdx.x < 8) { cnt_d[threadIdx.x] = 0; cnt_s[threadIdx.x] = 0; }
    __syncthreads();
    int* bc_d = bcur + enc * 16;
    int* bc_s = bcur + enc * 16 + 8;
    u32* bd = ebuf_d + (size_t)enc * 8 * CAPB;
    u16* bs = ebuf_s + (size_t)enc * 8 * CAPB;
    int e0 = blockIdx.x * PEB;
    int e1 = min(e0 + PEB, NE);
    for (int e = e0 + threadIdx.x * 4; e < e1; e += 1024) {
        int4 sv = *(const int4*)(s + e);
        int4 dv = *(const int4*)(d + e);
        #pragma unroll
        for (int j = 0; j < 4; ++j) {
            int src = j == 0 ? sv.x : j == 1 ? sv.y : j == 2 ? sv.z : sv.w;
            int dst = j == 0 ? dv.x : j == 1 ? dv.y : j == 2 ? dv.z : dv.w;
            int rd = dst / RN;
            u32 entry = (u32)src | ((u32)(dst - rd * RN) << 16);
            int slot = atomicAdd(&cnt_d[rd], 1);
            if (slot < PSTG) stage_d[rd][slot] = entry;
            else { int gp = atomicAdd(&bc_d[rd], 1); bd[(size_t)rd * CAPB + gp] = entry; }
            int rs = src / RN;
            int slot2 = atomicAdd(&cnt_s[rs], 1);
            if (slot2 < PSTG) stage_s[rs][slot2] = (u16)(src - rs * RN);
            else { int gp = atomicAdd(&bc_s[rs], 1); bs[(size_t)rs * CAPB + gp] = (u16)(src - rs * RN); }
        }
    }
    __syncthreads();
    if (threadIdx.x < 8) {
        int b = threadIdx.x;
        base_d[b] = atomicAdd(&bc_d[b], min(cnt_d[b], PSTG));
        base_s[b] = atomicAdd(&bc_s[b], min(cnt_s[b], PSTG));
    }
    __syncthreads();
    #pragma unroll
    for (int b = 0; b < 8; ++b) {
        int nb = min(cnt_d[b], PSTG);
        for (int i = threadIdx.x; i < nb; i += 256)
            bd[(size_t)b * CAPB + base_d[b] + i] = stage_d[b][i];
        int ns = min(cnt_s[b], PSTG);
        for (int i = threadIdx.x; i < ns; i += 256)
            bs[(size_t)b * CAPB + base_s[b] + i] = stage_s[b][i];
    }
}

// ---------------- bucket hist: in-degree per (dst,src-range) + src out-degree ----------------
// grid.x = 8*HCH (stripe = x&7, chunk = x>>3), grid.y = enc + 2*type (0=in/dst, 1=out/src)

__global__ __launch_bounds__(256)
void bhist_kernel(const u32* __restrict__ ebuf_d, const u16* __restrict__ ebuf_s,
                  const int* __restrict__ bcur,
                  u32* __restrict__ partial2, u32* __restrict__ partial_out) {
    __shared__ u32 sh[RN * 2];    // 50 KB (out-type uses first RN/2 words)
    int stripe = blockIdx.x & 7, chunk = blockIdx.x >> 3;
    int enc = blockIdx.y & 1, type = blockIdx.y >> 1;
    if (type == 0) {
        for (int i = threadIdx.x; i < RN * 2; i += 256) sh[i] = 0;
        __syncthreads();
        int size = bcur[enc * 16 + stripe];
        int cs = (size + HCH - 1) / HCH;
        int lo = chunk * cs, hi = min(lo + cs, size);
        const u32* b = ebuf_d + ((size_t)enc * 8 + stripe) * CAPB;
        for (int i = lo + threadIdx.x; i < hi; i += 256) {
            u32 e = b[i];
            u32 idx = (e >> 16) * 8 + (e & 0xffffu) / RN;
            atomicAdd(&sh[idx >> 2], 1u << ((idx & 3) * 8));
        }
        __syncthreads();
        u32* p2 = partial2 + ((size_t)enc * HCH + chunk) * (NN * 2) + stripe * (RN * 2);
        for (int i = threadIdx.x; i < RN * 2; i += 256) p2[i] = sh[i];
    } else {
        for (int i = threadIdx.x; i < RN / 2; i += 256) sh[i] = 0;
        __syncthreads();
        int size = bcur[enc * 16 + 8 + stripe];
        int cs = (size + HCH - 1) / HCH;
        int lo = chunk * cs, hi = min(lo + cs, size);
        const u16* b = ebuf_s + ((size_t)enc * 8 + stripe) * CAPB;
        for (int i = lo + threadIdx.x; i < hi; i += 256) {
            u32 sl = b[i];
            atomicAdd(&sh[sl >> 1], 1u << ((sl & 1) * 16));
        }
        __syncthreads();
        u32* po = partial_out + ((size_t)enc * HCH + chunk) * (NN / 2) + stripe * (RN / 2);
        for (int i = threadIdx.x; i < RN / 2; i += 256) po[i] = sh[i];
    }
}

// sum byte/halfword partials; writes deg2 (for scan) and norms directly
__global__ void reduce_hist_kernel(const u32* __restrict__ partial2,
                                   const u32* __restrict__ partial_out,
                                   int* __restrict__ deg2, float* __restrict__ norms) {
    int i = blockIdx.x * blockDim.x + threadIdx.x;
    if (i >= 2 * NN) return;
    int enc = i / NN;
    int dst = i - enc * NN;
    int cnt[8];
    #pragma unroll
    for (int r = 0; r < 8; ++r) cnt[r] = 0;
    for (int c = 0; c < HCH; ++c) {
        const u32* p = partial2 + ((size_t)enc * HCH + c) * (NN * 2) + dst * 2;
        u32 w0 = p[0], w1 = p[1];
        cnt[0] += w0 & 0xff; cnt[1] += (w0 >> 8) & 0xff; cnt[2] += (w0 >> 16) & 0xff; cnt[3] += w0 >> 24;
        cnt[4] += w1 & 0xff; cnt[5] += (w1 >> 8) & 0xff; cnt[6] += (w1 >> 16) & 0xff; cnt[7] += w1 >> 24;
    }
    int* dp = deg2 + (size_t)enc * NK + dst * 8;
    int din = 0;
    #pragma unroll
    for (int r = 0; r < 8; ++r) { dp[r] = cnt[r]; din += cnt[r]; }
    norms[(enc * 2 + 1) * NN + dst] = rsqrtf(fmaxf((float)din, 1.f));
    int dout = 0;
    for (int c = 0; c < HCH; ++c) {
        u32 w = partial_out[((size_t)enc * HCH + c) * (NN / 2) + (dst >> 1)];
        dout += (w >> ((dst & 1) * 16)) & 0xffff;
    }
    norms[(enc * 2 + 0) * NN + dst] = rsqrtf(fmaxf((float)dout, 1.f));
}

// ---------------- 3-phase scan over deg2 (400000 per enc) ----------------

__global__ __launch_bounds__(1024)
void scanA_kernel(const int* __restrict__ deg2, int* __restrict__ rp2_all, int* __restrict__ tot) {
    int enc = blockIdx.y;
    const int* deg = deg2 + (size_t)enc * NK;
    int* rp = rp2_all + (size_t)enc * (NK + 1);
    __shared__ int wsum[16];
    int t = threadIdx.x, lane = t & 63, wid = t >> 6;
    int i0 = blockIdx.x * 4096 + t * 4;
    int4 v = make_int4(0, 0, 0, 0);
    bool in = (i0 + 3 < NK);
    if (in) v = *(const int4*)(deg + i0);
    int s = v.x + v.y + v.z + v.w;
    int x = s;
    #pragma unroll
    for (int d = 1; d < 64; d <<= 1) {
        int y = __shfl_up(x, d, 64);
        if (lane >= d) x += y;
    }
    if (lane == 63) wsum[wid] = x;
    __syncthreads();
    if (t == 0) {
        int run = 0;
        #pragma unroll
        for (int w = 0; w < 16; ++w) { int q = wsum[w]; wsum[w] = run; run += q; }
        tot[enc * SAB + blockIdx.x] = run;
    }
    __syncthreads();
    if (in) {
        int excl = wsum[wid] + x - s;
        rp[i0] = excl;
        rp[i0 + 1] = excl + v.x;
        rp[i0 + 2] = excl + v.x + v.y;
        rp[i0 + 3] = excl + v.x + v.y + v.z;
    }
}

__global__ void scanB_kernel(int* __restrict__ tot) {
    int enc = threadIdx.x;
    if (enc < 2) {
        int run = 0;
        for (int b = 0; b < SAB; ++b) { int q = tot[enc * SAB + b]; tot[enc * SAB + b] = run; run += q; }
    }
}

__global__ __launch_bounds__(256)
void scanC_kernel(int* __restrict__ rp2_all, int* __restrict__ cur2_all, const int* __restrict__ tot) {
    int enc = blockIdx.y;
    int* rp = rp2_all + (size_t)enc * (NK + 1);
    int* cur = cur2_all + (size_t)enc * NK;
    int idx = (blockIdx.x * 256 + threadIdx.x) * 4;
    if (idx < NK) {
        int off = tot[enc * SAB + (idx >> 12)];
        int4 v = *(const int4*)(rp + idx);
        v.x += off; v.y += off; v.z += off; v.w += off;
        *(int4*)(rp + idx) = v;
        *(int4*)(cur + idx) = v;
    }
    if (blockIdx.x == 0 && threadIdx.x == 0) rp[NK] = NE;
}

// ---------------- scatter from buckets: XCD-pinned, key = dst*8 + src_range ----------------

__global__ __launch_bounds__(256)
void scatter_kernel(const u32* __restrict__ ebuf_d, const int* __restrict__ bcur,
                    int* __restrict__ cur2_all, u16* __restrict__ csr_all) {
    int stripe = blockIdx.x & 7, chunk = blockIdx.x >> 3;   // 64 chunks per stripe
    int enc = blockIdx.y;
    int size = bcur[enc * 16 + stripe];
    int cs = (size + 63) / 64;
    int lo = chunk * cs, hi = min(lo + cs, size);
    const u32* b = ebuf_d + ((size_t)enc * 8 + stripe) * CAPB;
    int* cursor = cur2_all + (size_t)enc * NK;
    u16* csr = csr_all + (size_t)enc * NE;
    int base = stripe * RN;
    for (int i = lo + threadIdx.x; i < hi; i += 256) {
        u32 e = b[i];
        int src = e & 0xffff;
        int dst = base + (int)(e >> 16);
        int key = dst * 8 + src / RN;
        int pos = atomicAdd(&cursor[key], 1);
        csr[pos] = (u16)src;
    }
}

__global__ void convw_kernel(const float* __restrict__ W1a, const float* __restrict__ W1b,
                             const float* __restrict__ W2a, const float* __restrict__ W2b,
                             u16* __restrict__ W1t_all, u16* __restrict__ W2t_all) {
    int mat = blockIdx.y;
    int idx = blockIdx.x * blockDim.x + threadIdx.x;
    const float* W; u16* Wt; int K, N;
    if (mat < 2) { W = mat ? W1b : W1a; Wt = W1t_all + (size_t)mat * 512 * 256; K = 512; N = 256; }
    else         { W = (mat == 3) ? W2b : W2a; Wt = W2t_all + (size_t)(mat - 2) * 256 * 128; K = 256; N = 128; }
    if (idx < K * N) {
        int k = idx / N, n = idx - k * N;
        Wt[(size_t)n * K + k] = f2bf_u16(W[idx]);
    }
}

// ---------------- MFMA GEMM: C = A @ Bt^T, 2-deep register-prefetch pipeline + ----------------
// ---------------- LDS-repacked full-line epilogue. K must be a multiple of 64. ----------------

template<bool A_F32, bool OUT_BF16, bool TRIANG, bool SCALE>
__global__ __launch_bounds__(256)
void gemm_kernel(const void* __restrict__ A0_, const void* __restrict__ A1_,
                 const u16* __restrict__ Bt0, const u16* __restrict__ Bt1,
                 void* __restrict__ C0_, void* __restrict__ C1_,
                 const float* __restrict__ rs0, const float* __restrict__ rs1,
                 int M, int N, int K) {
    int enc = blockIdx.z;
    const void* A_ = enc ? A1_ : A0_;
    const u16* Bt = enc ? Bt1 : Bt0;
    void* C_ = enc ? C1_ : C0_;
    const float* rowscale = enc ? rs1 : rs0;

    int it = blockIdx.x, jt = blockIdx.y;
    int t = threadIdx.x;
    int brow = it * 128, bcol = jt * 128;
    float* Cf = (float*)C_;
    if (TRIANG && jt < it) {
        f32x4 z = {0.f, 0.f, 0.f, 0.f};
        #pragma unroll
        for (int p = 0; p < 16; ++p) {
            int idx = p * 256 + t;
            int r = idx >> 5, c4 = idx & 31;
            __builtin_nontemporal_store(z, (f32x4*)(Cf + (size_t)(brow + r) * N + bcol + c4 * 4));
        }
        return;
    }
    __shared__ alignas(16) u16 smem[128 * 40 * 2];
    u16* As = smem;
    u16* Bs = smem + 128 * 40;
    int lane = t & 63, wv = t >> 6;
    int wr = wv >> 1, wc = wv & 1;
    f32x4 acc[4][4];
    #pragma unroll
    for (int m = 0; m < 4; ++m)
        #pragma unroll
        for (int n = 0; n < 4; ++n) acc[m][n] = f32x4{0.f, 0.f, 0.f, 0.f};

    // two named staging sets (static indexing only — runtime-indexed sets spill to scratch)
    float4 a_f0[4], a_f1[4];
    uint4  a_h0[2], a_h1[2];
    uint4  b_h0[2], b_h1[2];

#define LOADT(S, kk) do {                                                          \
    if constexpr (A_F32) {                                                         \
        const float* A = (const float*)A_;                                         \
        _Pragma("unroll")                                                          \
        for (int p = 0; p < 4; ++p) {                                              \
            int r = p * 32 + (t >> 3), c = (t & 7) * 4;                            \
            int gr = brow + r;                                                     \
            a_f##S[p] = make_float4(0.f, 0.f, 0.f, 0.f);                           \
            if (gr < M) a_f##S[p] = *(const float4*)(A + (size_t)gr * K + (kk) + c); \
        }                                                                          \
    } else {                                                                       \
        const u16* A = (const u16*)A_;                                             \
        _Pragma("unroll")                                                          \
        for (int p = 0; p < 2; ++p) {                                              \
            int r = p * 64 + (t >> 2), c = (t & 3) * 8;                            \
            int gr = brow + r;                                                     \
            a_h##S[p] = make_uint4(0u, 0u, 0u, 0u);                                \
            if (gr < M) a_h##S[p] = *(const uint4*)(A + (size_t)gr * K + (kk) + c); \
        }                                                                          \
    }                                                                              \
    _Pragma("unroll")                                                              \
    for (int p = 0; p < 2; ++p) {                                                  \
        int r = p * 64 + (t >> 2), c = (t & 3) * 8;                                \
        int gn = bcol + r;                                                         \
        b_h##S[p] = make_uint4(0u, 0u, 0u, 0u);                                    \
        if (gn < N) b_h##S[p] = *(const uint4*)(Bt + (size_t)gn * K + (kk) + c);   \
    }                                                                              \
} while (0)

#define STORET(S) do {                                                             \
    if constexpr (A_F32) {                                                         \
        _Pragma("unroll")                                                          \
        for (int p = 0; p < 4; ++p) {                                              \
            int r = p * 32 + (t >> 3), c = (t & 7) * 4;                            \
            u32 lo = (u32)f2bf_u16(a_f##S[p].x) | ((u32)f2bf_u16(a_f##S[p].y) << 16); \
            u32 hi = (u32)f2bf_u16(a_f##S[p].z) | ((u32)f2bf_u16(a_f##S[p].w) << 16); \
            *(uint2*)&As[r * 40 + c] = make_uint2(lo, hi);                         \
        }                                                                          \
    } else {                                                                       \
        _Pragma("unroll")                                                          \
        for (int p = 0; p < 2; ++p) {                                              \
            int r = p * 64 + (t >> 2), c = (t & 3) * 8;                            \
            *(uint4*)&As[r * 40 + c] = a_h##S[p];                                  \
        }                                                                          \
    }                                                                              \
    _Pragma("unroll")                                                              \
    for (int p = 0; p < 2; ++p) {                                                  \
        int r = p * 64 + (t >> 2), c = (t & 3) * 8;                                \
        *(uint4*)&Bs[r * 40 + c] = b_h##S[p];                                      \
    }                                                                              \
} while (0)

    auto compute = [&]() {
        int kg = (lane >> 4) * 8;
        short8 av[4], bv[4];
        #pragma unroll
        for (int m = 0; m < 4; ++m)
            av[m] = *(const short8*)&As[(wr * 64 + m * 16 + (lane & 15)) * 40 + kg];
        #pragma unroll
        for (int n = 0; n < 4; ++n)
            bv[n] = *(const short8*)&Bs[(wc * 64 + n * 16 + (lane & 15)) * 40 + kg];
        #pragma unroll
        for (int m = 0; m < 4; ++m)
            #pragma unroll
            for (int n = 0; n < 4; ++n)
                acc[m][n] = __builtin_amdgcn_mfma_f32_16x16x32_bf16(av[m], bv[n], acc[m][n], 0, 0, 0);
    };

    LOADT(0, 0);
    LOADT(1, 32);
    for (int k0 = 0; k0 < K; k0 += 64) {
        STORET(0);
        __syncthreads();
        if (k0 + 64 < K) LOADT(0, k0 + 64);   // 2 steps ahead — two MFMA phases of slack
        compute();
        __syncthreads();
        STORET(1);
        __syncthreads();
        if (k0 + 96 < K) LOADT(1, k0 + 96);
        compute();
        __syncthreads();
    }
#undef LOADT
#undef STORET

    // ---- epilogue: per-wave LDS repack -> full-line stores ----
    const int lane15 = lane & 15, lanehi = lane >> 4;
    if (OUT_BF16) {
        u16* stg = smem + wv * 1024;          // 16x64 u16 = 2 KB per wave
        #pragma unroll
        for (int m = 0; m < 4; ++m) {
            #pragma unroll
            for (int n = 0; n < 4; ++n)
                #pragma unroll
                for (int r = 0; r < 4; ++r) {
                    float v = acc[m][n][r];
                    if (SCALE) v *= rowscale[brow + wr * 64 + m * 16 + lanehi * 4 + r];
                    stg[(lanehi * 4 + r) * 64 + n * 16 + lane15] = f2bf_u16(v);
                }
            #pragma unroll
            for (int pass = 0; pass < 2; ++pass) {
                int lr = pass * 8 + (lane >> 3);
                int grow = brow + wr * 64 + m * 16 + lr;
                uint4 w = *(uint4*)&stg[lr * 64 + (lane & 7) * 8];
                if (grow < M)
                    *(uint4*)((u16*)C_ + (size_t)grow * N + bcol + wc * 64 + (lane & 7) * 8) = w;
            }
        }
    } else {
        float* stg = (float*)smem + wv * 1024;  // 16x64 f32 = 4 KB per wave
        #pragma unroll
        for (int m = 0; m < 4; ++m) {
            #pragma unroll
            for (int n = 0; n < 4; ++n)
                #pragma unroll
                for (int r = 0; r < 4; ++r) {
                    int row = brow + wr * 64 + m * 16 + lanehi * 4 + r;
                    int col = bcol + wc * 64 + n * 16 + lane15;
                    float v = acc[m][n][r];
                    if (SCALE) v *= rowscale[row];
                    if (TRIANG && col < row) v = 0.f;
                    stg[(lanehi * 4 + r) * 64 + n * 16 + lane15] = v;
                }
            #pragma unroll
            for (int pass = 0; pass < 4; ++pass) {
                int lr = pass * 4 + lanehi;
                int grow = brow + wr * 64 + m * 16 + lr;
                f32x4 w = *(f32x4*)&stg[lr * 64 + lane15 * 4];
                if (grow < M) {
                    float* dp = Cf + (size_t)grow * N + bcol + wc * 64 + lane15 * 4;
                    if (TRIANG) __builtin_nontemporal_store(w, (f32x4*)dp);
                    else *(f32x4*)dp = w;
                }
            }
        }
    }
}

// ---------------- aggregation (single enc): out[d] = nd[d]*sum Y[csr[e]] + b ----------------

template<int F, bool RELU, bool OUT_BF16>
__global__ __launch_bounds__(256)
void agg_kernel(const u16* __restrict__ Y, const int* __restrict__ rp2,
                const u16* __restrict__ csr, const float* __restrict__ nd,
                const float* __restrict__ bias, void* __restrict__ out) {
    constexpr int VPL = F / 64;
    int lane = threadIdx.x & 63;
    int node = blockIdx.x * 4 + (threadIdx.x >> 6);
    if (node >= NN) return;
    int e0 = rp2[node * 8], e1 = rp2[node * 8 + 8];
    float acc[VPL];
    #pragma unroll
    for (int j = 0; j < VPL; ++j) acc[j] = 0.f;
    const int off = lane * VPL;

    int e = e0;
    for (; e < e1 && (e & 7) != 0; ++e) {
        int s = csr[e];
        if (VPL == 4) {
            uint2 d = *(const uint2*)(Y + (size_t)s * F + off);
            acc[0] += bfu(d.x & 0xffffu); acc[1] += bfu(d.x >> 16);
            acc[2] += bfu(d.y & 0xffffu); acc[3] += bfu(d.y >> 16);
        } else {
            u32 d = *(const u32*)(Y + (size_t)s * F + off);
            acc[0] += bfu(d & 0xffffu); acc[1] += bfu(d >> 16);
        }
    }
    for (; e + 8 <= e1; e += 8) {
        uint4 iv = *(const uint4*)(csr + e);
        int s0 = iv.x & 0xffff, s1 = iv.x >> 16;
        int s2 = iv.y & 0xffff, s3 = iv.y >> 16;
        int s4 = iv.z & 0xffff, s5 = iv.z >> 16;
        int s6 = iv.w & 0xffff, s7 = iv.w >> 16;
        if (VPL == 4) {
            uint2 d0 = *(const uint2*)(Y + (size_t)s0 * F + off);
            uint2 d1 = *(const uint2*)(Y + (size_t)s1 * F + off);
            uint2 d2 = *(const uint2*)(Y + (size_t)s2 * F + off);
            uint2 d3 = *(const uint2*)(Y + (size_t)s3 * F + off);
            uint2 d4 = *(const uint2*)(Y + (size_t)s4 * F + off);
            uint2 d5 = *(const uint2*)(Y + (size_t)s5 * F + off);
            uint2 d6 = *(const uint2*)(Y + (size_t)s6 * F + off);
            uint2 d7 = *(const uint2*)(Y + (size_t)s7 * F + off);
            acc[0] += bfu(d0.x & 0xffffu); acc[1] += bfu(d0.x >> 16); acc[2] += bfu(d0.y & 0xffffu); acc[3] += bfu(d0.y >> 16);
            acc[0] += bfu(d1.x & 0xffffu); acc[1] += bfu(d1.x >> 16); acc[2] += bfu(d1.y & 0xffffu); acc[3] += bfu(d1.y >> 16);
            acc[0] += bfu(d2.x & 0xffffu); acc[1] += bfu(d2.x >> 16); acc[2] += bfu(d2.y & 0xffffu); acc[3] += bfu(d2.y >> 16);
            acc[0] += bfu(d3.x & 0xffffu); acc[1] += bfu(d3.x >> 16); acc[2] += bfu(d3.y & 0xffffu); acc[3] += bfu(d3.y >> 16);
            acc[0] += bfu(d4.x & 0xffffu); acc[1] += bfu(d4.x >> 16); acc[2] += bfu(d4.y & 0xffffu); acc[3] += bfu(d4.y >> 16);
            acc[0] += bfu(d5.x & 0xffffu); acc[1] += bfu(d5.x >> 16); acc[2] += bfu(d5.y & 0xffffu); acc[3] += bfu(d5.y >> 16);
            acc[0] += bfu(d6.x & 0xffffu); acc[1] += bfu(d6.x >> 16); acc[2] += bfu(d6.y & 0xffffu); acc[3] += bfu(d6.y >> 16);
            acc[0] += bfu(d7.x & 0xffffu); acc[1] += bfu(d7.x >> 16); acc[2] += bfu(d7.y & 0xffffu); acc[3] += bfu(d7.y >> 16);
        } else {
            u32 d0 = *(const u32*)(Y + (size_t)s0 * F + off);
            u32 d1 = *(const u32*)(Y + (size_t)s1 * F + off);
            u32 d2 = *(const u32*)(Y + (size_t)s2 * F + off);
            u32 d3 = *(const u32*)(Y + (size_t)s3 * F + off);
            u32 d4 = *(const u32*)(Y + (size_t)s4 * F + off);
            u32 d5 = *(const u32*)(Y + (size_t)s5 * F + off);
            u32 d6 = *(const u32*)(Y + (size_t)s6 * F + off);
            u32 d7 = *(const u32*)(Y + (size_t)s7 * F + off);
            acc[0] += bfu(d0 & 0xffffu); acc[1] += bfu(d0 >> 16);
            acc[0] += bfu(d1 & 0xffffu); acc[1] += bfu(d1 >> 16);
            acc[0] += bfu(d2 & 0xffffu); acc[1] += bfu(d2 >> 16);
            acc[0] += bfu(d3 & 0xffffu); acc[1] += bfu(d3 >> 16);
            acc[0] += bfu(d4 & 0xffffu); acc[1] += bfu(d4 >> 16);
            acc[0] += bfu(d5 & 0xffffu); acc[1] += bfu(d5 >> 16);
            acc[0] += bfu(d6 & 0xffffu); acc[1] += bfu(d6 >> 16);
            acc[0] += bfu(d7 & 0xffffu); acc[1] += bfu(d7 >> 16);
        }
    }
    for (; e < e1; ++e) {
        int s = csr[e];
        if (VPL == 4) {
            uint2 d = *(const uint2*)(Y + (size_t)s * F + off);
            acc[0] += bfu(d.x & 0xffffu); acc[1] += bfu(d.x >> 16);
            acc[2] += bfu(d.y & 0xffffu); acc[3] += bfu(d.y >> 16);
        } else {
            u32 d = *(const u32*)(Y + (size_t)s * F + off);
            acc[0] += bfu(d & 0xffffu); acc[1] += bfu(d >> 16);
        }
    }

    float ndv = nd[node];
    #pragma unroll
    for (int j = 0; j < VPL; ++j) {
        float o = acc[j] * ndv + bias[off + j];
        if (RELU) o = fmaxf(o, 0.f);
        if (OUT_BF16) ((u16*)out)[(size_t)node * F + off + j] = f2bf_u16(o);
        else ((float*)out)[(size_t)node * F + off + j] = o;
    }
}

// ---------------- normalize + build R = [ (a+b)/2 , (a-b)/(2*sqrt(3)) ] ----------------

__global__ __launch_bounds__(256)
void build_r_kernel(const float* __restrict__ H2a, const float* __restrict__ H2b,
                    const int* __restrict__ index, u16* __restrict__ R) {
    int lane = threadIdx.x & 63;
    int row = blockIdx.x * 4 + (threadIdx.x >> 6);
    int g = index[row];
    float2 a = *(const float2*)(H2a + (size_t)g * 128 + lane * 2);
    float2 b = *(const float2*)(H2b + (size_t)g * 128 + lane * 2);
    float sa = a.x * a.x + a.y * a.y;
    float sb = b.x * b.x + b.y * b.y;
    #pragma unroll
    for (int d = 1; d < 64; d <<= 1) {
        sa += __shfl_xor(sa, d, 64);
        sb += __shfl_xor(sb, d, 64);
    }
    float inva = 1.f / fmaxf(sqrtf(sa), 1e-12f);
    float invb = 1.f / fmaxf(sqrtf(sb), 1e-12f);
    float ax = a.x * inva, ay = a.y * inva;
    float bx = b.x * invb, by = b.y * invb;
    const float c2 = 0.5f, c3 = 0.28867513459481287f;  // 1/(2*sqrt(3))
    u16* Rp = R + (size_t)row * 256;
    Rp[lane * 2]           = f2bf_u16((ax + bx) * c2);
    Rp[lane * 2 + 1]       = f2bf_u16((ay + by) * c2);
    Rp[128 + lane * 2]     = f2bf_u16((ax - bx) * c3);
    Rp[128 + lane * 2 + 1] = f2bf_u16((ay - by) * c3);
}

// ---------------- launch ----------------

extern "C" void kernel_launch(void* const* d_in, const int* in_sizes, int n_in,
                              void* d_out, int out_size, void* d_ws, size_t ws_size,
                              hipStream_t stream) {
    (void)in_sizes; (void)n_in; (void)out_size; (void)ws_size;
    const float* raw0 = (const float*)d_in[0];
    const float* raw1 = (const float*)d_in[1];
    const int* src1 = (const int*)d_in[2], *dst1 = (const int*)d_in[3];
    const int* src2 = (const int*)d_in[4], *dst2 = (const int*)d_in[5];
    const int* index = (const int*)d_in[6];
    const float* W1a = (const float*)d_in[7];  const float* b1a = (const float*)d_in[8];
    const float* W2a = (const float*)d_in[9];  const float* b2a = (const float*)d_in[10];
    const float* W1b = (const float*)d_in[11]; const float* b1b = (const float*)d_in[12];
    const float* W2b = (const float*)d_in[13]; const float* b2b = (const float*)d_in[14];

    char* wp = (char*)d_ws;
    auto alloc = [&](size_t bytes) -> char* {
        char* r = wp;
        wp += (bytes + 255) & ~(size_t)255;
        return r;
    };
    float* norms   = (float*)alloc((size_t)4 * NN * 4);
    int*   deg2    = (int*)alloc((size_t)2 * NK * 4);
    int*   rp2     = (int*)alloc((size_t)2 * (NK + 1) * 4);
    int*   cur2    = (int*)alloc((size_t)2 * NK * 4);
    int*   tot     = (int*)alloc((size_t)2 * SAB * 4);
    int*   bcur    = (int*)alloc(32 * 4);
    u16*   csr_all = (u16*)alloc((size_t)2 * NE * 2);
    u16*   W1t     = (u16*)alloc((size_t)2 * 512 * 256 * 2);
    u16*   W2t     = (u16*)alloc((size_t)2 * 256 * 128 * 2);
    u16*   Y1      = (u16*)alloc((size_t)2 * NN * 256 * 2);
    u16*   H1      = (u16*)alloc((size_t)2 * NN * 256 * 2);
    u16*   Y2      = (u16*)alloc((size_t)2 * NN * 128 * 2);
    float* H2      = (float*)alloc((size_t)2 * NN * 128 * 4);
    u16*   R       = (u16*)alloc((size_t)NIDX * 256 * 2);
    // aliases (dead ranges at time of use):
    u32* partial2    = (u32*)Y1;   // 12.8 MB in Y1 (51.2 MB); dead before gemm1 writes Y1
    u32* partial_out = (u32*)H1;   //  3.2 MB in H1; dead before agg1 writes H1
    u32* ebuf_d      = (u32*)Y2;   // 16.8 MB in Y2 (25.6 MB); consumed by bhist/scatter, dead before gemm2
    u16* ebuf_s      = (u16*)H2;   //  8.4 MB in H2 (51.2 MB); consumed by bhist, dead before agg2

    const int MT = (NN + 127) / 128;  // 391 row tiles

    hipMemsetAsync(bcur, 0, 32 * 4, stream);
    convw_kernel<<<dim3((512 * 256 + 255) / 256, 4), 256, 0, stream>>>(W1a, W1b, W2a, W2b, W1t, W2t);
    partition_kernel<<<dim3(PGX, 2), 256, 0, stream>>>(src1, dst1, src2, dst2, bcur, ebuf_d, ebuf_s);
    bhist_kernel<<<dim3(8 * HCH, 4), 256, 0, stream>>>(ebuf_d, ebuf_s, bcur, partial2, partial_out);
    reduce_hist_kernel<<<(2 * NN + 255) / 256, 256, 0, stream>>>(partial2, partial_out, deg2, norms);
    scanA_kernel<<<dim3(SAB, 2), 1024, 0, stream>>>(deg2, rp2, tot);
    scanB_kernel<<<1, 64, 0, stream>>>(tot);
    scanC_kernel<<<dim3((NK / 4 + 255) / 256, 2), 256, 0, stream>>>(rp2, cur2, tot);
    scatter_kernel<<<dim3(8 * 64, 2), 256, 0, stream>>>(ebuf_d, bcur, cur2, csr_all);

    // Y1 = (raw @ W1) * ns[row]   (both encoders)
    gemm_kernel<true, true, false, true><<<dim3(MT, 2, 2), 256, 0, stream>>>(
        raw0, raw1, W1t, W1t + (size_t)512 * 256, Y1, Y1 + (size_t)NN * 256,
        norms, norms + (size_t)2 * NN, NN, 256, 512);
    // H1 = relu(nd * agg(Y1) + b1), bf16 — per-enc sequential (L2 slice residency)
    agg_kernel<256, true, true><<<(NN + 3) / 4, 256, 0, stream>>>(
        Y1, rp2, csr_all, norms + NN, b1a, H1);
    agg_kernel<256, true, true><<<(NN + 3) / 4, 256, 0, stream>>>(
        Y1 + (size_t)NN * 256, rp2 + (NK + 1), csr_all + (size_t)NE, norms + 3 * NN, b1b,
        H1 + (size_t)NN * 256);
    // Y2 = (H1 @ W2) * ns[row]
    gemm_kernel<false, true, false, true><<<dim3(MT, 1, 2), 256, 0, stream>>>(
        H1, H1 + (size_t)NN * 256, W2t, W2t + (size_t)256 * 128, Y2, Y2 + (size_t)NN * 128,
        norms, norms + (size_t)2 * NN, NN, 128, 256);
    // H2 = nd * agg(Y2) + b2, f32
    agg_kernel<128, false, false><<<(NN + 3) / 4, 256, 0, stream>>>(
        Y2, rp2, csr_all, norms + NN, b2a, H2);
    agg_kernel<128, false, false><<<(NN + 3) / 4, 256, 0, stream>>>(
        Y2 + (size_t)NN * 128, rp2 + (NK + 1), csr_all + (size_t)NE, norms + 3 * NN, b2b,
        H2 + (size_t)NN * 128);

    // R = [ (c1n+c2n)/2 , (c1n-c2n)/(2*sqrt(3)) ]  (8192 x 256, bf16)
    build_r_kernel<<<NIDX / 4, 256, 0, stream>>>(H2, H2 + (size_t)NN * 128, index, R);
    // z = triu(R @ R^T), LDS-repacked NT full-line stores (lower tiles zero-filled in-kernel)
    gemm_kernel<false, false, true, false><<<dim3(64, 64, 1), 256, 0, stream>>>(
        R, R, R, R, (float*)d_out, (float*)d_out, nullptr, nullptr, NIDX, NIDX, 256);
}

// Round 12
// 676.002 us; speedup vs baseline: 1.4477x; 1.0012x over previous
//
#include <hip/hip_runtime.h>
#include <hip/hip_bf16.h>

using u16 = unsigned short;
using u32 = unsigned int;

typedef __attribute__((ext_vector_type(8))) short short8;
typedef __attribute__((ext_vector_type(4))) float f32x4;

__device__ __forceinline__ u16 f2bf_u16(float f) {
    __hip_bfloat16 h = __float2bfloat16(f);
    return __builtin_bit_cast(u16, h);
}
__device__ __forceinline__ float bfu(u32 u) { return __uint_as_float(u << 16); }

static constexpr int NN = 50000;
static constexpr int NE = 1600000;
static constexpr int NIDX = 8192;
static constexpr int NRANGE = 8;              // src ranges AND dst-ranges (XCD pinning)
static constexpr int RN = NN / NRANGE;        // 6250 nodes per range
static constexpr int HCH = 16;                // hist chunks per bucket
static constexpr int NK = NN * NRANGE;        // 400000 (dst,range) keys per enc
static constexpr int SAB = (NK + 4095) / 4096;  // 98 scanA blocks per enc
static constexpr int CAPB = 262144;           // per-bucket capacity
static constexpr int PEB = 8192;              // edges per partition block
static constexpr int PGX = (NE + PEB - 1) / PEB;  // 196
static constexpr int PSTG = 1536;             // LDS staging slots per bucket
static constexpr int ZLB = 64 * 63 / 2;       // 2016 lower-tri z tiles
static constexpr int ZUB = 64 * 65 / 2;       // 2080 upper-tri z tiles
static constexpr int AGB = (NN + 3) / 4;      // 12500 agg blocks

// ---------------- partition: one edge read -> compacted per-range buckets ----------------

__global__ __launch_bounds__(256)
void partition_kernel(const int* __restrict__ s1, const int* __restrict__ d1,
                      const int* __restrict__ s2, const int* __restrict__ d2,
                      int* __restrict__ bcur, u32* __restrict__ ebuf_d, u16* __restrict__ ebuf_s) {
    __shared__ u32 stage_d[8][PSTG];
    __shared__ u16 stage_s[8][PSTG];
    __shared__ int cnt_d[8], cnt_s[8], base_d[8], base_s[8];
    int enc = blockIdx.y;
    const int* s = enc ? s2 : s1;
    const int* d = enc ? d2 : d1;
    if (threadIdx.x < 8) { cnt_d[threadIdx.x] = 0; cnt_s[threadIdx.x] = 0; }
    __syncthreads();
    int* bc_d = bcur + enc * 16;
    int* bc_s = bcur + enc * 16 + 8;
    u32* bd = ebuf_d + (size_t)enc * 8 * CAPB;
    u16* bs = ebuf_s + (size_t)enc * 8 * CAPB;
    int e0 = blockIdx.x * PEB;
    int e1 = min(e0 + PEB, NE);
    for (int e = e0 + threadIdx.x * 4; e < e1; e += 1024) {
        int4 sv = *(const int4*)(s + e);
        int4 dv = *(const int4*)(d + e);
        #pragma unroll
        for (int j = 0; j < 4; ++j) {
            int src = j == 0 ? sv.x : j == 1 ? sv.y : j == 2 ? sv.z : sv.w;
            int dst = j == 0 ? dv.x : j == 1 ? dv.y : j == 2 ? dv.z : dv.w;
            int rd = dst / RN;
            u32 entry = (u32)src | ((u32)(dst - rd * RN) << 16);
            int slot = atomicAdd(&cnt_d[rd], 1);
            if (slot < PSTG) stage_d[rd][slot] = entry;
            else { int gp = atomicAdd(&bc_d[rd], 1); bd[(size_t)rd * CAPB + gp] = entry; }
            int rs = src / RN;
            int slot2 = atomicAdd(&cnt_s[rs], 1);
            if (slot2 < PSTG) stage_s[rs][slot2] = (u16)(src - rs * RN);
            else { int gp = atomicAdd(&bc_s[rs], 1); bs[(size_t)rs * CAPB + gp] = (u16)(src - rs * RN); }
        }
    }
    __syncthreads();
    if (threadIdx.x < 8) {
        int b = threadIdx.x;
        base_d[b] = atomicAdd(&bc_d[b], min(cnt_d[b], PSTG));
        base_s[b] = atomicAdd(&bc_s[b], min(cnt_s[b], PSTG));
    }
    __syncthreads();
    #pragma unroll
    for (int b = 0; b < 8; ++b) {
        int nb = min(cnt_d[b], PSTG);
        for (int i = threadIdx.x; i < nb; i += 256)
            bd[(size_t)b * CAPB + base_d[b] + i] = stage_d[b][i];
        int ns = min(cnt_s[b], PSTG);
        for (int i = threadIdx.x; i < ns; i += 256)
            bs[(size_t)b * CAPB + base_s[b] + i] = stage_s[b][i];
    }
}

// ---------------- bucket hist: in-degree per (dst,src-range) + src out-degree ----------------

__global__ __launch_bounds__(256)
void bhist_kernel(const u32* __restrict__ ebuf_d, const u16* __restrict__ ebuf_s,
                  const int* __restrict__ bcur,
                  u32* __restrict__ partial2, u32* __restrict__ partial_out) {
    __shared__ u32 sh[RN * 2];
    int stripe = blockIdx.x & 7, chunk = blockIdx.x >> 3;
    int enc = blockIdx.y & 1, type = blockIdx.y >> 1;
    if (type == 0) {
        for (int i = threadIdx.x; i < RN * 2; i += 256) sh[i] = 0;
        __syncthreads();
        int size = bcur[enc * 16 + stripe];
        int cs = (size + HCH - 1) / HCH;
        int lo = chunk * cs, hi = min(lo + cs, size);
        const u32* b = ebuf_d + ((size_t)enc * 8 + stripe) * CAPB;
        for (int i = lo + threadIdx.x; i < hi; i += 256) {
            u32 e = b[i];
            u32 idx = (e >> 16) * 8 + (e & 0xffffu) / RN;
            atomicAdd(&sh[idx >> 2], 1u << ((idx & 3) * 8));
        }
        __syncthreads();
        u32* p2 = partial2 + ((size_t)enc * HCH + chunk) * (NN * 2) + stripe * (RN * 2);
        for (int i = threadIdx.x; i < RN * 2; i += 256) p2[i] = sh[i];
    } else {
        for (int i = threadIdx.x; i < RN / 2; i += 256) sh[i] = 0;
        __syncthreads();
        int size = bcur[enc * 16 + 8 + stripe];
        int cs = (size + HCH - 1) / HCH;
        int lo = chunk * cs, hi = min(lo + cs, size);
        const u16* b = ebuf_s + ((size_t)enc * 8 + stripe) * CAPB;
        for (int i = lo + threadIdx.x; i < hi; i += 256) {
            u32 sl = b[i];
            atomicAdd(&sh[sl >> 1], 1u << ((sl & 1) * 16));
        }
        __syncthreads();
        u32* po = partial_out + ((size_t)enc * HCH + chunk) * (NN / 2) + stripe * (RN / 2);
        for (int i = threadIdx.x; i < RN / 2; i += 256) po[i] = sh[i];
    }
}

// sum byte/halfword partials; writes deg2 (for scan) and norms directly
__global__ void reduce_hist_kernel(const u32* __restrict__ partial2,
                                   const u32* __restrict__ partial_out,
                                   int* __restrict__ deg2, float* __restrict__ norms) {
    int i = blockIdx.x * blockDim.x + threadIdx.x;
    if (i >= 2 * NN) return;
    int enc = i / NN;
    int dst = i - enc * NN;
    int cnt[8];
    #pragma unroll
    for (int r = 0; r < 8; ++r) cnt[r] = 0;
    for (int c = 0; c < HCH; ++c) {
        const u32* p = partial2 + ((size_t)enc * HCH + c) * (NN * 2) + dst * 2;
        u32 w0 = p[0], w1 = p[1];
        cnt[0] += w0 & 0xff; cnt[1] += (w0 >> 8) & 0xff; cnt[2] += (w0 >> 16) & 0xff; cnt[3] += w0 >> 24;
        cnt[4] += w1 & 0xff; cnt[5] += (w1 >> 8) & 0xff; cnt[6] += (w1 >> 16) & 0xff; cnt[7] += w1 >> 24;
    }
    int* dp = deg2 + (size_t)enc * NK + dst * 8;
    int din = 0;
    #pragma unroll
    for (int r = 0; r < 8; ++r) { dp[r] = cnt[r]; din += cnt[r]; }
    norms[(enc * 2 + 1) * NN + dst] = rsqrtf(fmaxf((float)din, 1.f));
    int dout = 0;
    for (int c = 0; c < HCH; ++c) {
        u32 w = partial_out[((size_t)enc * HCH + c) * (NN / 2) + (dst >> 1)];
        dout += (w >> ((dst & 1) * 16)) & 0xffff;
    }
    norms[(enc * 2 + 0) * NN + dst] = rsqrtf(fmaxf((float)dout, 1.f));
}

// ---------------- 2-phase scan over deg2 (scanC self-computes block offsets) ----------------

__global__ __launch_bounds__(1024)
void scanA_kernel(const int* __restrict__ deg2, int* __restrict__ rp2_all, int* __restrict__ tot) {
    int enc = blockIdx.y;
    const int* deg = deg2 + (size_t)enc * NK;
    int* rp = rp2_all + (size_t)enc * (NK + 1);
    __shared__ int wsum[16];
    int t = threadIdx.x, lane = t & 63, wid = t >> 6;
    int i0 = blockIdx.x * 4096 + t * 4;
    int4 v = make_int4(0, 0, 0, 0);
    bool in = (i0 + 3 < NK);
    if (in) v = *(const int4*)(deg + i0);
    int s = v.x + v.y + v.z + v.w;
    int x = s;
    #pragma unroll
    for (int d = 1; d < 64; d <<= 1) {
        int y = __shfl_up(x, d, 64);
        if (lane >= d) x += y;
    }
    if (lane == 63) wsum[wid] = x;
    __syncthreads();
    if (t == 0) {
        int run = 0;
        #pragma unroll
        for (int w = 0; w < 16; ++w) { int q = wsum[w]; wsum[w] = run; run += q; }
        tot[enc * SAB + blockIdx.x] = run;
    }
    __syncthreads();
    if (in) {
        int excl = wsum[wid] + x - s;
        rp[i0] = excl;
        rp[i0 + 1] = excl + v.x;
        rp[i0 + 2] = excl + v.x + v.y;
        rp[i0 + 3] = excl + v.x + v.y + v.z;
    }
}

__global__ __launch_bounds__(256)
void scanC_kernel(int* __restrict__ rp2_all, int* __restrict__ cur2_all, const int* __restrict__ tot) {
    int enc = blockIdx.y;
    int* rp = rp2_all + (size_t)enc * (NK + 1);
    int* cur = cur2_all + (size_t)enc * NK;
    // block covers 1024 elements -> single scanA-block index nA = blockIdx.x>>2
    int nA = blockIdx.x >> 2;
    int part = 0;
    for (int i = threadIdx.x; i < nA; i += 256) part += tot[enc * SAB + i];
    #pragma unroll
    for (int d = 1; d < 64; d <<= 1) part += __shfl_xor(part, d, 64);
    __shared__ int red[4];
    __shared__ int soff;
    int lane = threadIdx.x & 63, wv = threadIdx.x >> 6;
    if (lane == 0) red[wv] = part;
    __syncthreads();
    if (threadIdx.x == 0) soff = red[0] + red[1] + red[2] + red[3];
    __syncthreads();
    int off = soff;
    int idx = (blockIdx.x * 256 + threadIdx.x) * 4;
    if (idx < NK) {
        int4 v = *(const int4*)(rp + idx);
        v.x += off; v.y += off; v.z += off; v.w += off;
        *(int4*)(rp + idx) = v;
        *(int4*)(cur + idx) = v;
    }
    if (blockIdx.x == 0 && threadIdx.x == 0) rp[NK] = NE;
}

// ---------------- scatter from buckets: XCD-pinned, key = dst*8 + src_range ----------------

__global__ __launch_bounds__(256)
void scatter_kernel(const u32* __restrict__ ebuf_d, const int* __restrict__ bcur,
                    int* __restrict__ cur2_all, u16* __restrict__ csr_all) {
    int stripe = blockIdx.x & 7, chunk = blockIdx.x >> 3;   // 64 chunks per stripe
    int enc = blockIdx.y;
    int size = bcur[enc * 16 + stripe];
    int cs = (size + 63) / 64;
    int lo = chunk * cs, hi = min(lo + cs, size);
    const u32* b = ebuf_d + ((size_t)enc * 8 + stripe) * CAPB;
    int* cursor = cur2_all + (size_t)enc * NK;
    u16* csr = csr_all + (size_t)enc * NE;
    int base = stripe * RN;
    for (int i = lo + threadIdx.x; i < hi; i += 256) {
        u32 e = b[i];
        int src = e & 0xffff;
        int dst = base + (int)(e >> 16);
        int key = dst * 8 + src / RN;
        int pos = atomicAdd(&cursor[key], 1);
        csr[pos] = (u16)src;
    }
}

__global__ void convw_kernel(const float* __restrict__ W1a, const float* __restrict__ W1b,
                             const float* __restrict__ W2a, const float* __restrict__ W2b,
                             u16* __restrict__ W1t_all, u16* __restrict__ W2t_all) {
    int mat = blockIdx.y;
    int idx = blockIdx.x * blockDim.x + threadIdx.x;
    const float* W; u16* Wt; int K, N;
    if (mat < 2) { W = mat ? W1b : W1a; Wt = W1t_all + (size_t)mat * 512 * 256; K = 512; N = 256; }
    else         { W = (mat == 3) ? W2b : W2a; Wt = W2t_all + (size_t)(mat - 2) * 256 * 128; K = 256; N = 128; }
    if (idx < K * N) {
        int k = idx / N, n = idx - k * N;
        Wt[(size_t)n * K + k] = f2bf_u16(W[idx]);
    }
}

// ---------------- MFMA GEMM: C = A @ Bt^T, 2-deep register-prefetch pipeline + ----------------
// LDS-repacked full-line epilogue. K multiple of 64. TRIANG: 1D upper-tri grid (it<=jt).

template<bool A_F32, bool OUT_BF16, bool TRIANG, bool SCALE>
__global__ __launch_bounds__(256)
void gemm_kernel(const void* __restrict__ A0_, const void* __restrict__ A1_,
                 const u16* __restrict__ Bt0, const u16* __restrict__ Bt1,
                 void* __restrict__ C0_, void* __restrict__ C1_,
                 const float* __restrict__ rs0, const float* __restrict__ rs1,
                 int M, int N, int K) {
    int enc = blockIdx.z;
    const void* A_ = enc ? A1_ : A0_;
    const u16* Bt = enc ? Bt1 : Bt0;
    void* C_ = enc ? C1_ : C0_;
    const float* rowscale = enc ? rs1 : rs0;

    int it, jt;
    if (TRIANG) {
        int b = blockIdx.x;  // enumerate it<=jt pairs; S(i)=i*(129-i)/2 pairs before row i
        int i = (int)((129.0f - sqrtf(129.f * 129.f - 8.f * b)) * 0.5f);
        while ((i + 1) * (129 - (i + 1)) / 2 <= b) ++i;
        while (i * (129 - i) / 2 > b) --i;
        it = i;
        jt = i + (b - i * (129 - i) / 2);
    } else {
        it = blockIdx.x; jt = blockIdx.y;
    }
    int t = threadIdx.x;
    int brow = it * 128, bcol = jt * 128;
    float* Cf = (float*)C_;
    __shared__ alignas(16) u16 smem[128 * 40 * 2];
    u16* As = smem;
    u16* Bs = smem + 128 * 40;
    int lane = t & 63, wv = t >> 6;
    int wr = wv >> 1, wc = wv & 1;
    f32x4 acc[4][4];
    #pragma unroll
    for (int m = 0; m < 4; ++m)
        #pragma unroll
        for (int n = 0; n < 4; ++n) acc[m][n] = f32x4{0.f, 0.f, 0.f, 0.f};

    // two named staging sets (static indexing only — runtime-indexed sets spill to scratch)
    float4 a_f0[4], a_f1[4];
    uint4  a_h0[2], a_h1[2];
    uint4  b_h0[2], b_h1[2];

#define LOADT(S, kk) do {                                                          \
    if constexpr (A_F32) {                                                         \
        const float* A = (const float*)A_;                                         \
        _Pragma("unroll")                                                          \
        for (int p = 0; p < 4; ++p) {                                              \
            int r = p * 32 + (t >> 3), c = (t & 7) * 4;                            \
            int gr = brow + r;                                                     \
            a_f##S[p] = make_float4(0.f, 0.f, 0.f, 0.f);                           \
            if (gr < M) a_f##S[p] = *(const float4*)(A + (size_t)gr * K + (kk) + c); \
        }                                                                          \
    } else {                                                                       \
        const u16* A = (const u16*)A_;                                             \
        _Pragma("unroll")                                                          \
        for (int p = 0; p < 2; ++p) {                                              \
            int r = p * 64 + (t >> 2), c = (t & 3) * 8;                            \
            int gr = brow + r;                                                     \
            a_h##S[p] = make_uint4(0u, 0u, 0u, 0u);                                \
            if (gr < M) a_h##S[p] = *(const uint4*)(A + (size_t)gr * K + (kk) + c); \
        }                                                                          \
    }                                                                              \
    _Pragma("unroll")                                                              \
    for (int p = 0; p < 2; ++p) {                                                  \
        int r = p * 64 + (t >> 2), c = (t & 3) * 8;                                \
        int gn = bcol + r;                                                         \
        b_h##S[p] = make_uint4(0u, 0u, 0u, 0u);                                    \
        if (gn < N) b_h##S[p] = *(const uint4*)(Bt + (size_t)gn * K + (kk) + c);   \
    }                                                                              \
} while (0)

#define STORET(S) do {                                                             \
    if constexpr (A_F32) {                                                         \
        _Pragma("unroll")                                                          \
        for (int p = 0; p < 4; ++p) {                                              \
            int r = p * 32 + (t >> 3), c = (t & 7) * 4;                            \
            u32 lo = (u32)f2bf_u16(a_f##S[p].x) | ((u32)f2bf_u16(a_f##S[p].y) << 16); \
            u32 hi = (u32)f2bf_u16(a_f##S[p].z) | ((u32)f2bf_u16(a_f##S[p].w) << 16); \
            *(uint2*)&As[r * 40 + c] = make_uint2(lo, hi);                         \
        }                                                                          \
    } else {                                                                       \
        _Pragma("unroll")                                                          \
        for (int p = 0; p < 2; ++p) {                                              \
            int r = p * 64 + (t >> 2), c = (t & 3) * 8;                            \
            *(uint4*)&As[r * 40 + c] = a_h##S[p];                                  \
        }                                                                          \
    }                                                                              \
    _Pragma("unroll")                                                              \
    for (int p = 0; p < 2; ++p) {                                                  \
        int r = p * 64 + (t >> 2), c = (t & 3) * 8;                                \
        *(uint4*)&Bs[r * 40 + c] = b_h##S[p];                                      \
    }                                                                              \
} while (0)

    auto compute = [&]() {
        int kg = (lane >> 4) * 8;
        short8 av[4], bv[4];
        #pragma unroll
        for (int m = 0; m < 4; ++m)
            av[m] = *(const short8*)&As[(wr * 64 + m * 16 + (lane & 15)) * 40 + kg];
        #pragma unroll
        for (int n = 0; n < 4; ++n)
            bv[n] = *(const short8*)&Bs[(wc * 64 + n * 16 + (lane & 15)) * 40 + kg];
        #pragma unroll
        for (int m = 0; m < 4; ++m)
            #pragma unroll
            for (int n = 0; n < 4; ++n)
                acc[m][n] = __builtin_amdgcn_mfma_f32_16x16x32_bf16(av[m], bv[n], acc[m][n], 0, 0, 0);
    };

    LOADT(0, 0);
    LOADT(1, 32);
    for (int k0 = 0; k0 < K; k0 += 64) {
        STORET(0);
        __syncthreads();
        if (k0 + 64 < K) LOADT(0, k0 + 64);   // 2 steps ahead — two MFMA phases of slack
        compute();
        __syncthreads();
        STORET(1);
        __syncthreads();
        if (k0 + 96 < K) LOADT(1, k0 + 96);
        compute();
        __syncthreads();
    }
#undef LOADT
#undef STORET

    // ---- epilogue: per-wave LDS repack -> full-line stores ----
    const int lane15 = lane & 15, lanehi = lane >> 4;
    if (OUT_BF16) {
        u16* stg = smem + wv * 1024;          // 16x64 u16 = 2 KB per wave
        #pragma unroll
        for (int m = 0; m < 4; ++m) {
            #pragma unroll
            for (int n = 0; n < 4; ++n)
                #pragma unroll
                for (int r = 0; r < 4; ++r) {
                    float v = acc[m][n][r];
                    if (SCALE) v *= rowscale[brow + wr * 64 + m * 16 + lanehi * 4 + r];
                    stg[(lanehi * 4 + r) * 64 + n * 16 + lane15] = f2bf_u16(v);
                }
            #pragma unroll
            for (int pass = 0; pass < 2; ++pass) {
                int lr = pass * 8 + (lane >> 3);
                int grow = brow + wr * 64 + m * 16 + lr;
                uint4 w = *(uint4*)&stg[lr * 64 + (lane & 7) * 8];
                if (grow < M)
                    *(uint4*)((u16*)C_ + (size_t)grow * N + bcol + wc * 64 + (lane & 7) * 8) = w;
            }
        }
    } else {
        float* stg = (float*)smem + wv * 1024;  // 16x64 f32 = 4 KB per wave
        #pragma unroll
        for (int m = 0; m < 4; ++m) {
            #pragma unroll
            for (int n = 0; n < 4; ++n)
                #pragma unroll
                for (int r = 0; r < 4; ++r) {
                    int row = brow + wr * 64 + m * 16 + lanehi * 4 + r;
                    int col = bcol + wc * 64 + n * 16 + lane15;
                    float v = acc[m][n][r];
                    if (SCALE) v *= rowscale[row];
                    if (TRIANG && col < row) v = 0.f;
                    stg[(lanehi * 4 + r) * 64 + n * 16 + lane15] = v;
                }
            #pragma unroll
            for (int pass = 0; pass < 4; ++pass) {
                int lr = pass * 4 + lanehi;
                int grow = brow + wr * 64 + m * 16 + lr;
                f32x4 w = *(f32x4*)&stg[lr * 64 + lane15 * 4];
                if (grow < M) {
                    float* dp = Cf + (size_t)grow * N + bcol + wc * 64 + lane15 * 4;
                    if (TRIANG) __builtin_nontemporal_store(w, (f32x4*)dp);
                    else *(f32x4*)dp = w;
                }
            }
        }
    }
}

// ---------------- aggregation (single enc): out[d] = nd[d]*sum Y[csr[e]] + b ----------------
// ZFILL: first ZLB blocks zero one lower-triangle 128x128 tile of z (NT stores; no deps;
// resource-compatible with agg: no LDS, ~same VGPR -> occupancy unaffected).

template<int F, bool RELU, bool OUT_BF16, bool ZFILL>
__global__ __launch_bounds__(256)
void agg_kernel(const u16* __restrict__ Y, const int* __restrict__ rp2,
                const u16* __restrict__ csr, const float* __restrict__ nd,
                const float* __restrict__ bias, void* __restrict__ out,
                float* __restrict__ zout) {
    int bid = blockIdx.x;
    if (ZFILL) {
        if (bid < ZLB) {
            int b = bid;
            float fit = (sqrtf(8.f * b + 1.f) + 1.f) * 0.5f;
            int it = (int)fit;
            if (it * (it - 1) / 2 > b) --it;
            else if ((it + 1) * it / 2 <= b) ++it;
            int jt = b - it * (it - 1) / 2;
            int brow = it * 128, bcol = jt * 128;
            f32x4 z = {0.f, 0.f, 0.f, 0.f};
            #pragma unroll
            for (int pq = 0; pq < 16; ++pq) {
                int idx = pq * 256 + threadIdx.x;
                int r = idx >> 5, c4 = idx & 31;
                __builtin_nontemporal_store(z, (f32x4*)(zout + (size_t)(brow + r) * NIDX + bcol + c4 * 4));
            }
            return;
        }
        bid -= ZLB;
    }
    constexpr int VPL = F / 64;
    int lane = threadIdx.x & 63;
    int node = bid * 4 + (threadIdx.x >> 6);
    if (node >= NN) return;
    int e0 = rp2[node * 8], e1 = rp2[node * 8 + 8];
    float acc[VPL];
    #pragma unroll
    for (int j = 0; j < VPL; ++j) acc[j] = 0.f;
    const int off = lane * VPL;

    int e = e0;
    for (; e < e1 && (e & 7) != 0; ++e) {
        int s = csr[e];
        if (VPL == 4) {
            uint2 d = *(const uint2*)(Y + (size_t)s * F + off);
            acc[0] += bfu(d.x & 0xffffu); acc[1] += bfu(d.x >> 16);
            acc[2] += bfu(d.y & 0xffffu); acc[3] += bfu(d.y >> 16);
        } else {
            u32 d = *(const u32*)(Y + (size_t)s * F + off);
            acc[0] += bfu(d & 0xffffu); acc[1] += bfu(d >> 16);
        }
    }
    for (; e + 8 <= e1; e += 8) {
        uint4 iv = *(const uint4*)(csr + e);
        int s0 = iv.x & 0xffff, s1 = iv.x >> 16;
        int s2 = iv.y & 0xffff, s3 = iv.y >> 16;
        int s4 = iv.z & 0xffff, s5 = iv.z >> 16;
        int s6 = iv.w & 0xffff, s7 = iv.w >> 16;
        if (VPL == 4) {
            uint2 d0 = *(const uint2*)(Y + (size_t)s0 * F + off);
            uint2 d1 = *(const uint2*)(Y + (size_t)s1 * F + off);
            uint2 d2 = *(const uint2*)(Y + (size_t)s2 * F + off);
            uint2 d3 = *(const uint2*)(Y + (size_t)s3 * F + off);
            uint2 d4 = *(const uint2*)(Y + (size_t)s4 * F + off);
            uint2 d5 = *(const uint2*)(Y + (size_t)s5 * F + off);
            uint2 d6 = *(const uint2*)(Y + (size_t)s6 * F + off);
            uint2 d7 = *(const uint2*)(Y + (size_t)s7 * F + off);
            acc[0] += bfu(d0.x & 0xffffu); acc[1] += bfu(d0.x >> 16); acc[2] += bfu(d0.y & 0xffffu); acc[3] += bfu(d0.y >> 16);
            acc[0] += bfu(d1.x & 0xffffu); acc[1] += bfu(d1.x >> 16); acc[2] += bfu(d1.y & 0xffffu); acc[3] += bfu(d1.y >> 16);
            acc[0] += bfu(d2.x & 0xffffu); acc[1] += bfu(d2.x >> 16); acc[2] += bfu(d2.y & 0xffffu); acc[3] += bfu(d2.y >> 16);
            acc[0] += bfu(d3.x & 0xffffu); acc[1] += bfu(d3.x >> 16); acc[2] += bfu(d3.y & 0xffffu); acc[3] += bfu(d3.y >> 16);
            acc[0] += bfu(d4.x & 0xffffu); acc[1] += bfu(d4.x >> 16); acc[2] += bfu(d4.y & 0xffffu); acc[3] += bfu(d4.y >> 16);
            acc[0] += bfu(d5.x & 0xffffu); acc[1] += bfu(d5.x >> 16); acc[2] += bfu(d5.y & 0xffffu); acc[3] += bfu(d5.y >> 16);
            acc[0] += bfu(d6.x & 0xffffu); acc[1] += bfu(d6.x >> 16); acc[2] += bfu(d6.y & 0xffffu); acc[3] += bfu(d6.y >> 16);
            acc[0] += bfu(d7.x & 0xffffu); acc[1] += bfu(d7.x >> 16); acc[2] += bfu(d7.y & 0xffffu); acc[3] += bfu(d7.y >> 16);
        } else {
            u32 d0 = *(const u32*)(Y + (size_t)s0 * F + off);
            u32 d1 = *(const u32*)(Y + (size_t)s1 * F + off);
            u32 d2 = *(const u32*)(Y + (size_t)s2 * F + off);
            u32 d3 = *(const u32*)(Y + (size_t)s3 * F + off);
            u32 d4 = *(const u32*)(Y + (size_t)s4 * F + off);
            u32 d5 = *(const u32*)(Y + (size_t)s5 * F + off);
            u32 d6 = *(const u32*)(Y + (size_t)s6 * F + off);
            u32 d7 = *(const u32*)(Y + (size_t)s7 * F + off);
            acc[0] += bfu(d0 & 0xffffu); acc[1] += bfu(d0 >> 16);
            acc[0] += bfu(d1 & 0xffffu); acc[1] += bfu(d1 >> 16);
            acc[0] += bfu(d2 & 0xffffu); acc[1] += bfu(d2 >> 16);
            acc[0] += bfu(d3 & 0xffffu); acc[1] += bfu(d3 >> 16);
            acc[0] += bfu(d4 & 0xffffu); acc[1] += bfu(d4 >> 16);
            acc[0] += bfu(d5 & 0xffffu); acc[1] += bfu(d5 >> 16);
            acc[0] += bfu(d6 & 0xffffu); acc[1] += bfu(d6 >> 16);
            acc[0] += bfu(d7 & 0xffffu); acc[1] += bfu(d7 >> 16);
        }
    }
    for (; e < e1; ++e) {
        int s = csr[e];
        if (VPL == 4) {
            uint2 d = *(const uint2*)(Y + (size_t)s * F + off);
            acc[0] += bfu(d.x & 0xffffu); acc[1] += bfu(d.x >> 16);
            acc[2] += bfu(d.y & 0xffffu); acc[3] += bfu(d.y >> 16);
        } else {
            u32 d = *(const u32*)(Y + (size_t)s * F + off);
            acc[0] += bfu(d & 0xffffu); acc[1] += bfu(d >> 16);
        }
    }

    float ndv = nd[node];
    #pragma unroll
    for (int j = 0; j < VPL; ++j) {
        float o = acc[j] * ndv + bias[off + j];
        if (RELU) o = fmaxf(o, 0.f);
        if (OUT_BF16) ((u16*)out)[(size_t)node * F + off + j] = f2bf_u16(o);
        else ((float*)out)[(size_t)node * F + off + j] = o;
    }
}

// ---------------- normalize + build R = [ (a+b)/2 , (a-b)/(2*sqrt(3)) ] ----------------

__global__ __launch_bounds__(256)
void build_r_kernel(const float* __restrict__ H2a, const float* __restrict__ H2b,
                    const int* __restrict__ index, u16* __restrict__ R) {
    int lane = threadIdx.x & 63;
    int row = blockIdx.x * 4 + (threadIdx.x >> 6);
    int g = index[row];
    float2 a = *(const float2*)(H2a + (size_t)g * 128 + lane * 2);
    float2 b = *(const float2*)(H2b + (size_t)g * 128 + lane * 2);
    float sa = a.x * a.x + a.y * a.y;
    float sb = b.x * b.x + b.y * b.y;
    #pragma unroll
    for (int d = 1; d < 64; d <<= 1) {
        sa += __shfl_xor(sa, d, 64);
        sb += __shfl_xor(sb, d, 64);
    }
    float inva = 1.f / fmaxf(sqrtf(sa), 1e-12f);
    float invb = 1.f / fmaxf(sqrtf(sb), 1e-12f);
    float ax = a.x * inva, ay = a.y * inva;
    float bx = b.x * invb, by = b.y * invb;
    const float c2 = 0.5f, c3 = 0.28867513459481287f;  // 1/(2*sqrt(3))
    u16* Rp = R + (size_t)row * 256;
    Rp[lane * 2]           = f2bf_u16((ax + bx) * c2);
    Rp[lane * 2 + 1]       = f2bf_u16((ay + by) * c2);
    Rp[128 + lane * 2]     = f2bf_u16((ax - bx) * c3);
    Rp[128 + lane * 2 + 1] = f2bf_u16((ay - by) * c3);
}

// ---------------- launch ----------------

extern "C" void kernel_launch(void* const* d_in, const int* in_sizes, int n_in,
                              void* d_out, int out_size, void* d_ws, size_t ws_size,
                              hipStream_t stream) {
    (void)in_sizes; (void)n_in; (void)out_size; (void)ws_size;
    const float* raw0 = (const float*)d_in[0];
    const float* raw1 = (const float*)d_in[1];
    const int* src1 = (const int*)d_in[2], *dst1 = (const int*)d_in[3];
    const int* src2 = (const int*)d_in[4], *dst2 = (const int*)d_in[5];
    const int* index = (const int*)d_in[6];
    const float* W1a = (const float*)d_in[7];  const float* b1a = (const float*)d_in[8];
    const float* W2a = (const float*)d_in[9];  const float* b2a = (const float*)d_in[10];
    const float* W1b = (const float*)d_in[11]; const float* b1b = (const float*)d_in[12];
    const float* W2b = (const float*)d_in[13]; const float* b2b = (const float*)d_in[14];

    char* wp = (char*)d_ws;
    auto alloc = [&](size_t bytes) -> char* {
        char* r = wp;
        wp += (bytes + 255) & ~(size_t)255;
        return r;
    };
    float* norms   = (float*)alloc((size_t)4 * NN * 4);
    int*   deg2    = (int*)alloc((size_t)2 * NK * 4);
    int*   rp2     = (int*)alloc((size_t)2 * (NK + 1) * 4);
    int*   cur2    = (int*)alloc((size_t)2 * NK * 4);
    int*   tot     = (int*)alloc((size_t)2 * SAB * 4);
    int*   bcur    = (int*)alloc(32 * 4);
    u16*   csr_all = (u16*)alloc((size_t)2 * NE * 2);
    u16*   W1t     = (u16*)alloc((size_t)2 * 512 * 256 * 2);
    u16*   W2t     = (u16*)alloc((size_t)2 * 256 * 128 * 2);
    u16*   Y1      = (u16*)alloc((size_t)2 * NN * 256 * 2);
    u16*   H1      = (u16*)alloc((size_t)2 * NN * 256 * 2);
    u16*   Y2      = (u16*)alloc((size_t)2 * NN * 128 * 2);
    float* H2      = (float*)alloc((size_t)2 * NN * 128 * 4);
    u16*   R       = (u16*)alloc((size_t)NIDX * 256 * 2);
    // aliases (dead ranges at time of use):
    u32* partial2    = (u32*)Y1;   // 12.8 MB in Y1; dead before gemm1 writes Y1
    u32* partial_out = (u32*)H1;   //  3.2 MB in H1; dead before agg1 writes H1
    u32* ebuf_d      = (u32*)Y2;   // 16.8 MB in Y2; consumed by bhist/scatter, dead before gemm2
    u16* ebuf_s      = (u16*)H2;   //  8.4 MB in H2; consumed by bhist, dead before agg2

    const int MT = (NN + 127) / 128;  // 391 row tiles

    hipMemsetAsync(bcur, 0, 32 * 4, stream);
    convw_kernel<<<dim3((512 * 256 + 255) / 256, 4), 256, 0, stream>>>(W1a, W1b, W2a, W2b, W1t, W2t);
    partition_kernel<<<dim3(PGX, 2), 256, 0, stream>>>(src1, dst1, src2, dst2, bcur, ebuf_d, ebuf_s);
    bhist_kernel<<<dim3(8 * HCH, 4), 256, 0, stream>>>(ebuf_d, ebuf_s, bcur, partial2, partial_out);
    reduce_hist_kernel<<<(2 * NN + 255) / 256, 256, 0, stream>>>(partial2, partial_out, deg2, norms);
    scanA_kernel<<<dim3(SAB, 2), 1024, 0, stream>>>(deg2, rp2, tot);
    scanC_kernel<<<dim3((NK / 4 + 255) / 256, 2), 256, 0, stream>>>(rp2, cur2, tot);
    scatter_kernel<<<dim3(8 * 64, 2), 256, 0, stream>>>(ebuf_d, bcur, cur2, csr_all);

    // Y1 = (raw @ W1) * ns[row]   (both encoders)
    gemm_kernel<true, true, false, true><<<dim3(MT, 2, 2), 256, 0, stream>>>(
        raw0, raw1, W1t, W1t + (size_t)512 * 256, Y1, Y1 + (size_t)NN * 256,
        norms, norms + (size_t)2 * NN, NN, 256, 512);
    // H1 = relu(nd * agg(Y1) + b1), bf16 — enc0 launch also zero-fills z's lower triangle
    agg_kernel<256, true, true, true><<<ZLB + AGB, 256, 0, stream>>>(
        Y1, rp2, csr_all, norms + NN, b1a, H1, (float*)d_out);
    agg_kernel<256, true, true, false><<<AGB, 256, 0, stream>>>(
        Y1 + (size_t)NN * 256, rp2 + (NK + 1), csr_all + (size_t)NE, norms + 3 * NN, b1b,
        H1 + (size_t)NN * 256, nullptr);
    // Y2 = (H1 @ W2) * ns[row]
    gemm_kernel<false, true, false, true><<<dim3(MT, 1, 2), 256, 0, stream>>>(
        H1, H1 + (size_t)NN * 256, W2t, W2t + (size_t)256 * 128, Y2, Y2 + (size_t)NN * 128,
        norms, norms + (size_t)2 * NN, NN, 128, 256);
    // H2 = nd * agg(Y2) + b2, f32
    agg_kernel<128, false, false, false><<<AGB, 256, 0, stream>>>(
        Y2, rp2, csr_all, norms + NN, b2a, H2, nullptr);
    agg_kernel<128, false, false, false><<<AGB, 256, 0, stream>>>(
        Y2 + (size_t)NN * 128, rp2 + (NK + 1), csr_all + (size_t)NE, norms + 3 * NN, b2b,
        H2 + (size_t)NN * 128, nullptr);

    // R = [ (c1n+c2n)/2 , (c1n-c2n)/(2*sqrt(3)) ]  (8192 x 256, bf16)
    build_r_kernel<<<NIDX / 4, 256, 0, stream>>>(H2, H2 + (size_t)NN * 128, index, R);
    // z = triu(R @ R^T): upper-tri tiles only (1D grid; lower filled during agg1)
    gemm_kernel<false, false, true, false><<<dim3(ZUB, 1, 1), 256, 0, stream>>>(
        R, R, R, R, (float*)d_out, (float*)d_out, nullptr, nullptr, NIDX, NIDX, 256);
}